// Round 3
// baseline (494.031 us; speedup 1.0000x reference)
//
#include <hip/hip_runtime.h>
#include <hip/hip_fp16.h>
#include <math.h>

#define BB 16
#define NN 96
#define NE 256
#define FF (BB*NN)      // 1536
#define ATOM 128
#define EDIM 16
#define HID 128
#define LAT 128
#define RBFN 16
#define CUTOFF 5.0f
#define ZEMB 32
#define E_ATT 1024
#define M0I 64
#define M1I 32
#define M0O 32
#define M1O 16
#define NODE_DIM 160
#define OUT_DIM 80
#define INVD 48
#define WNUM 4608
#define SEG1 2048
#define SEG2 3072
#define SEG3 3584

// phase-A units
#define EDGE_BLKS (E_ATT/4)  // 256
#define EC_BLKS 16
#define HABS_BLKS 2
#define GATE_BLKS 16
#define TRANS_BLKS 144
#define STAGE1_UNITS (EDGE_BLKS + EC_BLKS + HABS_BLKS + GATE_BLKS + TRANS_BLKS + 1)  // 435

// phase-B units
#define MFMA_UNITS (36*16)          // 576
#define MQ_UNITS (MFMA_UNITS + 512) // 1088

// phase-C units
#define SCORE_UNITS 128
#define ST_UNITS (SCORE_UNITS + 512) // 640

// phase-D units
#define ATT_UNITS 512

#define GRID_BLKS 512
#define SMEM_BYTES 34304   // max over phases: scores 8544 floats

typedef _Float16 half8_t __attribute__((ext_vector_type(8)));
typedef float float4v __attribute__((ext_vector_type(4)));

__device__ __forceinline__ float silu_f(float x) { return x / (1.0f + expf(-x)); }

// Self-managed grid barrier (no cooperative launch; graph-capture safe).
// Monotonic counter: phase p waits for cnt >= GRID_BLKS*p.
// __threadfence() = agent-scope fence: on gfx950 this writes back / invalidates
// the per-XCD L2 (same semantics kernel boundaries provided in the 4-kernel version).
__device__ __forceinline__ void grid_barrier(int* cnt, int target) {
    __syncthreads();                       // drain this block's stores (waitcnt) + converge
    if (threadIdx.x == 0) {
        __threadfence();                   // release: write back dirty L2 to IF
        atomicAdd(cnt, 1);                 // device-scope by default on global mem
        while (__hip_atomic_load(cnt, __ATOMIC_RELAXED, __HIP_MEMORY_SCOPE_AGENT) < target) {
            __builtin_amdgcn_s_sleep(2);
        }
    }
    __syncthreads();
    __threadfence();                       // acquire: invalidate stale L1/L2 lines
}

struct Params {
    const float *h, *h_full, *e_feat, *att_dist, *att_vec, *z_emb;
    const float *rw1, *rb1, *rw2, *rb2;
    const float *ew1, *eb1, *ew2, *eb2;
    const float *qw1, *qb1, *qw2, *qb2, *qw3, *qb3;
    const float *kw1, *kb1, *kw2, *kb2, *kw3, *kb3;
    const float *ow1, *ob1, *ow2, *ob2, *ow3, *ob3;
    const int *z, *absorber, *att_dst;
    __half *hiddenH; float *kmat; float *ec; float *habs1; float *gexp;
    __half *rw2T; int *inv; float *y1E; float *envE;
    float *qmat; float *scoresW; __half *tpwE; float *virr;
    int *bar;
    float *out;
};

__global__ void k_init(int* bar) {
    if (threadIdx.x == 0) bar[0] = 0;
}

__global__ __launch_bounds__(256, 2) void k_mega(Params p)
{
    __shared__ __align__(16) char smemraw[SMEM_BYTES];
    float* smem = (float*)smemraw;
    const int t = threadIdx.x;
    const int blk = blockIdx.x;

    const float* __restrict__ h        = p.h;
    const float* __restrict__ h_full   = p.h_full;
    const float* __restrict__ e_feat   = p.e_feat;
    const float* __restrict__ att_dist = p.att_dist;
    const float* __restrict__ att_vec  = p.att_vec;
    const float* __restrict__ z_emb    = p.z_emb;
    const float* __restrict__ rw1 = p.rw1; const float* __restrict__ rb1 = p.rb1;
    const float* __restrict__ rw2 = p.rw2; const float* __restrict__ rb2 = p.rb2;
    const float* __restrict__ ew1 = p.ew1; const float* __restrict__ eb1 = p.eb1;
    const float* __restrict__ ew2 = p.ew2; const float* __restrict__ eb2 = p.eb2;
    const float* __restrict__ qw1 = p.qw1; const float* __restrict__ qb1 = p.qb1;
    const float* __restrict__ qw2 = p.qw2; const float* __restrict__ qb2 = p.qb2;
    const float* __restrict__ qw3 = p.qw3; const float* __restrict__ qb3 = p.qb3;
    const float* __restrict__ kw1 = p.kw1; const float* __restrict__ kb1 = p.kb1;
    const float* __restrict__ kw2 = p.kw2; const float* __restrict__ kb2 = p.kb2;
    const float* __restrict__ kw3 = p.kw3; const float* __restrict__ kb3 = p.kb3;
    const float* __restrict__ ow1 = p.ow1; const float* __restrict__ ob1 = p.ob1;
    const float* __restrict__ ow2 = p.ow2; const float* __restrict__ ob2 = p.ob2;
    const float* __restrict__ ow3 = p.ow3; const float* __restrict__ ob3 = p.ob3;
    const int* __restrict__ z        = p.z;
    const int* __restrict__ absorber = p.absorber;
    const int* __restrict__ att_dst  = p.att_dst;
    __half* __restrict__ hiddenH = p.hiddenH;
    float*  __restrict__ kmat    = p.kmat;
    float*  __restrict__ ec      = p.ec;
    float*  __restrict__ habs1   = p.habs1;
    float*  __restrict__ gexp    = p.gexp;
    __half* __restrict__ rw2T    = p.rw2T;
    int*    __restrict__ inv     = p.inv;
    float*  __restrict__ y1E     = p.y1E;
    float*  __restrict__ envE    = p.envE;
    float*  __restrict__ qmat    = p.qmat;
    float*  __restrict__ scoresW = p.scoresW;
    __half* __restrict__ tpwE    = p.tpwE;
    float*  __restrict__ virr    = p.virr;
    float*  __restrict__ out     = p.out;
    int* bar = p.bar;

    // =================== PHASE A: stage1 ===================
    for (int u = blk; u < STAGE1_UNITS; u += GRID_BLKS) {
        if (u < EDGE_BLKS) {
            float (*sin1)[184] = (float(*)[184])smem;
            float (*l1S)[128]  = (float(*)[128])(smem + 736);
            float (*l2S)[128]  = (float(*)[128])(smem + 736 + 512);
            int w = t >> 6;
            int c = t & 63;
            int e = u*4 + w;
            int f = att_dst[e];
            int b = f / NN, nn = f - b*NN;
            float d = att_dist[e];
            {
                float2 hv = *(const float2*)&h[f*ATOM + 2*c];
                sin1[w][2*c] = hv.x; sin1[w][2*c + 1] = hv.y;
            }
            if (c < ZEMB) sin1[w][ATOM + c] = z_emb[z[f]*ZEMB + c];
            if (c >= 32 && c < 48) {
                int j = c - 32;
                const float delta = CUTOFF / (RBFN - 1);
                float diff = d - j*delta;
                sin1[w][ATOM + ZEMB + 1 + j] = expf(-diff*diff / (2.0f*delta*delta));
            }
            if (c == 48) sin1[w][ATOM + ZEMB] = (absorber[b] == nn) ? 1.0f : 0.0f;
            __syncthreads();
            int c2 = 2*c;
            {   // hidden = silu(w_in @ rw1 + rb1): 49 -> 128
                float2 a0 = *(const float2*)&rb1[c2];
                float2 a1 = make_float2(0.f, 0.f);
                #pragma unroll 8
                for (int i = 0; i < 48; i += 2) {
                    float x0v = sin1[w][ATOM + i], x1v = sin1[w][ATOM + i + 1];
                    float2 w0 = *(const float2*)&rw1[i*HID + c2];
                    float2 w1 = *(const float2*)&rw1[(i+1)*HID + c2];
                    a0.x += x0v*w0.x; a0.y += x0v*w0.y;
                    a1.x += x1v*w1.x; a1.y += x1v*w1.y;
                }
                {
                    float x0v = sin1[w][ATOM + 48];
                    float2 w0 = *(const float2*)&rw1[48*HID + c2];
                    a0.x += x0v*w0.x; a0.y += x0v*w0.y;
                }
                *(__half2*)&hiddenH[e*HID + c2] =
                    __floats2half2_rn(silu_f(a0.x + a1.x), silu_f(a0.y + a1.y));
            }
            {   // k layer 1: 177 -> 128
                float2 a0 = *(const float2*)&kb1[c2];
                float2 a1 = make_float2(0.f, 0.f);
                #pragma unroll 8
                for (int i = 0; i < 176; i += 2) {
                    float x0v = sin1[w][i], x1v = sin1[w][i + 1];
                    float2 w0 = *(const float2*)&kw1[i*HID + c2];
                    float2 w1 = *(const float2*)&kw1[(i+1)*HID + c2];
                    a0.x += x0v*w0.x; a0.y += x0v*w0.y;
                    a1.x += x1v*w1.x; a1.y += x1v*w1.y;
                }
                {
                    float x0v = sin1[w][176];
                    float2 w0 = *(const float2*)&kw1[176*HID + c2];
                    a0.x += x0v*w0.x; a0.y += x0v*w0.y;
                }
                l1S[w][c2] = silu_f(a0.x + a1.x); l1S[w][c2+1] = silu_f(a0.y + a1.y);
            }
            __syncthreads();
            {   // k layer 2
                float2 a0 = *(const float2*)&kb2[c2];
                float2 a1 = make_float2(0.f, 0.f);
                #pragma unroll 8
                for (int i = 0; i < HID; i += 2) {
                    float x0v = l1S[w][i], x1v = l1S[w][i + 1];
                    float2 w0 = *(const float2*)&kw2[i*HID + c2];
                    float2 w1 = *(const float2*)&kw2[(i+1)*HID + c2];
                    a0.x += x0v*w0.x; a0.y += x0v*w0.y;
                    a1.x += x1v*w1.x; a1.y += x1v*w1.y;
                }
                l2S[w][c2] = silu_f(a0.x + a1.x); l2S[w][c2+1] = silu_f(a0.y + a1.y);
            }
            __syncthreads();
            {   // k layer 3 -> kmat
                float2 a0 = *(const float2*)&kb3[c2];
                float2 a1 = make_float2(0.f, 0.f);
                #pragma unroll 8
                for (int i = 0; i < HID; i += 2) {
                    float x0v = l2S[w][i], x1v = l2S[w][i + 1];
                    float2 w0 = *(const float2*)&kw3[i*HID + c2];
                    float2 w1 = *(const float2*)&kw3[(i+1)*HID + c2];
                    a0.x += x0v*w0.x; a0.y += x0v*w0.y;
                    a1.x += x1v*w1.x; a1.y += x1v*w1.y;
                }
                float2 o; o.x = a0.x + a1.x; o.y = a0.y + a1.y;
                *(float2*)&kmat[f*HID + c2] = o;
            }
        } else if (u < EDGE_BLKS + EC_BLKS) {
            float (*ef)[16] = (float(*)[16])smem;
            int e0 = (u - EDGE_BLKS) * 16;
            { int e = t >> 4, i = t & 15; ef[e][i] = e_feat[(e0 + e)*EDIM + i]; }
            __syncthreads();
            int r = t >> 4, c0 = (t & 15)*8;
            float4 a0 = make_float4(0,0,0,0), a1 = a0;
            #pragma unroll
            for (int i = 0; i < EDIM; i++) {
                float a = ef[r][i];
                float4 w0 = *(const float4*)&qw1[(ATOM + i)*HID + c0];
                float4 w1 = *(const float4*)&qw1[(ATOM + i)*HID + c0 + 4];
                a0.x += a*w0.x; a0.y += a*w0.y; a0.z += a*w0.z; a0.w += a*w0.w;
                a1.x += a*w1.x; a1.y += a*w1.y; a1.z += a*w1.z; a1.w += a*w1.w;
            }
            *(float4*)&ec[(e0 + r)*HID + c0] = a0;
            *(float4*)&ec[(e0 + r)*HID + c0 + 4] = a1;
        } else if (u < EDGE_BLKS + EC_BLKS + HABS_BLKS) {
            float (*hr)[128] = (float(*)[128])smem;
            int b0 = (u - EDGE_BLKS - EC_BLKS) * 8;
            {
                int r = t >> 5, i4 = t & 31;
                int b = b0 + r;
                int a = absorber[b];
                *(float4*)&hr[r][i4*4] = *(const float4*)&h[(b*NN + a)*ATOM + i4*4];
            }
            __syncthreads();
            int r = t >> 5, c0 = (t & 31)*4;
            float4 a0 = make_float4(0,0,0,0), a1 = a0;
            #pragma unroll 8
            for (int i = 0; i < ATOM; i += 2) {
                float x0v = hr[r][i], x1v = hr[r][i+1];
                float4 w0 = *(const float4*)&qw1[i*HID + c0];
                float4 w1 = *(const float4*)&qw1[(i+1)*HID + c0];
                a0.x += x0v*w0.x; a0.y += x0v*w0.y; a0.z += x0v*w0.z; a0.w += x0v*w0.w;
                a1.x += x1v*w1.x; a1.y += x1v*w1.y; a1.z += x1v*w1.z; a1.w += x1v*w1.w;
            }
            float4 o;
            o.x = a0.x + a1.x; o.y = a0.y + a1.y; o.z = a0.z + a1.z; o.w = a0.w + a1.w;
            *(float4*)&habs1[(b0 + r)*HID + c0] = o;
        } else if (u < EDGE_BLKS + EC_BLKS + HABS_BLKS + GATE_BLKS) {
            float (*ef)[16]   = (float(*)[16])smem;
            float (*l1g)[128] = (float(*)[128])(smem + 256);
            float (*gg)[48]   = (float(*)[48])(smem + 256 + 2048);
            int e0 = (u - EDGE_BLKS - EC_BLKS - HABS_BLKS) * 16;
            { int e = t >> 4, i = t & 15; ef[e][i] = e_feat[(e0 + e)*EDIM + i]; }
            __syncthreads();
            int r = t >> 4, c0 = (t & 15)*8;
            {
                float4 a0 = *(const float4*)&eb1[c0];
                float4 a1 = *(const float4*)&eb1[c0 + 4];
                #pragma unroll
                for (int i = 0; i < EDIM; i++) {
                    float a = ef[r][i];
                    float4 w0 = *(const float4*)&ew1[i*HID + c0];
                    float4 w1 = *(const float4*)&ew1[i*HID + c0 + 4];
                    a0.x += a*w0.x; a0.y += a*w0.y; a0.z += a*w0.z; a0.w += a*w0.w;
                    a1.x += a*w1.x; a1.y += a*w1.y; a1.z += a*w1.z; a1.w += a*w1.w;
                }
                l1g[r][c0]   = silu_f(a0.x); l1g[r][c0+1] = silu_f(a0.y);
                l1g[r][c0+2] = silu_f(a0.z); l1g[r][c0+3] = silu_f(a0.w);
                l1g[r][c0+4] = silu_f(a1.x); l1g[r][c0+5] = silu_f(a1.y);
                l1g[r][c0+6] = silu_f(a1.z); l1g[r][c0+7] = silu_f(a1.w);
            }
            __syncthreads();
            for (int uu = t; uu < 16*48; uu += 256) {
                int e = uu / 48, j = uu - 48*(uu/48);
                float acc = eb2[j];
                #pragma unroll 4
                for (int i = 0; i < HID; i++) acc += l1g[e][i]*ew2[i*48 + j];
                gg[e][j] = acc;
            }
            __syncthreads();
            for (int uu = t; uu < 16*80; uu += 256) {
                int e = uu / 80, cc = uu - 80*(uu/80);
                gexp[(e0 + e)*OUT_DIM + cc] = (cc < M0O) ? gg[e][cc] : gg[e][M0O + (cc - M0O)/3];
            }
        } else if (u < EDGE_BLKS + EC_BLKS + HABS_BLKS + GATE_BLKS + TRANS_BLKS) {
            __half* lds = (__half*)smem;  // [64][66]
            int tb = u - (EDGE_BLKS + EC_BLKS + HABS_BLKS + GATE_BLKS);
            int nt = tb % 72, kt = tb / 72;
            int n0 = nt*64, k0 = kt*64;
            for (int pp = 0; pp < 16; pp++) {
                int idx = t + 256*pp;
                int kk = idx >> 6, nn = idx & 63;
                lds[nn*66 + kk] = __float2half(rw2[(k0+kk)*WNUM + n0+nn]);
            }
            __syncthreads();
            for (int pp = 0; pp < 16; pp++) {
                int idx = t + 256*pp;
                int nn = idx >> 6, kk = idx & 63;
                rw2T[(n0+nn)*HID + k0+kk] = lds[nn*66 + kk];
            }
        } else {
            for (int pp = 0; pp < 6; pp++) inv[t + 256*pp] = -1;
            for (int pp = 0; pp < 4; pp++) {
                int e = t + 256*pp;
                float d = att_dist[e];
                envE[e] = (d < CUTOFF) ? 0.5f*(cosf(3.14159265358979323846f*d/CUTOFF) + 1.0f) : 0.0f;
                float vx = att_vec[3*e], vy = att_vec[3*e+1], vz = att_vec[3*e+2];
                float nrm = sqrtf(vx*vx + vy*vy + vz*vz);
                float is = 1.0f / fmaxf(nrm, 1e-8f);
                const float s3 = 1.7320508075688772f;
                y1E[3*e]   = s3*vx*is;
                y1E[3*e+1] = s3*vy*is;
                y1E[3*e+2] = s3*vz*is;
            }
            __syncthreads();
            for (int pp = 0; pp < 4; pp++) { int e = t + 256*pp; inv[att_dst[e]] = e; }
        }
    }

    grid_barrier(bar, GRID_BLKS*1);

    // =================== PHASE B: MFMA tpw + q layers ===================
    for (int u = blk; u < MQ_UNITS; u += GRID_BLKS) {
        __syncthreads();  // LDS reuse guard across units
        if (u < MFMA_UNITS) {
            int colTile = u % 36;
            int rowGrp  = u / 36;
            int wv = t >> 6;
            int lane = t & 63;
            int m0 = (rowGrp*4 + wv) * 16;
            int n0 = colTile * 128;
            int mrow = lane & 15, quad = lane >> 4;
            __half* cS = (__half*)smemraw + wv * (16*136);
            const _Float16* hp = (const _Float16*)hiddenH + (m0 + mrow)*HID + quad*8;
            half8_t af[4];
            #pragma unroll
            for (int kc = 0; kc < 4; kc++) af[kc] = *(const half8_t*)(hp + kc*32);
            #pragma unroll
            for (int nt = 0; nt < 8; nt++) {
                const _Float16* bp = (const _Float16*)rw2T + (n0 + nt*16 + mrow)*HID + quad*8;
                float4v acc = {0.f, 0.f, 0.f, 0.f};
                #pragma unroll
                for (int kc = 0; kc < 4; kc++) {
                    half8_t bf = *(const half8_t*)(bp + kc*32);
                    acc = __builtin_amdgcn_mfma_f32_16x16x32_f16(af[kc], bf, acc, 0, 0, 0);
                }
                float bias = rb2[n0 + nt*16 + mrow];
                #pragma unroll
                for (int r = 0; r < 4; r++)
                    cS[(quad*4 + r)*136 + nt*16 + mrow] = __float2half(acc[r] + bias);
            }
            __syncthreads();
            #pragma unroll
            for (int pp = 0; pp < 4; pp++) {
                int chunk = lane + 64*pp;
                int row = chunk >> 4, c8 = (chunk & 15)*8;
                float4 v = *(float4*)&cS[row*136 + c8];
                *(float4*)&tpwE[(long)(m0 + row)*WNUM + n0 + c8] = v;
            }
        } else {
            float* l1S = smem;
            float* l2S = smem + 1024;
            int r0 = (u - MFMA_UNITS) * 8;
            for (int pp = 0; pp < 4; pp++) {
                int idx = t + 256*pp;
                int rr = idx >> 7, i = idx & 127;
                int be = r0 + rr; int b = be >> 8; int e = be & 255;
                l1S[rr*128 + i] = silu_f(habs1[b*HID + i] + ec[e*HID + i] + qb1[i]);
            }
            __syncthreads();
            int r = t >> 5, c0 = (t & 31)*4;
            {
                float4 a0 = *(const float4*)&qb2[c0];
                float4 a1 = make_float4(0,0,0,0);
                #pragma unroll 8
                for (int i = 0; i < HID; i += 2) {
                    float x0v = l1S[r*128 + i], x1v = l1S[r*128 + i+1];
                    float4 w0 = *(const float4*)&qw2[i*HID + c0];
                    float4 w1 = *(const float4*)&qw2[(i+1)*HID + c0];
                    a0.x += x0v*w0.x; a0.y += x0v*w0.y; a0.z += x0v*w0.z; a0.w += x0v*w0.w;
                    a1.x += x1v*w1.x; a1.y += x1v*w1.y; a1.z += x1v*w1.z; a1.w += x1v*w1.w;
                }
                l2S[r*128 + c0]   = silu_f(a0.x + a1.x); l2S[r*128 + c0+1] = silu_f(a0.y + a1.y);
                l2S[r*128 + c0+2] = silu_f(a0.z + a1.z); l2S[r*128 + c0+3] = silu_f(a0.w + a1.w);
            }
            __syncthreads();
            {
                float4 a0 = *(const float4*)&qb3[c0];
                float4 a1 = make_float4(0,0,0,0);
                #pragma unroll 8
                for (int i = 0; i < HID; i += 2) {
                    float x0v = l2S[r*128 + i], x1v = l2S[r*128 + i+1];
                    float4 w0 = *(const float4*)&qw3[i*HID + c0];
                    float4 w1 = *(const float4*)&qw3[(i+1)*HID + c0];
                    a0.x += x0v*w0.x; a0.y += x0v*w0.y; a0.z += x0v*w0.z; a0.w += x0v*w0.w;
                    a1.x += x1v*w1.x; a1.y += x1v*w1.y; a1.z += x1v*w1.z; a1.w += x1v*w1.w;
                }
                float4 o;
                o.x = a0.x + a1.x; o.y = a0.y + a1.y; o.z = a0.z + a1.z; o.w = a0.w + a1.w;
                *(float4*)&qmat[(r0 + r)*LAT + c0] = o;
            }
        }
    }

    grid_barrier(bar, GRID_BLKS*2);

    // =================== PHASE C: scores GEMM + tensor product ===================
    for (int u = blk; u < ST_UNITS; u += GRID_BLKS) {
        __syncthreads();  // LDS reuse guard
        if (u < SCORE_UNITS) {
            int b  = u >> 3;
            int e0 = (u & 7) * 32;
            float (*Qs)[132] = (float(*)[132])smem;
            float (*Kt)[132] = (float(*)[132])(smem + 32*132);
            float* mS = smem + 2*32*132;
            for (int pp = 0; pp < 4; pp++) {
                int idx = t + 256*pp; int e = idx >> 5, i4 = idx & 31;
                *(float4*)&Qs[e][i4*4] = *(const float4*)&qmat[(b*NE + e0 + e)*LAT + i4*4];
            }
            if (t < NN) mS[t] = ((unsigned)inv[b*NN + t] < E_ATT) ? 1.0f : 0.0f;
            int te = t >> 5, tn = t & 31;
            float acc[4][3] = {};
            for (int nt = 0; nt < 3; nt++) {
                __syncthreads();
                for (int pp = 0; pp < 4; pp++) {
                    int idx = t + 256*pp; int n = idx >> 5, i4 = idx & 31;
                    *(float4*)&Kt[n][i4*4] = *(const float4*)&kmat[(b*NN + nt*32 + n)*LAT + i4*4];
                }
                __syncthreads();
                for (int i = 0; i < LAT; i++) {
                    float bv = Kt[tn][i];
                    acc[0][nt] += Qs[te*4 + 0][i]*bv;
                    acc[1][nt] += Qs[te*4 + 1][i]*bv;
                    acc[2][nt] += Qs[te*4 + 2][i]*bv;
                    acc[3][nt] += Qs[te*4 + 3][i]*bv;
                }
            }
            const float scale = 0.04419417382415922f;  // (1/HEADS)*HD^-0.5
            #pragma unroll
            for (int j = 0; j < 4; j++)
                #pragma unroll
                for (int jj = 0; jj < 3; jj++) {
                    int n = tn + 32*jj;
                    float s = (mS[n] != 0.f) ? acc[j][jj]*scale : -1e9f;
                    scoresW[((b*NE) + e0 + te*4 + j)*NN + n] = s;
                }
        } else {
            int sub = t >> 7, tt = t & 127;
            int e = (u - SCORE_UNITS)*2 + sub;
            int f = att_dst[e];
            float* x0  = smem + sub*256;
            float* x1f = smem + sub*256 + 64;
            float* xy  = smem + sub*256 + 160;
            float* y1s = smem + sub*256 + 192;
            const float* hf = h_full + f*NODE_DIM;
            if (tt < M0I) x0[tt] = hf[tt];
            if (tt < M1I*3) x1f[tt] = hf[M0I + tt];
            if (tt < 3) y1s[tt] = y1E[3*e + tt];
            __syncthreads();
            if (tt < M1I) xy[tt] = x1f[3*tt]*y1s[0] + x1f[3*tt+1]*y1s[1] + x1f[3*tt+2]*y1s[2];
            __syncthreads();
            float scale = envE[e];
            const __half* w = tpwE + (long)e*WNUM;
            const float alpha = 0.10206207261596575f;  // 1/sqrt(96)
            const float cc = 0.5773502691896258f;      // 1/sqrt(3)
            if (tt < M0O) {
                float t00 = 0.f, t11 = 0.f;
                #pragma unroll 4
                for (int i = 0; i < M0I; i++) t00 += x0[i]*__half2float(w[i*M0O + tt]);
                #pragma unroll 4
                for (int i = 0; i < M1I; i++) t11 += xy[i]*__half2float(w[SEG3 + i*M0O + tt]);
                virr[f*OUT_DIM + tt] = alpha*(t00 + cc*t11)*scale;
            } else if (tt < M0O + 3*M1O) {
                int idx = tt - M0O; int o = idx/3, m = idx - 3*o;
                float t01 = 0.f, t10 = 0.f;
                #pragma unroll 4
                for (int i = 0; i < M0I; i++) t01 += x0[i]*__half2float(w[SEG1 + i*M1O + o]);
                #pragma unroll 4
                for (int i = 0; i < M1I; i++) t10 += x1f[i*3 + m]*__half2float(w[SEG2 + i*M1O + o]);
                virr[f*OUT_DIM + tt] = alpha*cc*(t01*y1s[m] + t10)*scale;
            }
        }
    }

    grid_barrier(bar, GRID_BLKS*3);

    // =================== PHASE D: attention + final MLP ===================
    for (int u = blk; u < ATT_UNITS; u += GRID_BLKS) {
        int b  = u >> 5;
        int e0 = (u & 31) * 8;
        float (*aS)[100]  = (float(*)[100])smem;               // 800
        float (*gS)[84]   = (float(*)[84])(smem + 800);        // 672
        float (*ocS)[84]  = (float(*)[84])(smem + 1472);       // 672
        float* mS         = smem + 2144;                       // 96
        float (*inS)[INVD] = (float(*)[INVD])(smem + 2240);    // 384
        float (*l1S)[HID] = (float(*)[HID])(smem + 2624);      // 1024
        float (*l2S)[HID] = (float(*)[HID])(smem + 3648);      // 1024

        for (int pp = 0; pp < 3; pp++) {
            int idx = t + 256*pp;
            int el = idx / NN, n = idx - NN*(idx/NN);
            aS[el][n] = scoresW[((b*NE) + e0 + el)*NN + n];
        }
        if (t < 160) {
            int el = t / 20, c4 = t - 20*(t/20);
            *(float4*)&gS[el][c4*4] = *(const float4*)&gexp[(e0 + el)*OUT_DIM + c4*4];
        }
        if (t < NN) mS[t] = ((unsigned)inv[b*NN + t] < E_ATT) ? 1.0f : 0.0f;
        __syncthreads();

        {
            int el = t >> 5;
            int ng = t & 31;
            float s0 = aS[el][ng], s1 = aS[el][ng + 32], s2 = aS[el][ng + 64];
            float m0 = mS[ng], m1 = mS[ng + 32], m2 = mS[ng + 64];
            float mx = fmaxf(s0, fmaxf(s1, s2));
            #pragma unroll
            for (int off = 1; off < 32; off <<= 1) mx = fmaxf(mx, __shfl_xor(mx, off));
            float e0v = expf(s0 - mx), e1v = expf(s1 - mx), e2v = expf(s2 - mx);
            float sm = e0v + e1v + e2v;
            #pragma unroll
            for (int off = 1; off < 32; off <<= 1) sm += __shfl_xor(sm, off);
            float r = 1.0f / sm;
            float p0 = m0*e0v*r, p1 = m1*e1v*r, p2 = m2*e2v*r;
            float ss = p0 + p1 + p2;
            #pragma unroll
            for (int off = 1; off < 32; off <<= 1) ss += __shfl_xor(ss, off);
            float is = 1.0f / fmaxf(ss, 1e-8f);
            aS[el][ng]      = p0*is;
            aS[el][ng + 32] = p1*is;
            aS[el][ng + 64] = p2*is;
        }
        __syncthreads();

        if (t < 160) {
            int el = t / 20, c4 = t - 20*(t/20);
            const float* vp = virr + (long)b*NN*OUT_DIM + c4*4;
            float4 acc = make_float4(0,0,0,0);
            #pragma unroll 4
            for (int n = 0; n < NN; n++) {
                float a = aS[el][n];
                float4 v = *(const float4*)&vp[n*OUT_DIM];
                acc.x += a*v.x; acc.y += a*v.y; acc.z += a*v.z; acc.w += a*v.w;
            }
            float4 g = *(float4*)&gS[el][c4*4];
            float4 o; o.x = acc.x*g.x; o.y = acc.y*g.y; o.z = acc.z*g.z; o.w = acc.w*g.w;
            *(float4*)&ocS[el][c4*4] = o;
        }
        __syncthreads();

        for (int uu = t; uu < 8*INVD; uu += 256) {
            int el = uu / INVD, j = uu - INVD*(uu/INVD);
            float val;
            if (j < M0O) val = ocS[el][j];
            else {
                int o = j - M0O;
                float x = ocS[el][M0O + 3*o], y = ocS[el][M0O + 3*o + 1], zz = ocS[el][M0O + 3*o + 2];
                val = sqrtf(x*x + y*y + zz*zz + 1e-12f);
            }
            inS[el][j] = val;
        }
        __syncthreads();

        int r = t >> 5, c0 = (t & 31)*4;
        {
            float4 a0 = *(const float4*)&ob1[c0];
            float4 a1 = make_float4(0,0,0,0);
            #pragma unroll 8
            for (int i = 0; i < INVD; i += 2) {
                float x0v = inS[r][i], x1v = inS[r][i+1];
                float4 w0 = *(const float4*)&ow1[i*HID + c0];
                float4 w1 = *(const float4*)&ow1[(i+1)*HID + c0];
                a0.x += x0v*w0.x; a0.y += x0v*w0.y; a0.z += x0v*w0.z; a0.w += x0v*w0.w;
                a1.x += x1v*w1.x; a1.y += x1v*w1.y; a1.z += x1v*w1.z; a1.w += x1v*w1.w;
            }
            l1S[r][c0]   = silu_f(a0.x + a1.x); l1S[r][c0+1] = silu_f(a0.y + a1.y);
            l1S[r][c0+2] = silu_f(a0.z + a1.z); l1S[r][c0+3] = silu_f(a0.w + a1.w);
        }
        __syncthreads();
        {
            float4 a0 = *(const float4*)&ob2[c0];
            float4 a1 = make_float4(0,0,0,0);
            #pragma unroll 8
            for (int i = 0; i < HID; i += 2) {
                float x0v = l1S[r][i], x1v = l1S[r][i+1];
                float4 w0 = *(const float4*)&ow2[i*HID + c0];
                float4 w1 = *(const float4*)&ow2[(i+1)*HID + c0];
                a0.x += x0v*w0.x; a0.y += x0v*w0.y; a0.z += x0v*w0.z; a0.w += x0v*w0.w;
                a1.x += x1v*w1.x; a1.y += x1v*w1.y; a1.z += x1v*w1.z; a1.w += x1v*w1.w;
            }
            l2S[r][c0]   = silu_f(a0.x + a1.x); l2S[r][c0+1] = silu_f(a0.y + a1.y);
            l2S[r][c0+2] = silu_f(a0.z + a1.z); l2S[r][c0+3] = silu_f(a0.w + a1.w);
        }
        __syncthreads();
        {
            float4 a0 = *(const float4*)&ob3[c0];
            float4 a1 = make_float4(0,0,0,0);
            #pragma unroll 8
            for (int i = 0; i < HID; i += 2) {
                float x0v = l2S[r][i], x1v = l2S[r][i+1];
                float4 w0 = *(const float4*)&ow3[i*HID + c0];
                float4 w1 = *(const float4*)&ow3[(i+1)*HID + c0];
                a0.x += x0v*w0.x; a0.y += x0v*w0.y; a0.z += x0v*w0.z; a0.w += x0v*w0.w;
                a1.x += x1v*w1.x; a1.y += x1v*w1.y; a1.z += x1v*w1.z; a1.w += x1v*w1.w;
            }
            float4 o;
            o.x = a0.x + a1.x; o.y = a0.y + a1.y; o.z = a0.z + a1.z; o.w = a0.w + a1.w;
            *(float4*)&out[((b*NE + e0) + r)*LAT + c0] = o;
        }
    }
}

extern "C" void kernel_launch(void* const* d_in, const int* in_sizes, int n_in,
                              void* d_out, int out_size, void* d_ws, size_t ws_size,
                              hipStream_t stream) {
    Params prm;
    prm.h        = (const float*)d_in[0];
    prm.h_full   = (const float*)d_in[1];
    prm.e_feat   = (const float*)d_in[2];
    prm.att_dist = (const float*)d_in[3];
    prm.att_vec  = (const float*)d_in[4];
    prm.z_emb    = (const float*)d_in[5];
    prm.rw1 = (const float*)d_in[6];  prm.rb1 = (const float*)d_in[7];
    prm.rw2 = (const float*)d_in[8];  prm.rb2 = (const float*)d_in[9];
    prm.ew1 = (const float*)d_in[10]; prm.eb1 = (const float*)d_in[11];
    prm.ew2 = (const float*)d_in[12]; prm.eb2 = (const float*)d_in[13];
    prm.qw1 = (const float*)d_in[14]; prm.qb1 = (const float*)d_in[15];
    prm.qw2 = (const float*)d_in[16]; prm.qb2 = (const float*)d_in[17];
    prm.qw3 = (const float*)d_in[18]; prm.qb3 = (const float*)d_in[19];
    prm.kw1 = (const float*)d_in[20]; prm.kb1 = (const float*)d_in[21];
    prm.kw2 = (const float*)d_in[22]; prm.kb2 = (const float*)d_in[23];
    prm.kw3 = (const float*)d_in[24]; prm.kb3 = (const float*)d_in[25];
    prm.ow1 = (const float*)d_in[26]; prm.ob1 = (const float*)d_in[27];
    prm.ow2 = (const float*)d_in[28]; prm.ob2 = (const float*)d_in[29];
    prm.ow3 = (const float*)d_in[30]; prm.ob3 = (const float*)d_in[31];
    prm.z        = (const int*)d_in[32];
    prm.absorber = (const int*)d_in[34];
    prm.att_dst  = (const int*)d_in[35];

    float* ws = (float*)d_ws;
    prm.inv     = (int*)ws;                    // 1536
    prm.y1E     = ws + 1536;                   // 3072
    prm.envE    = ws + 4608;                   // 1024
    prm.kmat    = ws + 5632;                   // 196608 (1536x128)
    prm.qmat    = ws + 202240;                 // 524288 (4096x128)
    prm.gexp    = ws + 726528;                 // 20480
    prm.virr    = ws + 747008;                 // 122880 (1536x80)
    prm.habs1   = ws + 869888;                 // 2048
    prm.ec      = ws + 871936;                 // 32768
    prm.scoresW = ws + 904704;                 // 393216 (4096x96)
    prm.tpwE    = (__half*)(ws + 1297920);     // 4718592 halves
    prm.rw2T    = (__half*)(ws + 3657216);     // 589824 halves (4608x128)
    prm.hiddenH = (__half*)(ws + 3952128);     // 131072 halves (1024x128)
    prm.bar     = (int*)(ws + 4100096);        // barrier counter (re-zeroed each launch)

    prm.out = (float*)d_out;

    k_init<<<1, 64, 0, stream>>>(prm.bar);
    k_mega<<<GRID_BLKS, 256, 0, stream>>>(prm);
}

// Round 4
// 242.681 us; speedup vs baseline: 2.0357x; 2.0357x over previous
//
#include <hip/hip_runtime.h>
#include <hip/hip_fp16.h>
#include <math.h>

#define BB 16
#define NN 96
#define NE 256
#define FF (BB*NN)      // 1536
#define ATOM 128
#define EDIM 16
#define HID 128
#define LAT 128
#define RBFN 16
#define CUTOFF 5.0f
#define ZEMB 32
#define E_ATT 1024
#define M0I 64
#define M1I 32
#define M0O 32
#define M1O 16
#define NODE_DIM 160
#define OUT_DIM 80
#define INVD 48
#define WNUM 4608
#define SEG1 2048
#define SEG2 3072
#define SEG3 3584

// ---- stage1 block layout: heavy classes first ----
#define S1_EDGE 256                 // [0,256)   4 edges/block
#define S1_Q    512                 // [256,768) 8 q-rows/block (self-contained layer1!)
#define S1_GATE 16                  // [768,784)
#define S1_TRANS 144                // [784,928)
#define S1_PREP_AT 928
#define STAGE1_BLKS 929

#define MFMA_BLKS (36*16)           // 576
#define SCORE_BLKS 128
#define MQ_BLKS (MFMA_BLKS + SCORE_BLKS)  // 704

#define ST_BLKS 512                 // TP only

typedef _Float16 half8_t __attribute__((ext_vector_type(8)));
typedef float float4v __attribute__((ext_vector_type(4)));

__device__ __forceinline__ float silu_f(float x) { return x / (1.0f + expf(-x)); }

// ---------------- stage1 mega-kernel ----------------
__global__ __launch_bounds__(256) void k_stage1(
    const float* __restrict__ h, const float* __restrict__ z_emb, const int* __restrict__ z,
    const int* __restrict__ absorber, const float* __restrict__ e_feat,
    const int* __restrict__ att_dst, const float* __restrict__ att_dist,
    const float* __restrict__ att_vec,
    const float* __restrict__ rw1, const float* __restrict__ rb1,
    const float* __restrict__ kw1, const float* __restrict__ kb1,
    const float* __restrict__ kw2, const float* __restrict__ kb2,
    const float* __restrict__ kw3, const float* __restrict__ kb3,
    const float* __restrict__ qw1, const float* __restrict__ qb1,
    const float* __restrict__ qw2, const float* __restrict__ qb2,
    const float* __restrict__ qw3, const float* __restrict__ qb3,
    const float* __restrict__ ew1, const float* __restrict__ eb1,
    const float* __restrict__ ew2, const float* __restrict__ eb2,
    const float* __restrict__ rw2,
    __half* __restrict__ hiddenH, float* __restrict__ kmatw,
    float* __restrict__ qmat, float* __restrict__ gexp,
    __half* __restrict__ rw2T,
    int* __restrict__ inv, float* __restrict__ y1E, float* __restrict__ envE)
{
    __shared__ float smem[3488];
    int blk = blockIdx.x;
    int t = threadIdx.x;

    if (blk < S1_EDGE) {
        float (*sin1)[184] = (float(*)[184])smem;            // 4 x 184 (177 used)
        float (*l1S)[128]  = (float(*)[128])(smem + 736);
        float (*l2S)[128]  = (float(*)[128])(smem + 736 + 512);
        int w = t >> 6;           // wave = edge slot
        int c = t & 63;
        int e = blk*4 + w;
        int f = att_dst[e];
        int b = f / NN, nn = f - b*NN;
        float d = att_dist[e];
        {   // h[f]: 2 floats per lane (coalesced per wave)
            float2 hv = *(const float2*)&h[f*ATOM + 2*c];
            sin1[w][2*c] = hv.x; sin1[w][2*c + 1] = hv.y;
        }
        if (c < ZEMB) sin1[w][ATOM + c] = z_emb[z[f]*ZEMB + c];
        if (c >= 32 && c < 48) {
            int j = c - 32;
            const float delta = CUTOFF / (RBFN - 1);
            float diff = d - j*delta;
            sin1[w][ATOM + ZEMB + 1 + j] = expf(-diff*diff / (2.0f*delta*delta));
        }
        if (c == 48) sin1[w][ATOM + ZEMB] = (absorber[b] == nn) ? 1.0f : 0.0f;
        __syncthreads();
        int c2 = 2*c;
        {   // hidden = silu(w_in @ rw1 + rb1): 49 -> 128 (edge-indexed)
            float2 a0 = *(const float2*)&rb1[c2];
            float2 a1 = make_float2(0.f, 0.f);
            #pragma unroll 8
            for (int i = 0; i < 48; i += 2) {
                float x0v = sin1[w][ATOM + i], x1v = sin1[w][ATOM + i + 1];
                float2 w0 = *(const float2*)&rw1[i*HID + c2];
                float2 w1 = *(const float2*)&rw1[(i+1)*HID + c2];
                a0.x += x0v*w0.x; a0.y += x0v*w0.y;
                a1.x += x1v*w1.x; a1.y += x1v*w1.y;
            }
            {
                float x0v = sin1[w][ATOM + 48];
                float2 w0 = *(const float2*)&rw1[48*HID + c2];
                a0.x += x0v*w0.x; a0.y += x0v*w0.y;
            }
            *(__half2*)&hiddenH[e*HID + c2] =
                __floats2half2_rn(silu_f(a0.x + a1.x), silu_f(a0.y + a1.y));
        }
        {   // k layer 1: 177 -> 128
            float2 a0 = *(const float2*)&kb1[c2];
            float2 a1 = make_float2(0.f, 0.f);
            #pragma unroll 8
            for (int i = 0; i < 176; i += 2) {
                float x0v = sin1[w][i], x1v = sin1[w][i + 1];
                float2 w0 = *(const float2*)&kw1[i*HID + c2];
                float2 w1 = *(const float2*)&kw1[(i+1)*HID + c2];
                a0.x += x0v*w0.x; a0.y += x0v*w0.y;
                a1.x += x1v*w1.x; a1.y += x1v*w1.y;
            }
            {
                float x0v = sin1[w][176];
                float2 w0 = *(const float2*)&kw1[176*HID + c2];
                a0.x += x0v*w0.x; a0.y += x0v*w0.y;
            }
            l1S[w][c2] = silu_f(a0.x + a1.x); l1S[w][c2+1] = silu_f(a0.y + a1.y);
        }
        __syncthreads();
        {   // k layer 2
            float2 a0 = *(const float2*)&kb2[c2];
            float2 a1 = make_float2(0.f, 0.f);
            #pragma unroll 8
            for (int i = 0; i < HID; i += 2) {
                float x0v = l1S[w][i], x1v = l1S[w][i + 1];
                float2 w0 = *(const float2*)&kw2[i*HID + c2];
                float2 w1 = *(const float2*)&kw2[(i+1)*HID + c2];
                a0.x += x0v*w0.x; a0.y += x0v*w0.y;
                a1.x += x1v*w1.x; a1.y += x1v*w1.y;
            }
            l2S[w][c2] = silu_f(a0.x + a1.x); l2S[w][c2+1] = silu_f(a0.y + a1.y);
        }
        __syncthreads();
        {   // k layer 3 -> kmat (node-indexed, attended rows only)
            float2 a0 = *(const float2*)&kb3[c2];
            float2 a1 = make_float2(0.f, 0.f);
            #pragma unroll 8
            for (int i = 0; i < HID; i += 2) {
                float x0v = l2S[w][i], x1v = l2S[w][i + 1];
                float2 w0 = *(const float2*)&kw3[i*HID + c2];
                float2 w1 = *(const float2*)&kw3[(i+1)*HID + c2];
                a0.x += x0v*w0.x; a0.y += x0v*w0.y;
                a1.x += x1v*w1.x; a1.y += x1v*w1.y;
            }
            float2 o; o.x = a0.x + a1.x; o.y = a0.y + a1.y;
            *(float2*)&kmatw[f*HID + c2] = o;
        }
    } else if (blk < S1_EDGE + S1_Q) {
        // q-MLP, self-contained: layer1 = silu(h_abs@qw1[0:128] + ef@qw1[128:144] + qb1)
        float* hA          = smem;                         // 128
        float (*ef)[16]    = (float(*)[16])(smem + 128);   // 8x16
        float (*part)[128] = (float(*)[128])(smem + 256);  // 8x128
        float* l1S         = smem + 1280;                  // 8x128
        float* l2S         = smem + 2304;                  // 8x128  (total 3328)
        int idx = blk - S1_EDGE;
        int r0 = idx * 8;          // 8 rows of (b*NE+e), same b (256 % 8 == 0)
        int b  = r0 >> 8;
        int e8 = r0 & 255;
        if (t < 32) *(float4*)&hA[t*4] = *(const float4*)&h[(b*NN + absorber[b])*ATOM + t*4];
        if (t >= 128 && t < 256) { int e = (t - 128) >> 4, j = t & 15; ef[e][j] = e_feat[(e8 + e)*EDIM + j]; }
        __syncthreads();
        int r = t >> 5, c0 = (t & 31)*4;
        {   // partial h_abs GEMV over k-chunk r (16 k's)
            float4 a0 = make_float4(0,0,0,0);
            int k0 = r*16;
            #pragma unroll
            for (int k = 0; k < 16; k++) {
                float hv = hA[k0 + k];
                float4 w0 = *(const float4*)&qw1[(k0 + k)*HID + c0];
                a0.x += hv*w0.x; a0.y += hv*w0.y; a0.z += hv*w0.z; a0.w += hv*w0.w;
            }
            *(float4*)&part[r][c0] = a0;
        }
        __syncthreads();
        {   // combine + edge-feature part + bias -> l1S[row r]
            float4 s = *(const float4*)&qb1[c0];
            #pragma unroll
            for (int g = 0; g < 8; g++) {
                float4 pg = *(const float4*)&part[g][c0];
                s.x += pg.x; s.y += pg.y; s.z += pg.z; s.w += pg.w;
            }
            #pragma unroll
            for (int j = 0; j < 16; j++) {
                float a = ef[r][j];
                float4 w0 = *(const float4*)&qw1[(ATOM + j)*HID + c0];
                s.x += a*w0.x; s.y += a*w0.y; s.z += a*w0.z; s.w += a*w0.w;
            }
            l1S[r*128 + c0]   = silu_f(s.x); l1S[r*128 + c0+1] = silu_f(s.y);
            l1S[r*128 + c0+2] = silu_f(s.z); l1S[r*128 + c0+3] = silu_f(s.w);
        }
        __syncthreads();
        {   // layer 2
            float4 a0 = *(const float4*)&qb2[c0];
            float4 a1 = make_float4(0,0,0,0);
            #pragma unroll 8
            for (int i = 0; i < HID; i += 2) {
                float x0v = l1S[r*128 + i], x1v = l1S[r*128 + i+1];
                float4 w0 = *(const float4*)&qw2[i*HID + c0];
                float4 w1 = *(const float4*)&qw2[(i+1)*HID + c0];
                a0.x += x0v*w0.x; a0.y += x0v*w0.y; a0.z += x0v*w0.z; a0.w += x0v*w0.w;
                a1.x += x1v*w1.x; a1.y += x1v*w1.y; a1.z += x1v*w1.z; a1.w += x1v*w1.w;
            }
            l2S[r*128 + c0]   = silu_f(a0.x + a1.x); l2S[r*128 + c0+1] = silu_f(a0.y + a1.y);
            l2S[r*128 + c0+2] = silu_f(a0.z + a1.z); l2S[r*128 + c0+3] = silu_f(a0.w + a1.w);
        }
        __syncthreads();
        {   // layer 3 -> qmat
            float4 a0 = *(const float4*)&qb3[c0];
            float4 a1 = make_float4(0,0,0,0);
            #pragma unroll 8
            for (int i = 0; i < HID; i += 2) {
                float x0v = l2S[r*128 + i], x1v = l2S[r*128 + i+1];
                float4 w0 = *(const float4*)&qw3[i*HID + c0];
                float4 w1 = *(const float4*)&qw3[(i+1)*HID + c0];
                a0.x += x0v*w0.x; a0.y += x0v*w0.y; a0.z += x0v*w0.z; a0.w += x0v*w0.w;
                a1.x += x1v*w1.x; a1.y += x1v*w1.y; a1.z += x1v*w1.z; a1.w += x1v*w1.w;
            }
            float4 o;
            o.x = a0.x + a1.x; o.y = a0.y + a1.y; o.z = a0.z + a1.z; o.w = a0.w + a1.w;
            *(float4*)&qmat[(r0 + r)*LAT + c0] = o;
        }
    } else if (blk < S1_EDGE + S1_Q + S1_GATE) {
        float (*ef)[16]   = (float(*)[16])smem;
        float (*l1g)[128] = (float(*)[128])(smem + 256);
        float (*gg)[48]   = (float(*)[48])(smem + 256 + 2048);
        int e0 = (blk - S1_EDGE - S1_Q) * 16;
        { int e = t >> 4, i = t & 15; ef[e][i] = e_feat[(e0 + e)*EDIM + i]; }
        __syncthreads();
        int r = t >> 4, c0 = (t & 15)*8;
        {
            float4 a0 = *(const float4*)&eb1[c0];
            float4 a1 = *(const float4*)&eb1[c0 + 4];
            #pragma unroll
            for (int i = 0; i < EDIM; i++) {
                float a = ef[r][i];
                float4 w0 = *(const float4*)&ew1[i*HID + c0];
                float4 w1 = *(const float4*)&ew1[i*HID + c0 + 4];
                a0.x += a*w0.x; a0.y += a*w0.y; a0.z += a*w0.z; a0.w += a*w0.w;
                a1.x += a*w1.x; a1.y += a*w1.y; a1.z += a*w1.z; a1.w += a*w1.w;
            }
            l1g[r][c0]   = silu_f(a0.x); l1g[r][c0+1] = silu_f(a0.y);
            l1g[r][c0+2] = silu_f(a0.z); l1g[r][c0+3] = silu_f(a0.w);
            l1g[r][c0+4] = silu_f(a1.x); l1g[r][c0+5] = silu_f(a1.y);
            l1g[r][c0+6] = silu_f(a1.z); l1g[r][c0+7] = silu_f(a1.w);
        }
        __syncthreads();
        for (int u = t; u < 16*48; u += 256) {
            int e = u / 48, j = u - 48*(u/48);
            float acc = eb2[j];
            #pragma unroll 4
            for (int i = 0; i < HID; i++) acc += l1g[e][i]*ew2[i*48 + j];
            gg[e][j] = acc;
        }
        __syncthreads();
        for (int u = t; u < 16*80; u += 256) {
            int e = u / 80, cc = u - 80*(u/80);
            gexp[(e0 + e)*OUT_DIM + cc] = (cc < M0O) ? gg[e][cc] : gg[e][M0O + (cc - M0O)/3];
        }
    } else if (blk < S1_EDGE + S1_Q + S1_GATE + S1_TRANS) {
        __half* lds = (__half*)smem;  // [64][66]
        int tb = blk - (S1_EDGE + S1_Q + S1_GATE);
        int nt = tb % 72, kt = tb / 72;
        int n0 = nt*64, k0 = kt*64;
        for (int p = 0; p < 16; p++) {
            int idx = t + 256*p;
            int kk = idx >> 6, nn = idx & 63;
            lds[nn*66 + kk] = __float2half(rw2[(k0+kk)*WNUM + n0+nn]);
        }
        __syncthreads();
        for (int p = 0; p < 16; p++) {
            int idx = t + 256*p;
            int nn = idx >> 6, kk = idx & 63;
            rw2T[(n0+nn)*HID + k0+kk] = lds[nn*66 + kk];
        }
    } else {
        // prep: inv init + per-edge y1/env + scatter
        for (int p = 0; p < 6; p++) inv[t + 256*p] = -1;
        for (int p = 0; p < 4; p++) {
            int e = t + 256*p;
            float d = att_dist[e];
            envE[e] = (d < CUTOFF) ? 0.5f*(cosf(3.14159265358979323846f*d/CUTOFF) + 1.0f) : 0.0f;
            float vx = att_vec[3*e], vy = att_vec[3*e+1], vz = att_vec[3*e+2];
            float nrm = sqrtf(vx*vx + vy*vy + vz*vz);
            float is = 1.0f / fmaxf(nrm, 1e-8f);
            const float s3 = 1.7320508075688772f;
            y1E[3*e]   = s3*vx*is;
            y1E[3*e+1] = s3*vy*is;
            y1E[3*e+2] = s3*vz*is;
        }
        __syncthreads();
        for (int p = 0; p < 4; p++) { int e = t + 256*p; inv[att_dst[e]] = e; }
    }
}

// ---------------- MFMA tpw GEMM + scores GEMM (independent block ranges) ----------------
__global__ __launch_bounds__(256) void k_mq(
    const __half* __restrict__ hiddenH, const __half* __restrict__ rw2T,
    const float* __restrict__ rb2,
    const float* __restrict__ qmat, const float* __restrict__ kmat,
    const int* __restrict__ inv,
    __half* __restrict__ tpwE, float* __restrict__ scoresW)
{
    __shared__ __align__(16) char smemraw[34176];
    float* smem = (float*)smemraw;
    int blk = blockIdx.x;
    int t = threadIdx.x;
    if (blk < MFMA_BLKS) {
        int colTile = blk % 36;
        int rowGrp  = blk / 36;
        int wv = t >> 6;
        int lane = t & 63;
        int m0 = (rowGrp*4 + wv) * 16;
        int n0 = colTile * 128;
        int mrow = lane & 15, quad = lane >> 4;
        __half* cS = (__half*)smemraw + wv * (16*136);
        const _Float16* hp = (const _Float16*)hiddenH + (m0 + mrow)*HID + quad*8;
        half8_t af[4];
        #pragma unroll
        for (int kc = 0; kc < 4; kc++) af[kc] = *(const half8_t*)(hp + kc*32);
        #pragma unroll
        for (int nt = 0; nt < 8; nt++) {
            const _Float16* bp = (const _Float16*)rw2T + (n0 + nt*16 + mrow)*HID + quad*8;
            float4v acc = {0.f, 0.f, 0.f, 0.f};
            #pragma unroll
            for (int kc = 0; kc < 4; kc++) {
                half8_t bf = *(const half8_t*)(bp + kc*32);
                acc = __builtin_amdgcn_mfma_f32_16x16x32_f16(af[kc], bf, acc, 0, 0, 0);
            }
            float bias = rb2[n0 + nt*16 + mrow];
            #pragma unroll
            for (int r = 0; r < 4; r++)
                cS[(quad*4 + r)*136 + nt*16 + mrow] = __float2half(acc[r] + bias);
        }
        #pragma unroll
        for (int p = 0; p < 4; p++) {
            int chunk = lane + 64*p;
            int row = chunk >> 4, c8 = (chunk & 15)*8;
            float4 v = *(float4*)&cS[row*136 + c8];
            *(float4*)&tpwE[(long)(m0 + row)*WNUM + n0 + c8] = v;
        }
    } else {
        int u = blk - MFMA_BLKS;
        int b  = u >> 3;
        int e0 = (u & 7) * 32;
        float (*Qs)[132] = (float(*)[132])smem;
        float (*Kt)[132] = (float(*)[132])(smem + 32*132);
        float* mS = smem + 2*32*132;
        for (int p = 0; p < 4; p++) {
            int idx = t + 256*p; int e = idx >> 5, i4 = idx & 31;
            *(float4*)&Qs[e][i4*4] = *(const float4*)&qmat[(b*NE + e0 + e)*LAT + i4*4];
        }
        if (t < NN) mS[t] = ((unsigned)inv[b*NN + t] < E_ATT) ? 1.0f : 0.0f;
        int te = t >> 5, tn = t & 31;
        float acc[4][3] = {};
        for (int nt = 0; nt < 3; nt++) {
            __syncthreads();
            for (int p = 0; p < 4; p++) {
                int idx = t + 256*p; int n = idx >> 5, i4 = idx & 31;
                *(float4*)&Kt[n][i4*4] = *(const float4*)&kmat[(b*NN + nt*32 + n)*LAT + i4*4];
            }
            __syncthreads();
            for (int i = 0; i < LAT; i++) {
                float bv = Kt[tn][i];
                acc[0][nt] += Qs[te*4 + 0][i]*bv;
                acc[1][nt] += Qs[te*4 + 1][i]*bv;
                acc[2][nt] += Qs[te*4 + 2][i]*bv;
                acc[3][nt] += Qs[te*4 + 3][i]*bv;
            }
        }
        const float scale = 0.04419417382415922f;  // (1/HEADS)*HD^-0.5
        #pragma unroll
        for (int j = 0; j < 4; j++)
            #pragma unroll
            for (int jj = 0; jj < 3; jj++) {
                int n = tn + 32*jj;
                float s = (mS[n] != 0.f) ? acc[j][jj]*scale : -1e9f;
                scoresW[((b*NE) + e0 + te*4 + j)*NN + n] = s;
            }
    }
}

// ---------------- tensor product only ----------------
__global__ __launch_bounds__(256) void k_st(
    const float* __restrict__ h_full, const __half* __restrict__ tpwE,
    const int* __restrict__ att_dst,
    const float* __restrict__ envE, const float* __restrict__ y1E,
    float* __restrict__ virr)
{
    __shared__ float smem[512];
    int blk = blockIdx.x;
    int t = threadIdx.x;
    int sub = t >> 7, tt = t & 127;
    int e = blk*2 + sub;
    int f = att_dst[e];
    float* x0  = smem + sub*256;
    float* x1f = smem + sub*256 + 64;
    float* xy  = smem + sub*256 + 160;
    float* y1s = smem + sub*256 + 192;
    const float* hf = h_full + f*NODE_DIM;
    if (tt < M0I) x0[tt] = hf[tt];
    if (tt < M1I*3) x1f[tt] = hf[M0I + tt];
    if (tt < 3) y1s[tt] = y1E[3*e + tt];
    __syncthreads();
    if (tt < M1I) xy[tt] = x1f[3*tt]*y1s[0] + x1f[3*tt+1]*y1s[1] + x1f[3*tt+2]*y1s[2];
    __syncthreads();
    float scale = envE[e];
    const __half* w = tpwE + (long)e*WNUM;
    const float alpha = 0.10206207261596575f;  // 1/sqrt(96)
    const float cc = 0.5773502691896258f;      // 1/sqrt(3)
    if (tt < M0O) {
        float t00 = 0.f, t11 = 0.f;
        #pragma unroll 4
        for (int i = 0; i < M0I; i++) t00 += x0[i]*__half2float(w[i*M0O + tt]);
        #pragma unroll 4
        for (int i = 0; i < M1I; i++) t11 += xy[i]*__half2float(w[SEG3 + i*M0O + tt]);
        virr[f*OUT_DIM + tt] = alpha*(t00 + cc*t11)*scale;
    } else if (tt < M0O + 3*M1O) {
        int idx = tt - M0O; int o = idx/3, m = idx - 3*o;
        float t01 = 0.f, t10 = 0.f;
        #pragma unroll 4
        for (int i = 0; i < M0I; i++) t01 += x0[i]*__half2float(w[SEG1 + i*M1O + o]);
        #pragma unroll 4
        for (int i = 0; i < M1I; i++) t10 += x1f[i*3 + m]*__half2float(w[SEG2 + i*M1O + o]);
        virr[f*OUT_DIM + tt] = alpha*cc*(t01*y1s[m] + t10)*scale;
    }
}

// ---------------- fused attention(softmax+PV) + final MLP ----------------
__global__ __launch_bounds__(256) void k_attf(
    const float* __restrict__ scoresW, const int* __restrict__ inv,
    const float* __restrict__ virr, const float* __restrict__ gexp,
    const float* __restrict__ ow1, const float* __restrict__ ob1,
    const float* __restrict__ ow2, const float* __restrict__ ob2,
    const float* __restrict__ ow3, const float* __restrict__ ob3,
    float* __restrict__ out)
{
    int b  = blockIdx.x >> 5;
    int e0 = (blockIdx.x & 31) * 8;
    int t = threadIdx.x;
    __shared__ float aS[8][100];
    __shared__ float gS[8][84];
    __shared__ float ocS[8][84];
    __shared__ float mS[NN];
    __shared__ float inS[8][INVD];
    __shared__ float l1S[8][HID];
    __shared__ float l2S[8][HID];

    for (int p = 0; p < 3; p++) {
        int idx = t + 256*p;
        int el = idx / NN, n = idx - NN*(idx/NN);
        aS[el][n] = scoresW[((b*NE) + e0 + el)*NN + n];
    }
    if (t < 160) {
        int el = t / 20, c4 = t - 20*(t/20);
        *(float4*)&gS[el][c4*4] = *(const float4*)&gexp[(e0 + el)*OUT_DIM + c4*4];
    }
    if (t < NN) mS[t] = ((unsigned)inv[b*NN + t] < E_ATT) ? 1.0f : 0.0f;
    __syncthreads();

    {
        int el = t >> 5;
        int ng = t & 31;
        float s0 = aS[el][ng], s1 = aS[el][ng + 32], s2 = aS[el][ng + 64];
        float m0 = mS[ng], m1 = mS[ng + 32], m2 = mS[ng + 64];
        float mx = fmaxf(s0, fmaxf(s1, s2));
        #pragma unroll
        for (int off = 1; off < 32; off <<= 1) mx = fmaxf(mx, __shfl_xor(mx, off));
        float e0v = expf(s0 - mx), e1v = expf(s1 - mx), e2v = expf(s2 - mx);
        float sm = e0v + e1v + e2v;
        #pragma unroll
        for (int off = 1; off < 32; off <<= 1) sm += __shfl_xor(sm, off);
        float r = 1.0f / sm;
        float p0 = m0*e0v*r, p1 = m1*e1v*r, p2 = m2*e2v*r;
        float ss = p0 + p1 + p2;
        #pragma unroll
        for (int off = 1; off < 32; off <<= 1) ss += __shfl_xor(ss, off);
        float is = 1.0f / fmaxf(ss, 1e-8f);
        aS[el][ng]      = p0*is;
        aS[el][ng + 32] = p1*is;
        aS[el][ng + 64] = p2*is;
    }
    __syncthreads();

    if (t < 160) {
        int el = t / 20, c4 = t - 20*(t/20);
        const float* vp = virr + (long)b*NN*OUT_DIM + c4*4;
        float4 acc = make_float4(0,0,0,0);
        #pragma unroll 4
        for (int n = 0; n < NN; n++) {
            float a = aS[el][n];
            float4 v = *(const float4*)&vp[n*OUT_DIM];
            acc.x += a*v.x; acc.y += a*v.y; acc.z += a*v.z; acc.w += a*v.w;
        }
        float4 g = *(float4*)&gS[el][c4*4];
        float4 o; o.x = acc.x*g.x; o.y = acc.y*g.y; o.z = acc.z*g.z; o.w = acc.w*g.w;
        *(float4*)&ocS[el][c4*4] = o;
    }
    __syncthreads();

    for (int u = t; u < 8*INVD; u += 256) {
        int el = u / INVD, j = u - INVD*(u/INVD);
        float val;
        if (j < M0O) val = ocS[el][j];
        else {
            int o = j - M0O;
            float x = ocS[el][M0O + 3*o], y = ocS[el][M0O + 3*o + 1], zz = ocS[el][M0O + 3*o + 2];
            val = sqrtf(x*x + y*y + zz*zz + 1e-12f);
        }
        inS[el][j] = val;
    }
    __syncthreads();

    int r = t >> 5, c0 = (t & 31)*4;
    {
        float4 a0 = *(const float4*)&ob1[c0];
        float4 a1 = make_float4(0,0,0,0);
        #pragma unroll 8
        for (int i = 0; i < INVD; i += 2) {
            float x0v = inS[r][i], x1v = inS[r][i+1];
            float4 w0 = *(const float4*)&ow1[i*HID + c0];
            float4 w1 = *(const float4*)&ow1[(i+1)*HID + c0];
            a0.x += x0v*w0.x; a0.y += x0v*w0.y; a0.z += x0v*w0.z; a0.w += x0v*w0.w;
            a1.x += x1v*w1.x; a1.y += x1v*w1.y; a1.z += x1v*w1.z; a1.w += x1v*w1.w;
        }
        l1S[r][c0]   = silu_f(a0.x + a1.x); l1S[r][c0+1] = silu_f(a0.y + a1.y);
        l1S[r][c0+2] = silu_f(a0.z + a1.z); l1S[r][c0+3] = silu_f(a0.w + a1.w);
    }
    __syncthreads();
    {
        float4 a0 = *(const float4*)&ob2[c0];
        float4 a1 = make_float4(0,0,0,0);
        #pragma unroll 8
        for (int i = 0; i < HID; i += 2) {
            float x0v = l1S[r][i], x1v = l1S[r][i+1];
            float4 w0 = *(const float4*)&ow2[i*HID + c0];
            float4 w1 = *(const float4*)&ow2[(i+1)*HID + c0];
            a0.x += x0v*w0.x; a0.y += x0v*w0.y; a0.z += x0v*w0.z; a0.w += x0v*w0.w;
            a1.x += x1v*w1.x; a1.y += x1v*w1.y; a1.z += x1v*w1.z; a1.w += x1v*w1.w;
        }
        l2S[r][c0]   = silu_f(a0.x + a1.x); l2S[r][c0+1] = silu_f(a0.y + a1.y);
        l2S[r][c0+2] = silu_f(a0.z + a1.z); l2S[r][c0+3] = silu_f(a0.w + a1.w);
    }
    __syncthreads();
    {
        float4 a0 = *(const float4*)&ob3[c0];
        float4 a1 = make_float4(0,0,0,0);
        #pragma unroll 8
        for (int i = 0; i < HID; i += 2) {
            float x0v = l2S[r][i], x1v = l2S[r][i+1];
            float4 w0 = *(const float4*)&ow3[i*HID + c0];
            float4 w1 = *(const float4*)&ow3[(i+1)*HID + c0];
            a0.x += x0v*w0.x; a0.y += x0v*w0.y; a0.z += x0v*w0.z; a0.w += x0v*w0.w;
            a1.x += x1v*w1.x; a1.y += x1v*w1.y; a1.z += x1v*w1.z; a1.w += x1v*w1.w;
        }
        float4 o;
        o.x = a0.x + a1.x; o.y = a0.y + a1.y; o.z = a0.z + a1.z; o.w = a0.w + a1.w;
        *(float4*)&out[((b*NE + e0) + r)*LAT + c0] = o;
    }
}

extern "C" void kernel_launch(void* const* d_in, const int* in_sizes, int n_in,
                              void* d_out, int out_size, void* d_ws, size_t ws_size,
                              hipStream_t stream) {
    const float* h        = (const float*)d_in[0];
    const float* h_full   = (const float*)d_in[1];
    const float* e_feat   = (const float*)d_in[2];
    const float* att_dist = (const float*)d_in[3];
    const float* att_vec  = (const float*)d_in[4];
    const float* z_emb    = (const float*)d_in[5];
    const float* rw1 = (const float*)d_in[6];  const float* rb1 = (const float*)d_in[7];
    const float* rw2 = (const float*)d_in[8];  const float* rb2 = (const float*)d_in[9];
    const float* ew1 = (const float*)d_in[10]; const float* eb1 = (const float*)d_in[11];
    const float* ew2 = (const float*)d_in[12]; const float* eb2 = (const float*)d_in[13];
    const float* qw1 = (const float*)d_in[14]; const float* qb1 = (const float*)d_in[15];
    const float* qw2 = (const float*)d_in[16]; const float* qb2 = (const float*)d_in[17];
    const float* qw3 = (const float*)d_in[18]; const float* qb3 = (const float*)d_in[19];
    const float* kw1 = (const float*)d_in[20]; const float* kb1 = (const float*)d_in[21];
    const float* kw2 = (const float*)d_in[22]; const float* kb2 = (const float*)d_in[23];
    const float* kw3 = (const float*)d_in[24]; const float* kb3 = (const float*)d_in[25];
    const float* ow1 = (const float*)d_in[26]; const float* ob1 = (const float*)d_in[27];
    const float* ow2 = (const float*)d_in[28]; const float* ob2 = (const float*)d_in[29];
    const float* ow3 = (const float*)d_in[30]; const float* ob3 = (const float*)d_in[31];
    const int* z        = (const int*)d_in[32];
    const int* absorber = (const int*)d_in[34];
    const int* att_dst  = (const int*)d_in[35];

    float* ws = (float*)d_ws;
    int*   inv     = (int*)ws;                    // 1536
    float* y1E     = ws + 1536;                   // 3072
    float* envE    = ws + 4608;                   // 1024
    float* kmat    = ws + 5632;                   // 196608 (1536x128)
    float* qmat    = ws + 202240;                 // 524288 (4096x128)
    float* gexp    = ws + 726528;                 // 20480
    float* virr    = ws + 747008;                 // 122880 (1536x80)
    float* scoresW = ws + 904704;                 // 393216 (4096x96)
    __half* tpwE   = (__half*)(ws + 1297920);     // 4718592 halves
    __half* rw2T   = (__half*)(ws + 3657216);     // 589824 halves (4608x128)
    __half* hiddenH= (__half*)(ws + 3952128);     // 131072 halves (1024x128)

    float* out = (float*)d_out;

    k_stage1<<<STAGE1_BLKS, 256, 0, stream>>>(h, z_emb, z, absorber, e_feat,
                                              att_dst, att_dist, att_vec,
                                              rw1, rb1, kw1, kb1, kw2, kb2, kw3, kb3,
                                              qw1, qb1, qw2, qb2, qw3, qb3,
                                              ew1, eb1, ew2, eb2, rw2,
                                              hiddenH, kmat, qmat, gexp, rw2T,
                                              inv, y1E, envE);
    k_mq<<<MQ_BLKS, 256, 0, stream>>>(hiddenH, rw2T, rb2, qmat, kmat, inv,
                                      tpwE, scoresW);
    k_st<<<ST_BLKS, 256, 0, stream>>>(h_full, tpwE, att_dst, envE, y1E, virr);
    k_attf<<<BB*32, 256, 0, stream>>>(scoresW, inv, virr, gexp,
                                      ow1, ob1, ow2, ob2, ow3, ob3, out);
}

// Round 5
// 226.960 us; speedup vs baseline: 2.1767x; 1.0693x over previous
//
#include <hip/hip_runtime.h>
#include <hip/hip_fp16.h>
#include <math.h>

#define BB 16
#define NN 96
#define NE 256
#define FF (BB*NN)      // 1536
#define ATOM 128
#define EDIM 16
#define HID 128
#define LAT 128
#define RBFN 16
#define CUTOFF 5.0f
#define ZEMB 32
#define E_ATT 1024
#define M0I 64
#define M1I 32
#define M0O 32
#define M1O 16
#define NODE_DIM 160
#define OUT_DIM 80
#define INVD 48
#define WNUM 4608
#define SEG1 2048
#define SEG2 3072
#define SEG3 3584

// ---- stage1 block layout (R4-proven) ----
#define S1_EDGE 256                 // [0,256)   4 edges/block
#define S1_Q    512                 // [256,768) 8 q-rows/block
#define S1_GATE 16                  // [768,784)
#define S1_TRANS 144                // [784,928)
#define STAGE1_BLKS 929

// ---- K2: fused GEMM+TP (192) + scores (128) ----
#define TP_BLKS 192                 // 64 edge-tiles x 3 output-slices
#define SCORE_BLKS 128
#define K2_BLKS (TP_BLKS + SCORE_BLKS)  // 320

typedef _Float16 half8_t __attribute__((ext_vector_type(8)));
typedef float float4v __attribute__((ext_vector_type(4)));

__device__ __forceinline__ float silu_f(float x) { return x / (1.0f + expf(-x)); }

// ---------------- stage1 mega-kernel (R4-proven, verbatim) ----------------
__global__ __launch_bounds__(256) void k_stage1(
    const float* __restrict__ h, const float* __restrict__ z_emb, const int* __restrict__ z,
    const int* __restrict__ absorber, const float* __restrict__ e_feat,
    const int* __restrict__ att_dst, const float* __restrict__ att_dist,
    const float* __restrict__ att_vec,
    const float* __restrict__ rw1, const float* __restrict__ rb1,
    const float* __restrict__ kw1, const float* __restrict__ kb1,
    const float* __restrict__ kw2, const float* __restrict__ kb2,
    const float* __restrict__ kw3, const float* __restrict__ kb3,
    const float* __restrict__ qw1, const float* __restrict__ qb1,
    const float* __restrict__ qw2, const float* __restrict__ qb2,
    const float* __restrict__ qw3, const float* __restrict__ qb3,
    const float* __restrict__ ew1, const float* __restrict__ eb1,
    const float* __restrict__ ew2, const float* __restrict__ eb2,
    const float* __restrict__ rw2,
    __half* __restrict__ hiddenH, float* __restrict__ kmatw,
    float* __restrict__ qmat, float* __restrict__ gexp,
    __half* __restrict__ rw2T,
    int* __restrict__ inv, float* __restrict__ y1E, float* __restrict__ envE)
{
    __shared__ float smem[3488];
    int blk = blockIdx.x;
    int t = threadIdx.x;

    if (blk < S1_EDGE) {
        float (*sin1)[184] = (float(*)[184])smem;
        float (*l1S)[128]  = (float(*)[128])(smem + 736);
        float (*l2S)[128]  = (float(*)[128])(smem + 736 + 512);
        int w = t >> 6;
        int c = t & 63;
        int e = blk*4 + w;
        int f = att_dst[e];
        int b = f / NN, nn = f - b*NN;
        float d = att_dist[e];
        {
            float2 hv = *(const float2*)&h[f*ATOM + 2*c];
            sin1[w][2*c] = hv.x; sin1[w][2*c + 1] = hv.y;
        }
        if (c < ZEMB) sin1[w][ATOM + c] = z_emb[z[f]*ZEMB + c];
        if (c >= 32 && c < 48) {
            int j = c - 32;
            const float delta = CUTOFF / (RBFN - 1);
            float diff = d - j*delta;
            sin1[w][ATOM + ZEMB + 1 + j] = expf(-diff*diff / (2.0f*delta*delta));
        }
        if (c == 48) sin1[w][ATOM + ZEMB] = (absorber[b] == nn) ? 1.0f : 0.0f;
        __syncthreads();
        int c2 = 2*c;
        {
            float2 a0 = *(const float2*)&rb1[c2];
            float2 a1 = make_float2(0.f, 0.f);
            #pragma unroll 8
            for (int i = 0; i < 48; i += 2) {
                float x0v = sin1[w][ATOM + i], x1v = sin1[w][ATOM + i + 1];
                float2 w0 = *(const float2*)&rw1[i*HID + c2];
                float2 w1 = *(const float2*)&rw1[(i+1)*HID + c2];
                a0.x += x0v*w0.x; a0.y += x0v*w0.y;
                a1.x += x1v*w1.x; a1.y += x1v*w1.y;
            }
            {
                float x0v = sin1[w][ATOM + 48];
                float2 w0 = *(const float2*)&rw1[48*HID + c2];
                a0.x += x0v*w0.x; a0.y += x0v*w0.y;
            }
            *(__half2*)&hiddenH[e*HID + c2] =
                __floats2half2_rn(silu_f(a0.x + a1.x), silu_f(a0.y + a1.y));
        }
        {
            float2 a0 = *(const float2*)&kb1[c2];
            float2 a1 = make_float2(0.f, 0.f);
            #pragma unroll 8
            for (int i = 0; i < 176; i += 2) {
                float x0v = sin1[w][i], x1v = sin1[w][i + 1];
                float2 w0 = *(const float2*)&kw1[i*HID + c2];
                float2 w1 = *(const float2*)&kw1[(i+1)*HID + c2];
                a0.x += x0v*w0.x; a0.y += x0v*w0.y;
                a1.x += x1v*w1.x; a1.y += x1v*w1.y;
            }
            {
                float x0v = sin1[w][176];
                float2 w0 = *(const float2*)&kw1[176*HID + c2];
                a0.x += x0v*w0.x; a0.y += x0v*w0.y;
            }
            l1S[w][c2] = silu_f(a0.x + a1.x); l1S[w][c2+1] = silu_f(a0.y + a1.y);
        }
        __syncthreads();
        {
            float2 a0 = *(const float2*)&kb2[c2];
            float2 a1 = make_float2(0.f, 0.f);
            #pragma unroll 8
            for (int i = 0; i < HID; i += 2) {
                float x0v = l1S[w][i], x1v = l1S[w][i + 1];
                float2 w0 = *(const float2*)&kw2[i*HID + c2];
                float2 w1 = *(const float2*)&kw2[(i+1)*HID + c2];
                a0.x += x0v*w0.x; a0.y += x0v*w0.y;
                a1.x += x1v*w1.x; a1.y += x1v*w1.y;
            }
            l2S[w][c2] = silu_f(a0.x + a1.x); l2S[w][c2+1] = silu_f(a0.y + a1.y);
        }
        __syncthreads();
        {
            float2 a0 = *(const float2*)&kb3[c2];
            float2 a1 = make_float2(0.f, 0.f);
            #pragma unroll 8
            for (int i = 0; i < HID; i += 2) {
                float x0v = l2S[w][i], x1v = l2S[w][i + 1];
                float2 w0 = *(const float2*)&kw3[i*HID + c2];
                float2 w1 = *(const float2*)&kw3[(i+1)*HID + c2];
                a0.x += x0v*w0.x; a0.y += x0v*w0.y;
                a1.x += x1v*w1.x; a1.y += x1v*w1.y;
            }
            float2 o; o.x = a0.x + a1.x; o.y = a0.y + a1.y;
            *(float2*)&kmatw[f*HID + c2] = o;
        }
    } else if (blk < S1_EDGE + S1_Q) {
        float* hA          = smem;
        float (*ef)[16]    = (float(*)[16])(smem + 128);
        float (*part)[128] = (float(*)[128])(smem + 256);
        float* l1S         = smem + 1280;
        float* l2S         = smem + 2304;
        int idx = blk - S1_EDGE;
        int r0 = idx * 8;
        int b  = r0 >> 8;
        int e8 = r0 & 255;
        if (t < 32) *(float4*)&hA[t*4] = *(const float4*)&h[(b*NN + absorber[b])*ATOM + t*4];
        if (t >= 128 && t < 256) { int e = (t - 128) >> 4, j = t & 15; ef[e][j] = e_feat[(e8 + e)*EDIM + j]; }
        __syncthreads();
        int r = t >> 5, c0 = (t & 31)*4;
        {
            float4 a0 = make_float4(0,0,0,0);
            int k0 = r*16;
            #pragma unroll
            for (int k = 0; k < 16; k++) {
                float hv = hA[k0 + k];
                float4 w0 = *(const float4*)&qw1[(k0 + k)*HID + c0];
                a0.x += hv*w0.x; a0.y += hv*w0.y; a0.z += hv*w0.z; a0.w += hv*w0.w;
            }
            *(float4*)&part[r][c0] = a0;
        }
        __syncthreads();
        {
            float4 s = *(const float4*)&qb1[c0];
            #pragma unroll
            for (int g = 0; g < 8; g++) {
                float4 pg = *(const float4*)&part[g][c0];
                s.x += pg.x; s.y += pg.y; s.z += pg.z; s.w += pg.w;
            }
            #pragma unroll
            for (int j = 0; j < 16; j++) {
                float a = ef[r][j];
                float4 w0 = *(const float4*)&qw1[(ATOM + j)*HID + c0];
                s.x += a*w0.x; s.y += a*w0.y; s.z += a*w0.z; s.w += a*w0.w;
            }
            l1S[r*128 + c0]   = silu_f(s.x); l1S[r*128 + c0+1] = silu_f(s.y);
            l1S[r*128 + c0+2] = silu_f(s.z); l1S[r*128 + c0+3] = silu_f(s.w);
        }
        __syncthreads();
        {
            float4 a0 = *(const float4*)&qb2[c0];
            float4 a1 = make_float4(0,0,0,0);
            #pragma unroll 8
            for (int i = 0; i < HID; i += 2) {
                float x0v = l1S[r*128 + i], x1v = l1S[r*128 + i+1];
                float4 w0 = *(const float4*)&qw2[i*HID + c0];
                float4 w1 = *(const float4*)&qw2[(i+1)*HID + c0];
                a0.x += x0v*w0.x; a0.y += x0v*w0.y; a0.z += x0v*w0.z; a0.w += x0v*w0.w;
                a1.x += x1v*w1.x; a1.y += x1v*w1.y; a1.z += x1v*w1.z; a1.w += x1v*w1.w;
            }
            l2S[r*128 + c0]   = silu_f(a0.x + a1.x); l2S[r*128 + c0+1] = silu_f(a0.y + a1.y);
            l2S[r*128 + c0+2] = silu_f(a0.z + a1.z); l2S[r*128 + c0+3] = silu_f(a0.w + a1.w);
        }
        __syncthreads();
        {
            float4 a0 = *(const float4*)&qb3[c0];
            float4 a1 = make_float4(0,0,0,0);
            #pragma unroll 8
            for (int i = 0; i < HID; i += 2) {
                float x0v = l2S[r*128 + i], x1v = l2S[r*128 + i+1];
                float4 w0 = *(const float4*)&qw3[i*HID + c0];
                float4 w1 = *(const float4*)&qw3[(i+1)*HID + c0];
                a0.x += x0v*w0.x; a0.y += x0v*w0.y; a0.z += x0v*w0.z; a0.w += x0v*w0.w;
                a1.x += x1v*w1.x; a1.y += x1v*w1.y; a1.z += x1v*w1.z; a1.w += x1v*w1.w;
            }
            float4 o;
            o.x = a0.x + a1.x; o.y = a0.y + a1.y; o.z = a0.z + a1.z; o.w = a0.w + a1.w;
            *(float4*)&qmat[(r0 + r)*LAT + c0] = o;
        }
    } else if (blk < S1_EDGE + S1_Q + S1_GATE) {
        float (*ef)[16]   = (float(*)[16])smem;
        float (*l1g)[128] = (float(*)[128])(smem + 256);
        float (*gg)[48]   = (float(*)[48])(smem + 256 + 2048);
        int e0 = (blk - S1_EDGE - S1_Q) * 16;
        { int e = t >> 4, i = t & 15; ef[e][i] = e_feat[(e0 + e)*EDIM + i]; }
        __syncthreads();
        int r = t >> 4, c0 = (t & 15)*8;
        {
            float4 a0 = *(const float4*)&eb1[c0];
            float4 a1 = *(const float4*)&eb1[c0 + 4];
            #pragma unroll
            for (int i = 0; i < EDIM; i++) {
                float a = ef[r][i];
                float4 w0 = *(const float4*)&ew1[i*HID + c0];
                float4 w1 = *(const float4*)&ew1[i*HID + c0 + 4];
                a0.x += a*w0.x; a0.y += a*w0.y; a0.z += a*w0.z; a0.w += a*w0.w;
                a1.x += a*w1.x; a1.y += a*w1.y; a1.z += a*w1.z; a1.w += a*w1.w;
            }
            l1g[r][c0]   = silu_f(a0.x); l1g[r][c0+1] = silu_f(a0.y);
            l1g[r][c0+2] = silu_f(a0.z); l1g[r][c0+3] = silu_f(a0.w);
            l1g[r][c0+4] = silu_f(a1.x); l1g[r][c0+5] = silu_f(a1.y);
            l1g[r][c0+6] = silu_f(a1.z); l1g[r][c0+7] = silu_f(a1.w);
        }
        __syncthreads();
        for (int u = t; u < 16*48; u += 256) {
            int e = u / 48, j = u - 48*(u/48);
            float acc = eb2[j];
            #pragma unroll 4
            for (int i = 0; i < HID; i++) acc += l1g[e][i]*ew2[i*48 + j];
            gg[e][j] = acc;
        }
        __syncthreads();
        for (int u = t; u < 16*80; u += 256) {
            int e = u / 80, cc = u - 80*(u/80);
            gexp[(e0 + e)*OUT_DIM + cc] = (cc < M0O) ? gg[e][cc] : gg[e][M0O + (cc - M0O)/3];
        }
    } else if (blk < S1_EDGE + S1_Q + S1_GATE + S1_TRANS) {
        __half* lds = (__half*)smem;  // [64][66]
        int tb = blk - (S1_EDGE + S1_Q + S1_GATE);
        int nt = tb % 72, kt = tb / 72;
        int n0 = nt*64, k0 = kt*64;
        for (int p = 0; p < 16; p++) {
            int idx = t + 256*p;
            int kk = idx >> 6, nn = idx & 63;
            lds[nn*66 + kk] = __float2half(rw2[(k0+kk)*WNUM + n0+nn]);
        }
        __syncthreads();
        for (int p = 0; p < 16; p++) {
            int idx = t + 256*p;
            int nn = idx >> 6, kk = idx & 63;
            rw2T[(n0+nn)*HID + k0+kk] = lds[nn*66 + kk];
        }
    } else {
        for (int p = 0; p < 6; p++) inv[t + 256*p] = -1;
        for (int p = 0; p < 4; p++) {
            int e = t + 256*p;
            float d = att_dist[e];
            envE[e] = (d < CUTOFF) ? 0.5f*(cosf(3.14159265358979323846f*d/CUTOFF) + 1.0f) : 0.0f;
            float vx = att_vec[3*e], vy = att_vec[3*e+1], vz = att_vec[3*e+2];
            float nrm = sqrtf(vx*vx + vy*vy + vz*vz);
            float is = 1.0f / fmaxf(nrm, 1e-8f);
            const float s3 = 1.7320508075688772f;
            y1E[3*e]   = s3*vx*is;
            y1E[3*e+1] = s3*vy*is;
            y1E[3*e+2] = s3*vz*is;
        }
        __syncthreads();
        for (int p = 0; p < 4; p++) { int e = t + 256*p; inv[att_dst[e]] = e; }
    }
}

// ---------------- K2: fused MFMA GEMM + tensor product, plus scores GEMM ----------------
// TP block: cls = blk%3 (0: out0[:,0:16) even SEG0/SEG3 tiles; 1: out0[:,16:32) odd;
//           2: out1 via SEG1+SEG2), tile = blk/3 -> edges [tile*16, tile*16+16).
// 96 column-tiles per block, processed as 12 groups of 8 (MFMA -> LDS -> TP regs).
// tpw never hits HBM; virr written once per element, no atomics.
__global__ __launch_bounds__(256) void k_fuse(
    const __half* __restrict__ hiddenH, const __half* __restrict__ rw2T,
    const float* __restrict__ rb2,
    const float* __restrict__ qmat, const float* __restrict__ kmat,
    const int* __restrict__ inv, const int* __restrict__ att_dst,
    const float* __restrict__ h_full,
    const float* __restrict__ envE, const float* __restrict__ y1E,
    float* __restrict__ virr, float* __restrict__ scoresW)
{
    __shared__ __align__(16) char smemraw[34176];
    float* smem = (float*)smemraw;
    int blk = blockIdx.x;
    int t = threadIdx.x;
    if (blk < TP_BLKS) {
        __half* cS   = (__half*)smemraw;        // [16][136] halves (2176 halves = 1088 floats)
        float* x0f   = smem + 1088;             // [16][64]
        float* x1f   = smem + 2112;             // [16][96]
        float* xyf   = smem + 3648;             // [16][32]
        float* y1f   = smem + 4160;             // [16][4]
        float* envf  = smem + 4224;             // [16]
        int*   fI    = (int*)(smem + 4240);     // [16]
        int cls  = blk % 3;
        int tile = blk / 3;
        int e0 = tile * 16;
        // meta
        if (t < 16) {
            int e = e0 + t;
            fI[t] = att_dst[e];
            envf[t] = envE[e];
            y1f[t*4]   = y1E[3*e];
            y1f[t*4+1] = y1E[3*e+1];
            y1f[t*4+2] = y1E[3*e+2];
        }
        __syncthreads();
        // gather h_full rows: 16 x 160 floats
        for (int p = 0; p < 10; p++) {
            int idx = t + 256*p;
            int edge = idx / 160, j = idx - 160*edge;
            float v = h_full[fI[edge]*NODE_DIM + j];
            if (j < M0I) x0f[edge*64 + j] = v;
            else         x1f[edge*96 + (j - M0I)] = v;
        }
        __syncthreads();
        // xy = x1 . y1
        for (int p = 0; p < 2; p++) {
            int idx = t + 256*p;
            int edge = idx >> 5, i = idx & 31;
            xyf[edge*32 + i] = x1f[edge*96 + 3*i]*y1f[edge*4]
                             + x1f[edge*96 + 3*i+1]*y1f[edge*4+1]
                             + x1f[edge*96 + 3*i+2]*y1f[edge*4+2];
        }
        __syncthreads();

        int wv = t >> 6;
        int lane = t & 63;
        int mrow = lane & 15, quad = lane >> 4;
        // A-fragments: fixed per block (16 edges)
        const _Float16* hp = (const _Float16*)hiddenH + (e0 + mrow)*HID + quad*8;
        half8_t af[4];
        #pragma unroll
        for (int kc = 0; kc < 4; kc++) af[kc] = *(const half8_t*)(hp + kc*32);

        int edge = t >> 4, o = t & 15;
        float t00 = 0.f, t11 = 0.f;            // cls 0/1
        float t01 = 0.f, tm0 = 0.f, tm1 = 0.f, tm2 = 0.f;  // cls 2
        int clsAdd = (cls == 1) ? 1 : 0;

        for (int g = 0; g < 12; g++) {
            // ---- MFMA phase: wave wv computes local tiles {2wv, 2wv+1} ----
            #pragma unroll
            for (int sub = 0; sub < 2; sub++) {
                int ntl = 2*wv + sub;          // local tile 0..7
                int j = g*8 + ntl;             // 0..95
                int ntg = (cls == 2) ? (128 + j)
                                     : (2*j + clsAdd + ((j >= 64) ? 96 : 0));
                const _Float16* bp = (const _Float16*)rw2T + (ntg*16 + mrow)*HID + quad*8;
                float4v acc = {0.f, 0.f, 0.f, 0.f};
                #pragma unroll
                for (int kc = 0; kc < 4; kc++) {
                    half8_t bf = *(const half8_t*)(bp + kc*32);
                    acc = __builtin_amdgcn_mfma_f32_16x16x32_f16(af[kc], bf, acc, 0, 0, 0);
                }
                float bias = rb2[ntg*16 + mrow];
                #pragma unroll
                for (int r = 0; r < 4; r++)
                    cS[(quad*4 + r)*136 + ntl*16 + mrow] = __float2half(acc[r] + bias);
            }
            __syncthreads();
            // ---- TP phase: thread owns (edge, o) ----
            if (cls < 2) {
                if (g < 8) {
                    #pragma unroll
                    for (int nt = 0; nt < 8; nt++) {
                        int j = g*8 + nt;   // i = j (SEG0)
                        float C = __half2float(cS[edge*136 + nt*16 + o]);
                        t00 += x0f[edge*64 + j]*C;
                    }
                } else {
                    #pragma unroll
                    for (int nt = 0; nt < 8; nt++) {
                        int j = g*8 + nt;   // i = j-64 (SEG3)
                        float C = __half2float(cS[edge*136 + nt*16 + o]);
                        t11 += xyf[edge*32 + (j - 64)]*C;
                    }
                }
            } else {
                if (g < 8) {
                    #pragma unroll
                    for (int nt = 0; nt < 8; nt++) {
                        int j = g*8 + nt;   // i = j (SEG1)
                        float C = __half2float(cS[edge*136 + nt*16 + o]);
                        t01 += x0f[edge*64 + j]*C;
                    }
                } else {
                    #pragma unroll
                    for (int nt = 0; nt < 8; nt++) {
                        int j = g*8 + nt;   // i = j-64 (SEG2)
                        int i = j - 64;
                        float C = __half2float(cS[edge*136 + nt*16 + o]);
                        tm0 += x1f[edge*96 + 3*i]*C;
                        tm1 += x1f[edge*96 + 3*i+1]*C;
                        tm2 += x1f[edge*96 + 3*i+2]*C;
                    }
                }
            }
            __syncthreads();
        }
        // ---- finalize ----
        const float alpha = 0.10206207261596575f;  // 1/sqrt(96)
        const float ccf   = 0.5773502691896258f;   // 1/sqrt(3)
        int f = fI[edge];
        float env = envf[edge];
        if (cls < 2) {
            virr[f*OUT_DIM + cls*16 + o] = alpha*(t00 + ccf*t11)*env;
        } else {
            float y0 = y1f[edge*4], y1v = y1f[edge*4+1], y2 = y1f[edge*4+2];
            virr[f*OUT_DIM + M0O + 3*o]     = alpha*ccf*(t01*y0 + tm0)*env;
            virr[f*OUT_DIM + M0O + 3*o + 1] = alpha*ccf*(t01*y1v + tm1)*env;
            virr[f*OUT_DIM + M0O + 3*o + 2] = alpha*ccf*(t01*y2 + tm2)*env;
        }
    } else {
        // ---- scores GEMM (R4-proven) ----
        int u = blk - TP_BLKS;
        int b  = u >> 3;
        int e0 = (u & 7) * 32;
        float (*Qs)[132] = (float(*)[132])smem;
        float (*Kt)[132] = (float(*)[132])(smem + 32*132);
        float* mS = smem + 2*32*132;
        for (int p = 0; p < 4; p++) {
            int idx = t + 256*p; int e = idx >> 5, i4 = idx & 31;
            *(float4*)&Qs[e][i4*4] = *(const float4*)&qmat[(b*NE + e0 + e)*LAT + i4*4];
        }
        if (t < NN) mS[t] = ((unsigned)inv[b*NN + t] < E_ATT) ? 1.0f : 0.0f;
        int te = t >> 5, tn = t & 31;
        float acc[4][3] = {};
        for (int nt = 0; nt < 3; nt++) {
            __syncthreads();
            for (int p = 0; p < 4; p++) {
                int idx = t + 256*p; int n = idx >> 5, i4 = idx & 31;
                *(float4*)&Kt[n][i4*4] = *(const float4*)&kmat[(b*NN + nt*32 + n)*LAT + i4*4];
            }
            __syncthreads();
            for (int i = 0; i < LAT; i++) {
                float bv = Kt[tn][i];
                acc[0][nt] += Qs[te*4 + 0][i]*bv;
                acc[1][nt] += Qs[te*4 + 1][i]*bv;
                acc[2][nt] += Qs[te*4 + 2][i]*bv;
                acc[3][nt] += Qs[te*4 + 3][i]*bv;
            }
        }
        const float scale = 0.04419417382415922f;  // (1/HEADS)*HD^-0.5
        #pragma unroll
        for (int j = 0; j < 4; j++)
            #pragma unroll
            for (int jj = 0; jj < 3; jj++) {
                int n = tn + 32*jj;
                float s = (mS[n] != 0.f) ? acc[j][jj]*scale : -1e9f;
                scoresW[((b*NE) + e0 + te*4 + j)*NN + n] = s;
            }
    }
}

// ---------------- fused attention(softmax+PV) + final MLP (proven) ----------------
__global__ __launch_bounds__(256) void k_attf(
    const float* __restrict__ scoresW, const int* __restrict__ inv,
    const float* __restrict__ virr, const float* __restrict__ gexp,
    const float* __restrict__ ow1, const float* __restrict__ ob1,
    const float* __restrict__ ow2, const float* __restrict__ ob2,
    const float* __restrict__ ow3, const float* __restrict__ ob3,
    float* __restrict__ out)
{
    int b  = blockIdx.x >> 5;
    int e0 = (blockIdx.x & 31) * 8;
    int t = threadIdx.x;
    __shared__ float aS[8][100];
    __shared__ float gS[8][84];
    __shared__ float ocS[8][84];
    __shared__ float mS[NN];
    __shared__ float inS[8][INVD];
    __shared__ float l1S[8][HID];
    __shared__ float l2S[8][HID];

    for (int p = 0; p < 3; p++) {
        int idx = t + 256*p;
        int el = idx / NN, n = idx - NN*(idx/NN);
        aS[el][n] = scoresW[((b*NE) + e0 + el)*NN + n];
    }
    if (t < 160) {
        int el = t / 20, c4 = t - 20*(t/20);
        *(float4*)&gS[el][c4*4] = *(const float4*)&gexp[(e0 + el)*OUT_DIM + c4*4];
    }
    if (t < NN) mS[t] = ((unsigned)inv[b*NN + t] < E_ATT) ? 1.0f : 0.0f;
    __syncthreads();

    {
        int el = t >> 5;
        int ng = t & 31;
        float s0 = aS[el][ng], s1 = aS[el][ng + 32], s2 = aS[el][ng + 64];
        float m0 = mS[ng], m1 = mS[ng + 32], m2 = mS[ng + 64];
        float mx = fmaxf(s0, fmaxf(s1, s2));
        #pragma unroll
        for (int off = 1; off < 32; off <<= 1) mx = fmaxf(mx, __shfl_xor(mx, off));
        float e0v = expf(s0 - mx), e1v = expf(s1 - mx), e2v = expf(s2 - mx);
        float sm = e0v + e1v + e2v;
        #pragma unroll
        for (int off = 1; off < 32; off <<= 1) sm += __shfl_xor(sm, off);
        float r = 1.0f / sm;
        float p0 = m0*e0v*r, p1 = m1*e1v*r, p2 = m2*e2v*r;
        float ss = p0 + p1 + p2;
        #pragma unroll
        for (int off = 1; off < 32; off <<= 1) ss += __shfl_xor(ss, off);
        float is = 1.0f / fmaxf(ss, 1e-8f);
        aS[el][ng]      = p0*is;
        aS[el][ng + 32] = p1*is;
        aS[el][ng + 64] = p2*is;
    }
    __syncthreads();

    if (t < 160) {
        int el = t / 20, c4 = t - 20*(t/20);
        const float* vp = virr + (long)b*NN*OUT_DIM + c4*4;
        float4 acc = make_float4(0,0,0,0);
        #pragma unroll 4
        for (int n = 0; n < NN; n++) {
            float a = aS[el][n];
            float4 v = *(const float4*)&vp[n*OUT_DIM];
            acc.x += a*v.x; acc.y += a*v.y; acc.z += a*v.z; acc.w += a*v.w;
        }
        float4 g = *(float4*)&gS[el][c4*4];
        float4 o; o.x = acc.x*g.x; o.y = acc.y*g.y; o.z = acc.z*g.z; o.w = acc.w*g.w;
        *(float4*)&ocS[el][c4*4] = o;
    }
    __syncthreads();

    for (int u = t; u < 8*INVD; u += 256) {
        int el = u / INVD, j = u - INVD*(u/INVD);
        float val;
        if (j < M0O) val = ocS[el][j];
        else {
            int o = j - M0O;
            float x = ocS[el][M0O + 3*o], y = ocS[el][M0O + 3*o + 1], zz = ocS[el][M0O + 3*o + 2];
            val = sqrtf(x*x + y*y + zz*zz + 1e-12f);
        }
        inS[el][j] = val;
    }
    __syncthreads();

    int r = t >> 5, c0 = (t & 31)*4;
    {
        float4 a0 = *(const float4*)&ob1[c0];
        float4 a1 = make_float4(0,0,0,0);
        #pragma unroll 8
        for (int i = 0; i < INVD; i += 2) {
            float x0v = inS[r][i], x1v = inS[r][i+1];
            float4 w0 = *(const float4*)&ow1[i*HID + c0];
            float4 w1 = *(const float4*)&ow1[(i+1)*HID + c0];
            a0.x += x0v*w0.x; a0.y += x0v*w0.y; a0.z += x0v*w0.z; a0.w += x0v*w0.w;
            a1.x += x1v*w1.x; a1.y += x1v*w1.y; a1.z += x1v*w1.z; a1.w += x1v*w1.w;
        }
        l1S[r][c0]   = silu_f(a0.x + a1.x); l1S[r][c0+1] = silu_f(a0.y + a1.y);
        l1S[r][c0+2] = silu_f(a0.z + a1.z); l1S[r][c0+3] = silu_f(a0.w + a1.w);
    }
    __syncthreads();
    {
        float4 a0 = *(const float4*)&ob2[c0];
        float4 a1 = make_float4(0,0,0,0);
        #pragma unroll 8
        for (int i = 0; i < HID; i += 2) {
            float x0v = l1S[r][i], x1v = l1S[r][i+1];
            float4 w0 = *(const float4*)&ow2[i*HID + c0];
            float4 w1 = *(const float4*)&ow2[(i+1)*HID + c0];
            a0.x += x0v*w0.x; a0.y += x0v*w0.y; a0.z += x0v*w0.z; a0.w += x0v*w0.w;
            a1.x += x1v*w1.x; a1.y += x1v*w1.y; a1.z += x1v*w1.z; a1.w += x1v*w1.w;
        }
        l2S[r][c0]   = silu_f(a0.x + a1.x); l2S[r][c0+1] = silu_f(a0.y + a1.y);
        l2S[r][c0+2] = silu_f(a0.z + a1.z); l2S[r][c0+3] = silu_f(a0.w + a1.w);
    }
    __syncthreads();
    {
        float4 a0 = *(const float4*)&ob3[c0];
        float4 a1 = make_float4(0,0,0,0);
        #pragma unroll 8
        for (int i = 0; i < HID; i += 2) {
            float x0v = l2S[r][i], x1v = l2S[r][i+1];
            float4 w0 = *(const float4*)&ow3[i*HID + c0];
            float4 w1 = *(const float4*)&ow3[(i+1)*HID + c0];
            a0.x += x0v*w0.x; a0.y += x0v*w0.y; a0.z += x0v*w0.z; a0.w += x0v*w0.w;
            a1.x += x1v*w1.x; a1.y += x1v*w1.y; a1.z += x1v*w1.z; a1.w += x1v*w1.w;
        }
        float4 o;
        o.x = a0.x + a1.x; o.y = a0.y + a1.y; o.z = a0.z + a1.z; o.w = a0.w + a1.w;
        *(float4*)&out[((b*NE + e0) + r)*LAT + c0] = o;
    }
}

extern "C" void kernel_launch(void* const* d_in, const int* in_sizes, int n_in,
                              void* d_out, int out_size, void* d_ws, size_t ws_size,
                              hipStream_t stream) {
    const float* h        = (const float*)d_in[0];
    const float* h_full   = (const float*)d_in[1];
    const float* e_feat   = (const float*)d_in[2];
    const float* att_dist = (const float*)d_in[3];
    const float* att_vec  = (const float*)d_in[4];
    const float* z_emb    = (const float*)d_in[5];
    const float* rw1 = (const float*)d_in[6];  const float* rb1 = (const float*)d_in[7];
    const float* rw2 = (const float*)d_in[8];  const float* rb2 = (const float*)d_in[9];
    const float* ew1 = (const float*)d_in[10]; const float* eb1 = (const float*)d_in[11];
    const float* ew2 = (const float*)d_in[12]; const float* eb2 = (const float*)d_in[13];
    const float* qw1 = (const float*)d_in[14]; const float* qb1 = (const float*)d_in[15];
    const float* qw2 = (const float*)d_in[16]; const float* qb2 = (const float*)d_in[17];
    const float* qw3 = (const float*)d_in[18]; const float* qb3 = (const float*)d_in[19];
    const float* kw1 = (const float*)d_in[20]; const float* kb1 = (const float*)d_in[21];
    const float* kw2 = (const float*)d_in[22]; const float* kb2 = (const float*)d_in[23];
    const float* kw3 = (const float*)d_in[24]; const float* kb3 = (const float*)d_in[25];
    const float* ow1 = (const float*)d_in[26]; const float* ob1 = (const float*)d_in[27];
    const float* ow2 = (const float*)d_in[28]; const float* ob2 = (const float*)d_in[29];
    const float* ow3 = (const float*)d_in[30]; const float* ob3 = (const float*)d_in[31];
    const int* z        = (const int*)d_in[32];
    const int* absorber = (const int*)d_in[34];
    const int* att_dst  = (const int*)d_in[35];

    float* ws = (float*)d_ws;
    int*   inv     = (int*)ws;                    // 1536
    float* y1E     = ws + 1536;                   // 3072
    float* envE    = ws + 4608;                   // 1024
    float* kmat    = ws + 5632;                   // 196608 (1536x128)
    float* qmat    = ws + 202240;                 // 524288 (4096x128)
    float* gexp    = ws + 726528;                 // 20480
    float* virr    = ws + 747008;                 // 122880 (1536x80)
    float* scoresW = ws + 904704;                 // 393216 (4096x96)
    __half* rw2T   = (__half*)(ws + 3657216);     // 589824 halves (4608x128)
    __half* hiddenH= (__half*)(ws + 3952128);     // 131072 halves (1024x128)

    float* out = (float*)d_out;

    k_stage1<<<STAGE1_BLKS, 256, 0, stream>>>(h, z_emb, z, absorber, e_feat,
                                              att_dst, att_dist, att_vec,
                                              rw1, rb1, kw1, kb1, kw2, kb2, kw3, kb3,
                                              qw1, qb1, qw2, qb2, qw3, qb3,
                                              ew1, eb1, ew2, eb2, rw2,
                                              hiddenH, kmat, qmat, gexp, rw2T,
                                              inv, y1E, envE);
    k_fuse<<<K2_BLKS, 256, 0, stream>>>(hiddenH, rw2T, rb2, qmat, kmat, inv,
                                        att_dst, h_full, envE, y1E, virr, scoresW);
    k_attf<<<BB*32, 256, 0, stream>>>(scoresW, inv, virr, gexp,
                                      ow1, ob1, ow2, ob2, ow3, ob3, out);
}

// Round 6
// 226.352 us; speedup vs baseline: 2.1826x; 1.0027x over previous
//
#include <hip/hip_runtime.h>
#include <hip/hip_fp16.h>
#include <math.h>

#define BB 16
#define NN 96
#define NE 256
#define FF (BB*NN)      // 1536
#define ATOM 128
#define EDIM 16
#define HID 128
#define LAT 128
#define RBFN 16
#define CUTOFF 5.0f
#define ZEMB 32
#define E_ATT 1024
#define M0I 64
#define M1I 32
#define M0O 32
#define M1O 16
#define NODE_DIM 160
#define OUT_DIM 80
#define INVD 48
#define WNUM 4608
#define SEG1 2048
#define SEG2 3072
#define SEG3 3584

// ---- stage1 block layout ----
#define S1_EDGE 256                 // [0,256)   4 edges/block
#define S1_Q    512                 // [256,768) 8 q-rows/block
#define S1_GATE 16                  // [768,784)
#define S1_TRANS 144                // [784,928)
#define STAGE1_BLKS 929

// ---- K2: fused GEMM+TP (192) + scores (128) ----
#define TP_BLKS 192                 // 64 edge-tiles x 3 output-slices
#define SCORE_BLKS 128
#define K2_BLKS (TP_BLKS + SCORE_BLKS)  // 320

// C-panel LDS stride (halves): 96 tiles * 16 + 8 pad
#define CSTR 1544

typedef _Float16 half8_t __attribute__((ext_vector_type(8)));
typedef float float4v __attribute__((ext_vector_type(4)));

__device__ __forceinline__ float silu_f(float x) { return x / (1.0f + expf(-x)); }

// ---------------- stage1 mega-kernel ----------------
__global__ __launch_bounds__(256) void k_stage1(
    const float* __restrict__ h, const float* __restrict__ z_emb, const int* __restrict__ z,
    const int* __restrict__ absorber, const float* __restrict__ e_feat,
    const int* __restrict__ att_dst, const float* __restrict__ att_dist,
    const float* __restrict__ att_vec,
    const float* __restrict__ rw1, const float* __restrict__ rb1,
    const float* __restrict__ kw1, const float* __restrict__ kb1,
    const float* __restrict__ kw2, const float* __restrict__ kb2,
    const float* __restrict__ kw3, const float* __restrict__ kb3,
    const float* __restrict__ qw1, const float* __restrict__ qb1,
    const float* __restrict__ qw2, const float* __restrict__ qb2,
    const float* __restrict__ qw3, const float* __restrict__ qb3,
    const float* __restrict__ ew1, const float* __restrict__ eb1,
    const float* __restrict__ ew2, const float* __restrict__ eb2,
    const float* __restrict__ rw2,
    __half* __restrict__ hiddenH, float* __restrict__ kmatw,
    float* __restrict__ qmat, float* __restrict__ gexp,
    __half* __restrict__ rw2T,
    int* __restrict__ inv, float* __restrict__ y1E, float* __restrict__ envE)
{
    __shared__ float smem[3488];
    int blk = blockIdx.x;
    int t = threadIdx.x;

    if (blk < S1_EDGE) {
        // wave = edge; sin1/l1S/l2S slices are WAVE-PRIVATE -> no __syncthreads needed.
        // LDS ops within a wave complete in order; wave_barrier() fences compiler reordering.
        float (*sin1)[184] = (float(*)[184])smem;
        float (*l1S)[128]  = (float(*)[128])(smem + 736);
        float (*l2S)[128]  = (float(*)[128])(smem + 736 + 512);
        int w = t >> 6;
        int c = t & 63;
        int e = blk*4 + w;
        int f = att_dst[e];
        int b = f / NN, nn = f - b*NN;
        float d = att_dist[e];
        {
            float2 hv = *(const float2*)&h[f*ATOM + 2*c];
            sin1[w][2*c] = hv.x; sin1[w][2*c + 1] = hv.y;
        }
        if (c < ZEMB) sin1[w][ATOM + c] = z_emb[z[f]*ZEMB + c];
        if (c >= 32 && c < 48) {
            int j = c - 32;
            const float delta = CUTOFF / (RBFN - 1);
            float diff = d - j*delta;
            sin1[w][ATOM + ZEMB + 1 + j] = expf(-diff*diff / (2.0f*delta*delta));
        }
        if (c == 48) sin1[w][ATOM + ZEMB] = (absorber[b] == nn) ? 1.0f : 0.0f;
        __builtin_amdgcn_wave_barrier();
        int c2 = 2*c;
        {   // hidden = silu(w_in @ rw1 + rb1): 49 -> 128
            float2 a0 = *(const float2*)&rb1[c2];
            float2 a1 = make_float2(0.f, 0.f);
            #pragma unroll 8
            for (int i = 0; i < 48; i += 2) {
                float x0v = sin1[w][ATOM + i], x1v = sin1[w][ATOM + i + 1];
                float2 w0 = *(const float2*)&rw1[i*HID + c2];
                float2 w1 = *(const float2*)&rw1[(i+1)*HID + c2];
                a0.x += x0v*w0.x; a0.y += x0v*w0.y;
                a1.x += x1v*w1.x; a1.y += x1v*w1.y;
            }
            {
                float x0v = sin1[w][ATOM + 48];
                float2 w0 = *(const float2*)&rw1[48*HID + c2];
                a0.x += x0v*w0.x; a0.y += x0v*w0.y;
            }
            *(__half2*)&hiddenH[e*HID + c2] =
                __floats2half2_rn(silu_f(a0.x + a1.x), silu_f(a0.y + a1.y));
        }
        {   // k layer 1: 177 -> 128
            float2 a0 = *(const float2*)&kb1[c2];
            float2 a1 = make_float2(0.f, 0.f);
            #pragma unroll 16
            for (int i = 0; i < 176; i += 2) {
                float x0v = sin1[w][i], x1v = sin1[w][i + 1];
                float2 w0 = *(const float2*)&kw1[i*HID + c2];
                float2 w1 = *(const float2*)&kw1[(i+1)*HID + c2];
                a0.x += x0v*w0.x; a0.y += x0v*w0.y;
                a1.x += x1v*w1.x; a1.y += x1v*w1.y;
            }
            {
                float x0v = sin1[w][176];
                float2 w0 = *(const float2*)&kw1[176*HID + c2];
                a0.x += x0v*w0.x; a0.y += x0v*w0.y;
            }
            l1S[w][c2] = silu_f(a0.x + a1.x); l1S[w][c2+1] = silu_f(a0.y + a1.y);
        }
        __builtin_amdgcn_wave_barrier();
        {   // k layer 2
            float2 a0 = *(const float2*)&kb2[c2];
            float2 a1 = make_float2(0.f, 0.f);
            #pragma unroll 16
            for (int i = 0; i < HID; i += 2) {
                float x0v = l1S[w][i], x1v = l1S[w][i + 1];
                float2 w0 = *(const float2*)&kw2[i*HID + c2];
                float2 w1 = *(const float2*)&kw2[(i+1)*HID + c2];
                a0.x += x0v*w0.x; a0.y += x0v*w0.y;
                a1.x += x1v*w1.x; a1.y += x1v*w1.y;
            }
            l2S[w][c2] = silu_f(a0.x + a1.x); l2S[w][c2+1] = silu_f(a0.y + a1.y);
        }
        __builtin_amdgcn_wave_barrier();
        {   // k layer 3 -> kmat
            float2 a0 = *(const float2*)&kb3[c2];
            float2 a1 = make_float2(0.f, 0.f);
            #pragma unroll 16
            for (int i = 0; i < HID; i += 2) {
                float x0v = l2S[w][i], x1v = l2S[w][i + 1];
                float2 w0 = *(const float2*)&kw3[i*HID + c2];
                float2 w1 = *(const float2*)&kw3[(i+1)*HID + c2];
                a0.x += x0v*w0.x; a0.y += x0v*w0.y;
                a1.x += x1v*w1.x; a1.y += x1v*w1.y;
            }
            float2 o; o.x = a0.x + a1.x; o.y = a0.y + a1.y;
            *(float2*)&kmatw[f*HID + c2] = o;
        }
    } else if (blk < S1_EDGE + S1_Q) {
        float* hA          = smem;
        float (*ef)[16]    = (float(*)[16])(smem + 128);
        float (*part)[128] = (float(*)[128])(smem + 256);
        float* l1S         = smem + 1280;
        float* l2S         = smem + 2304;
        int idx = blk - S1_EDGE;
        int r0 = idx * 8;
        int b  = r0 >> 8;
        int e8 = r0 & 255;
        if (t < 32) *(float4*)&hA[t*4] = *(const float4*)&h[(b*NN + absorber[b])*ATOM + t*4];
        if (t >= 128 && t < 256) { int e = (t - 128) >> 4, j = t & 15; ef[e][j] = e_feat[(e8 + e)*EDIM + j]; }
        __syncthreads();
        int r = t >> 5, c0 = (t & 31)*4;
        {
            float4 a0 = make_float4(0,0,0,0);
            int k0 = r*16;
            #pragma unroll
            for (int k = 0; k < 16; k++) {
                float hv = hA[k0 + k];
                float4 w0 = *(const float4*)&qw1[(k0 + k)*HID + c0];
                a0.x += hv*w0.x; a0.y += hv*w0.y; a0.z += hv*w0.z; a0.w += hv*w0.w;
            }
            *(float4*)&part[r][c0] = a0;
        }
        __syncthreads();
        {
            float4 s = *(const float4*)&qb1[c0];
            #pragma unroll
            for (int g = 0; g < 8; g++) {
                float4 pg = *(const float4*)&part[g][c0];
                s.x += pg.x; s.y += pg.y; s.z += pg.z; s.w += pg.w;
            }
            #pragma unroll
            for (int j = 0; j < 16; j++) {
                float a = ef[r][j];
                float4 w0 = *(const float4*)&qw1[(ATOM + j)*HID + c0];
                s.x += a*w0.x; s.y += a*w0.y; s.z += a*w0.z; s.w += a*w0.w;
            }
            l1S[r*128 + c0]   = silu_f(s.x); l1S[r*128 + c0+1] = silu_f(s.y);
            l1S[r*128 + c0+2] = silu_f(s.z); l1S[r*128 + c0+3] = silu_f(s.w);
        }
        __syncthreads();
        {
            float4 a0 = *(const float4*)&qb2[c0];
            float4 a1 = make_float4(0,0,0,0);
            #pragma unroll 8
            for (int i = 0; i < HID; i += 2) {
                float x0v = l1S[r*128 + i], x1v = l1S[r*128 + i+1];
                float4 w0 = *(const float4*)&qw2[i*HID + c0];
                float4 w1 = *(const float4*)&qw2[(i+1)*HID + c0];
                a0.x += x0v*w0.x; a0.y += x0v*w0.y; a0.z += x0v*w0.z; a0.w += x0v*w0.w;
                a1.x += x1v*w1.x; a1.y += x1v*w1.y; a1.z += x1v*w1.z; a1.w += x1v*w1.w;
            }
            l2S[r*128 + c0]   = silu_f(a0.x + a1.x); l2S[r*128 + c0+1] = silu_f(a0.y + a1.y);
            l2S[r*128 + c0+2] = silu_f(a0.z + a1.z); l2S[r*128 + c0+3] = silu_f(a0.w + a1.w);
        }
        __syncthreads();
        {
            float4 a0 = *(const float4*)&qb3[c0];
            float4 a1 = make_float4(0,0,0,0);
            #pragma unroll 8
            for (int i = 0; i < HID; i += 2) {
                float x0v = l2S[r*128 + i], x1v = l2S[r*128 + i+1];
                float4 w0 = *(const float4*)&qw3[i*HID + c0];
                float4 w1 = *(const float4*)&qw3[(i+1)*HID + c0];
                a0.x += x0v*w0.x; a0.y += x0v*w0.y; a0.z += x0v*w0.z; a0.w += x0v*w0.w;
                a1.x += x1v*w1.x; a1.y += x1v*w1.y; a1.z += x1v*w1.z; a1.w += x1v*w1.w;
            }
            float4 o;
            o.x = a0.x + a1.x; o.y = a0.y + a1.y; o.z = a0.z + a1.z; o.w = a0.w + a1.w;
            *(float4*)&qmat[(r0 + r)*LAT + c0] = o;
        }
    } else if (blk < S1_EDGE + S1_Q + S1_GATE) {
        float (*ef)[16]   = (float(*)[16])smem;
        float (*l1g)[128] = (float(*)[128])(smem + 256);
        float (*gg)[48]   = (float(*)[48])(smem + 256 + 2048);
        int e0 = (blk - S1_EDGE - S1_Q) * 16;
        { int e = t >> 4, i = t & 15; ef[e][i] = e_feat[(e0 + e)*EDIM + i]; }
        __syncthreads();
        int r = t >> 4, c0 = (t & 15)*8;
        {
            float4 a0 = *(const float4*)&eb1[c0];
            float4 a1 = *(const float4*)&eb1[c0 + 4];
            #pragma unroll
            for (int i = 0; i < EDIM; i++) {
                float a = ef[r][i];
                float4 w0 = *(const float4*)&ew1[i*HID + c0];
                float4 w1 = *(const float4*)&ew1[i*HID + c0 + 4];
                a0.x += a*w0.x; a0.y += a*w0.y; a0.z += a*w0.z; a0.w += a*w0.w;
                a1.x += a*w1.x; a1.y += a*w1.y; a1.z += a*w1.z; a1.w += a*w1.w;
            }
            l1g[r][c0]   = silu_f(a0.x); l1g[r][c0+1] = silu_f(a0.y);
            l1g[r][c0+2] = silu_f(a0.z); l1g[r][c0+3] = silu_f(a0.w);
            l1g[r][c0+4] = silu_f(a1.x); l1g[r][c0+5] = silu_f(a1.y);
            l1g[r][c0+6] = silu_f(a1.z); l1g[r][c0+7] = silu_f(a1.w);
        }
        __syncthreads();
        for (int u = t; u < 16*48; u += 256) {
            int e = u / 48, j = u - 48*(u/48);
            float acc = eb2[j];
            #pragma unroll 4
            for (int i = 0; i < HID; i++) acc += l1g[e][i]*ew2[i*48 + j];
            gg[e][j] = acc;
        }
        __syncthreads();
        for (int u = t; u < 16*80; u += 256) {
            int e = u / 80, cc = u - 80*(u/80);
            gexp[(e0 + e)*OUT_DIM + cc] = (cc < M0O) ? gg[e][cc] : gg[e][M0O + (cc - M0O)/3];
        }
    } else if (blk < S1_EDGE + S1_Q + S1_GATE + S1_TRANS) {
        __half* lds = (__half*)smem;  // [64][66]
        int tb = blk - (S1_EDGE + S1_Q + S1_GATE);
        int nt = tb % 72, kt = tb / 72;
        int n0 = nt*64, k0 = kt*64;
        for (int p = 0; p < 16; p++) {
            int idx = t + 256*p;
            int kk = idx >> 6, nn = idx & 63;
            lds[nn*66 + kk] = __float2half(rw2[(k0+kk)*WNUM + n0+nn]);
        }
        __syncthreads();
        for (int p = 0; p < 16; p++) {
            int idx = t + 256*p;
            int nn = idx >> 6, kk = idx & 63;
            rw2T[(n0+nn)*HID + k0+kk] = lds[nn*66 + kk];
        }
    } else {
        for (int p = 0; p < 6; p++) inv[t + 256*p] = -1;
        for (int p = 0; p < 4; p++) {
            int e = t + 256*p;
            float d = att_dist[e];
            envE[e] = (d < CUTOFF) ? 0.5f*(cosf(3.14159265358979323846f*d/CUTOFF) + 1.0f) : 0.0f;
            float vx = att_vec[3*e], vy = att_vec[3*e+1], vz = att_vec[3*e+2];
            float nrm = sqrtf(vx*vx + vy*vy + vz*vz);
            float is = 1.0f / fmaxf(nrm, 1e-8f);
            const float s3 = 1.7320508075688772f;
            y1E[3*e]   = s3*vx*is;
            y1E[3*e+1] = s3*vy*is;
            y1E[3*e+2] = s3*vz*is;
        }
        __syncthreads();
        for (int p = 0; p < 4; p++) { int e = t + 256*p; inv[att_dst[e]] = e; }
    }
}

// ---------------- K2: fused MFMA GEMM + tensor product (single-pass C-panel), + scores ----------------
// TP block: cls = blk%3, tile = blk/3 -> edges [tile*16, tile*16+16).
// Full 16x(96 tiles) C-panel in LDS (49.4 KB): each wave MFMAs its 24 column-tiles
// back-to-back (no inter-group barriers), then ONE barrier, then the TP contraction.
// Numerics identical to R5 (same fp16 round + bias, same ntg mapping).
__global__ __launch_bounds__(256) void k_fuse(
    const __half* __restrict__ hiddenH, const __half* __restrict__ rw2T,
    const float* __restrict__ rb2,
    const float* __restrict__ qmat, const float* __restrict__ kmat,
    const int* __restrict__ inv, const int* __restrict__ att_dst,
    const float* __restrict__ h_full,
    const float* __restrict__ envE, const float* __restrict__ y1E,
    float* __restrict__ virr, float* __restrict__ scoresW)
{
    __shared__ __align__(16) char smemraw[62208];
    float* smem = (float*)smemraw;
    int blk = blockIdx.x;
    int t = threadIdx.x;
    if (blk < TP_BLKS) {
        __half* cS   = (__half*)smemraw;            // [16][CSTR] halves = 49408 B
        float* fbase = (float*)(smemraw + 49408);
        float* x0f   = fbase;                       // [16][64]
        float* x1f   = fbase + 1024;                // [16][96]
        float* xyf   = fbase + 2560;                // [16][32]
        float* y1f   = fbase + 3072;                // [16][4]
        float* envf  = fbase + 3136;                // [16]
        int*   fI    = (int*)(fbase + 3152);        // [16]
        int cls  = blk % 3;
        int tile = blk / 3;
        int e0 = tile * 16;
        if (t < 16) {
            int e = e0 + t;
            fI[t] = att_dst[e];
            envf[t] = envE[e];
            y1f[t*4]   = y1E[3*e];
            y1f[t*4+1] = y1E[3*e+1];
            y1f[t*4+2] = y1E[3*e+2];
        }
        __syncthreads();
        for (int p = 0; p < 10; p++) {
            int idx = t + 256*p;
            int edge = idx / 160, j = idx - 160*edge;
            float v = h_full[fI[edge]*NODE_DIM + j];
            if (j < M0I) x0f[edge*64 + j] = v;
            else         x1f[edge*96 + (j - M0I)] = v;
        }
        __syncthreads();
        for (int p = 0; p < 2; p++) {
            int idx = t + 256*p;
            int edge = idx >> 5, i = idx & 31;
            xyf[edge*32 + i] = x1f[edge*96 + 3*i]*y1f[edge*4]
                             + x1f[edge*96 + 3*i+1]*y1f[edge*4+1]
                             + x1f[edge*96 + 3*i+2]*y1f[edge*4+2];
        }

        int wv = t >> 6;
        int lane = t & 63;
        int mrow = lane & 15, quad = lane >> 4;
        const _Float16* hp = (const _Float16*)hiddenH + (e0 + mrow)*HID + quad*8;
        half8_t af[4];
        #pragma unroll
        for (int kc = 0; kc < 4; kc++) af[kc] = *(const half8_t*)(hp + kc*32);

        int clsAdd = (cls == 1) ? 1 : 0;
        // ---- MFMA all 96 tiles: wave wv owns j in [wv*24, wv*24+24) ----
        #pragma unroll 4
        for (int jj = 0; jj < 24; jj++) {
            int j = wv*24 + jj;
            int ntg = (cls == 2) ? (128 + j)
                                 : (2*j + clsAdd + ((j >= 64) ? 96 : 0));
            const _Float16* bp = (const _Float16*)rw2T + (ntg*16 + mrow)*HID + quad*8;
            float4v acc = {0.f, 0.f, 0.f, 0.f};
            #pragma unroll
            for (int kc = 0; kc < 4; kc++) {
                half8_t bf = *(const half8_t*)(bp + kc*32);
                acc = __builtin_amdgcn_mfma_f32_16x16x32_f16(af[kc], bf, acc, 0, 0, 0);
            }
            float bias = rb2[ntg*16 + mrow];
            #pragma unroll
            for (int r = 0; r < 4; r++)
                cS[(quad*4 + r)*CSTR + j*16 + mrow] = __float2half(acc[r] + bias);
        }
        __syncthreads();

        // ---- TP contraction: thread owns (edge, o) ----
        int edge = t >> 4, o = t & 15;
        const __half* cRow = cS + edge*CSTR + o;
        const float alpha = 0.10206207261596575f;  // 1/sqrt(96)
        const float ccf   = 0.5773502691896258f;   // 1/sqrt(3)
        int f = fI[edge];
        float env = envf[edge];
        if (cls < 2) {
            float t00 = 0.f, t11 = 0.f;
            #pragma unroll 8
            for (int j = 0; j < 64; j++)
                t00 += x0f[edge*64 + j]*__half2float(cRow[j*16]);
            #pragma unroll 8
            for (int j = 64; j < 96; j++)
                t11 += xyf[edge*32 + (j - 64)]*__half2float(cRow[j*16]);
            virr[f*OUT_DIM + cls*16 + o] = alpha*(t00 + ccf*t11)*env;
        } else {
            float t01 = 0.f, tm0 = 0.f, tm1 = 0.f, tm2 = 0.f;
            #pragma unroll 8
            for (int j = 0; j < 64; j++)
                t01 += x0f[edge*64 + j]*__half2float(cRow[j*16]);
            #pragma unroll 8
            for (int j = 64; j < 96; j++) {
                int i = j - 64;
                float C = __half2float(cRow[j*16]);
                tm0 += x1f[edge*96 + 3*i]*C;
                tm1 += x1f[edge*96 + 3*i+1]*C;
                tm2 += x1f[edge*96 + 3*i+2]*C;
            }
            float y0 = y1f[edge*4], y1v = y1f[edge*4+1], y2 = y1f[edge*4+2];
            virr[f*OUT_DIM + M0O + 3*o]     = alpha*ccf*(t01*y0 + tm0)*env;
            virr[f*OUT_DIM + M0O + 3*o + 1] = alpha*ccf*(t01*y1v + tm1)*env;
            virr[f*OUT_DIM + M0O + 3*o + 2] = alpha*ccf*(t01*y2 + tm2)*env;
        }
    } else {
        // ---- scores GEMM (proven) ----
        int u = blk - TP_BLKS;
        int b  = u >> 3;
        int e0 = (u & 7) * 32;
        float (*Qs)[132] = (float(*)[132])smem;
        float (*Kt)[132] = (float(*)[132])(smem + 32*132);
        float* mS = smem + 2*32*132;
        for (int p = 0; p < 4; p++) {
            int idx = t + 256*p; int e = idx >> 5, i4 = idx & 31;
            *(float4*)&Qs[e][i4*4] = *(const float4*)&qmat[(b*NE + e0 + e)*LAT + i4*4];
        }
        if (t < NN) mS[t] = ((unsigned)inv[b*NN + t] < E_ATT) ? 1.0f : 0.0f;
        int te = t >> 5, tn = t & 31;
        float acc[4][3] = {};
        for (int nt = 0; nt < 3; nt++) {
            __syncthreads();
            for (int p = 0; p < 4; p++) {
                int idx = t + 256*p; int n = idx >> 5, i4 = idx & 31;
                *(float4*)&Kt[n][i4*4] = *(const float4*)&kmat[(b*NN + nt*32 + n)*LAT + i4*4];
            }
            __syncthreads();
            for (int i = 0; i < LAT; i++) {
                float bv = Kt[tn][i];
                acc[0][nt] += Qs[te*4 + 0][i]*bv;
                acc[1][nt] += Qs[te*4 + 1][i]*bv;
                acc[2][nt] += Qs[te*4 + 2][i]*bv;
                acc[3][nt] += Qs[te*4 + 3][i]*bv;
            }
        }
        const float scale = 0.04419417382415922f;  // (1/HEADS)*HD^-0.5
        #pragma unroll
        for (int j = 0; j < 4; j++)
            #pragma unroll
            for (int jj = 0; jj < 3; jj++) {
                int n = tn + 32*jj;
                float s = (mS[n] != 0.f) ? acc[j][jj]*scale : -1e9f;
                scoresW[((b*NE) + e0 + te*4 + j)*NN + n] = s;
            }
    }
}

// ---------------- fused attention(softmax+PV) + final MLP (proven) ----------------
__global__ __launch_bounds__(256) void k_attf(
    const float* __restrict__ scoresW, const int* __restrict__ inv,
    const float* __restrict__ virr, const float* __restrict__ gexp,
    const float* __restrict__ ow1, const float* __restrict__ ob1,
    const float* __restrict__ ow2, const float* __restrict__ ob2,
    const float* __restrict__ ow3, const float* __restrict__ ob3,
    float* __restrict__ out)
{
    int b  = blockIdx.x >> 5;
    int e0 = (blockIdx.x & 31) * 8;
    int t = threadIdx.x;
    __shared__ float aS[8][100];
    __shared__ float gS[8][84];
    __shared__ float ocS[8][84];
    __shared__ float mS[NN];
    __shared__ float inS[8][INVD];
    __shared__ float l1S[8][HID];
    __shared__ float l2S[8][HID];

    for (int p = 0; p < 3; p++) {
        int idx = t + 256*p;
        int el = idx / NN, n = idx - NN*(idx/NN);
        aS[el][n] = scoresW[((b*NE) + e0 + el)*NN + n];
    }
    if (t < 160) {
        int el = t / 20, c4 = t - 20*(t/20);
        *(float4*)&gS[el][c4*4] = *(const float4*)&gexp[(e0 + el)*OUT_DIM + c4*4];
    }
    if (t < NN) mS[t] = ((unsigned)inv[b*NN + t] < E_ATT) ? 1.0f : 0.0f;
    __syncthreads();

    {
        int el = t >> 5;
        int ng = t & 31;
        float s0 = aS[el][ng], s1 = aS[el][ng + 32], s2 = aS[el][ng + 64];
        float m0 = mS[ng], m1 = mS[ng + 32], m2 = mS[ng + 64];
        float mx = fmaxf(s0, fmaxf(s1, s2));
        #pragma unroll
        for (int off = 1; off < 32; off <<= 1) mx = fmaxf(mx, __shfl_xor(mx, off));
        float e0v = expf(s0 - mx), e1v = expf(s1 - mx), e2v = expf(s2 - mx);
        float sm = e0v + e1v + e2v;
        #pragma unroll
        for (int off = 1; off < 32; off <<= 1) sm += __shfl_xor(sm, off);
        float r = 1.0f / sm;
        float p0 = m0*e0v*r, p1 = m1*e1v*r, p2 = m2*e2v*r;
        float ss = p0 + p1 + p2;
        #pragma unroll
        for (int off = 1; off < 32; off <<= 1) ss += __shfl_xor(ss, off);
        float is = 1.0f / fmaxf(ss, 1e-8f);
        aS[el][ng]      = p0*is;
        aS[el][ng + 32] = p1*is;
        aS[el][ng + 64] = p2*is;
    }
    __syncthreads();

    if (t < 160) {
        int el = t / 20, c4 = t - 20*(t/20);
        const float* vp = virr + (long)b*NN*OUT_DIM + c4*4;
        float4 acc = make_float4(0,0,0,0);
        #pragma unroll 4
        for (int n = 0; n < NN; n++) {
            float a = aS[el][n];
            float4 v = *(const float4*)&vp[n*OUT_DIM];
            acc.x += a*v.x; acc.y += a*v.y; acc.z += a*v.z; acc.w += a*v.w;
        }
        float4 g = *(float4*)&gS[el][c4*4];
        float4 o; o.x = acc.x*g.x; o.y = acc.y*g.y; o.z = acc.z*g.z; o.w = acc.w*g.w;
        *(float4*)&ocS[el][c4*4] = o;
    }
    __syncthreads();

    for (int u = t; u < 8*INVD; u += 256) {
        int el = u / INVD, j = u - INVD*(u/INVD);
        float val;
        if (j < M0O) val = ocS[el][j];
        else {
            int o = j - M0O;
            float x = ocS[el][M0O + 3*o], y = ocS[el][M0O + 3*o + 1], zz = ocS[el][M0O + 3*o + 2];
            val = sqrtf(x*x + y*y + zz*zz + 1e-12f);
        }
        inS[el][j] = val;
    }
    __syncthreads();

    int r = t >> 5, c0 = (t & 31)*4;
    {
        float4 a0 = *(const float4*)&ob1[c0];
        float4 a1 = make_float4(0,0,0,0);
        #pragma unroll 8
        for (int i = 0; i < INVD; i += 2) {
            float x0v = inS[r][i], x1v = inS[r][i+1];
            float4 w0 = *(const float4*)&ow1[i*HID + c0];
            float4 w1 = *(const float4*)&ow1[(i+1)*HID + c0];
            a0.x += x0v*w0.x; a0.y += x0v*w0.y; a0.z += x0v*w0.z; a0.w += x0v*w0.w;
            a1.x += x1v*w1.x; a1.y += x1v*w1.y; a1.z += x1v*w1.z; a1.w += x1v*w1.w;
        }
        l1S[r][c0]   = silu_f(a0.x + a1.x); l1S[r][c0+1] = silu_f(a0.y + a1.y);
        l1S[r][c0+2] = silu_f(a0.z + a1.z); l1S[r][c0+3] = silu_f(a0.w + a1.w);
    }
    __syncthreads();
    {
        float4 a0 = *(const float4*)&ob2[c0];
        float4 a1 = make_float4(0,0,0,0);
        #pragma unroll 8
        for (int i = 0; i < HID; i += 2) {
            float x0v = l1S[r][i], x1v = l1S[r][i+1];
            float4 w0 = *(const float4*)&ow2[i*HID + c0];
            float4 w1 = *(const float4*)&ow2[(i+1)*HID + c0];
            a0.x += x0v*w0.x; a0.y += x0v*w0.y; a0.z += x0v*w0.z; a0.w += x0v*w0.w;
            a1.x += x1v*w1.x; a1.y += x1v*w1.y; a1.z += x1v*w1.z; a1.w += x1v*w1.w;
        }
        l2S[r][c0]   = silu_f(a0.x + a1.x); l2S[r][c0+1] = silu_f(a0.y + a1.y);
        l2S[r][c0+2] = silu_f(a0.z + a1.z); l2S[r][c0+3] = silu_f(a0.w + a1.w);
    }
    __syncthreads();
    {
        float4 a0 = *(const float4*)&ob3[c0];
        float4 a1 = make_float4(0,0,0,0);
        #pragma unroll 8
        for (int i = 0; i < HID; i += 2) {
            float x0v = l2S[r][i], x1v = l2S[r][i+1];
            float4 w0 = *(const float4*)&ow3[i*HID + c0];
            float4 w1 = *(const float4*)&ow3[(i+1)*HID + c0];
            a0.x += x0v*w0.x; a0.y += x0v*w0.y; a0.z += x0v*w0.z; a0.w += x0v*w0.w;
            a1.x += x1v*w1.x; a1.y += x1v*w1.y; a1.z += x1v*w1.z; a1.w += x1v*w1.w;
        }
        float4 o;
        o.x = a0.x + a1.x; o.y = a0.y + a1.y; o.z = a0.z + a1.z; o.w = a0.w + a1.w;
        *(float4*)&out[((b*NE + e0) + r)*LAT + c0] = o;
    }
}

extern "C" void kernel_launch(void* const* d_in, const int* in_sizes, int n_in,
                              void* d_out, int out_size, void* d_ws, size_t ws_size,
                              hipStream_t stream) {
    const float* h        = (const float*)d_in[0];
    const float* h_full   = (const float*)d_in[1];
    const float* e_feat   = (const float*)d_in[2];
    const float* att_dist = (const float*)d_in[3];
    const float* att_vec  = (const float*)d_in[4];
    const float* z_emb    = (const float*)d_in[5];
    const float* rw1 = (const float*)d_in[6];  const float* rb1 = (const float*)d_in[7];
    const float* rw2 = (const float*)d_in[8];  const float* rb2 = (const float*)d_in[9];
    const float* ew1 = (const float*)d_in[10]; const float* eb1 = (const float*)d_in[11];
    const float* ew2 = (const float*)d_in[12]; const float* eb2 = (const float*)d_in[13];
    const float* qw1 = (const float*)d_in[14]; const float* qb1 = (const float*)d_in[15];
    const float* qw2 = (const float*)d_in[16]; const float* qb2 = (const float*)d_in[17];
    const float* qw3 = (const float*)d_in[18]; const float* qb3 = (const float*)d_in[19];
    const float* kw1 = (const float*)d_in[20]; const float* kb1 = (const float*)d_in[21];
    const float* kw2 = (const float*)d_in[22]; const float* kb2 = (const float*)d_in[23];
    const float* kw3 = (const float*)d_in[24]; const float* kb3 = (const float*)d_in[25];
    const float* ow1 = (const float*)d_in[26]; const float* ob1 = (const float*)d_in[27];
    const float* ow2 = (const float*)d_in[28]; const float* ob2 = (const float*)d_in[29];
    const float* ow3 = (const float*)d_in[30]; const float* ob3 = (const float*)d_in[31];
    const int* z        = (const int*)d_in[32];
    const int* absorber = (const int*)d_in[34];
    const int* att_dst  = (const int*)d_in[35];

    float* ws = (float*)d_ws;
    int*   inv     = (int*)ws;                    // 1536
    float* y1E     = ws + 1536;                   // 3072
    float* envE    = ws + 4608;                   // 1024
    float* kmat    = ws + 5632;                   // 196608 (1536x128)
    float* qmat    = ws + 202240;                 // 524288 (4096x128)
    float* gexp    = ws + 726528;                 // 20480
    float* virr    = ws + 747008;                 // 122880 (1536x80)
    float* scoresW = ws + 904704;                 // 393216 (4096x96)
    __half* rw2T   = (__half*)(ws + 3657216);     // 589824 halves (4608x128)
    __half* hiddenH= (__half*)(ws + 3952128);     // 131072 halves (1024x128)

    float* out = (float*)d_out;

    k_stage1<<<STAGE1_BLKS, 256, 0, stream>>>(h, z_emb, z, absorber, e_feat,
                                              att_dst, att_dist, att_vec,
                                              rw1, rb1, kw1, kb1, kw2, kb2, kw3, kb3,
                                              qw1, qb1, qw2, qb2, qw3, qb3,
                                              ew1, eb1, ew2, eb2, rw2,
                                              hiddenH, kmat, qmat, gexp, rw2T,
                                              inv, y1E, envE);
    k_fuse<<<K2_BLKS, 256, 0, stream>>>(hiddenH, rw2T, rb2, qmat, kmat, inv,
                                        att_dst, h_full, envE, y1E, virr, scoresW);
    k_attf<<<BB*32, 256, 0, stream>>>(scoresW, inv, virr, gexp,
                                      ow1, ob1, ow2, ob2, ow3, ob3, out);
}

// Round 7
// 211.379 us; speedup vs baseline: 2.3372x; 1.0708x over previous
//
#include <hip/hip_runtime.h>
#include <hip/hip_fp16.h>
#include <math.h>

#define BB 16
#define NN 96
#define NE 256
#define FF (BB*NN)      // 1536
#define ATOM 128
#define EDIM 16
#define HID 128
#define LAT 128
#define RBFN 16
#define CUTOFF 5.0f
#define ZEMB 32
#define E_ATT 1024
#define M0I 64
#define M1I 32
#define M0O 32
#define M1O 16
#define NODE_DIM 160
#define OUT_DIM 80
#define INVD 48
#define WNUM 4608

// ---- K1 block layout: heavy classes first ----
#define K1_TP 192                   // [0,192)    fused GEMM+TP (self-contained)
#define K1_EDGE_AT 192              // [192,448)  4 edges/block: features + k-MLP
#define K1_Q_AT 448                 // [448,960)  8 q-rows/block
#define K1_GATE_AT 960              // [960,976)
#define K1_PREP_AT 976              // [976]
#define K1_BLKS 977

// TP C-panel group stride (halves): 32 tiles * 16 + 8 pad
#define CSTR2 520

typedef _Float16 half8_t __attribute__((ext_vector_type(8)));
typedef float float4v __attribute__((ext_vector_type(4)));

__device__ __forceinline__ float silu_f(float x) { return x / (1.0f + expf(-x)); }

// =======================================================================
// K1: TP(GEMM+contract) + edge k-MLP + q-MLP + gates + prep  (independent)
// =======================================================================
__global__ __launch_bounds__(256) void k1(
    const float* __restrict__ h, const float* __restrict__ h_full,
    const float* __restrict__ z_emb, const int* __restrict__ z,
    const int* __restrict__ absorber, const float* __restrict__ e_feat,
    const int* __restrict__ att_dst, const float* __restrict__ att_dist,
    const float* __restrict__ att_vec,
    const float* __restrict__ rw1, const float* __restrict__ rb1,
    const float* __restrict__ rw2, const float* __restrict__ rb2,
    const float* __restrict__ kw1, const float* __restrict__ kb1,
    const float* __restrict__ kw2, const float* __restrict__ kb2,
    const float* __restrict__ kw3, const float* __restrict__ kb3,
    const float* __restrict__ qw1, const float* __restrict__ qb1,
    const float* __restrict__ qw2, const float* __restrict__ qb2,
    const float* __restrict__ qw3, const float* __restrict__ qb3,
    const float* __restrict__ ew1, const float* __restrict__ eb1,
    const float* __restrict__ ew2, const float* __restrict__ eb2,
    float* __restrict__ kmatw, float* __restrict__ qmat,
    float* __restrict__ gexp, float* __restrict__ virr,
    int* __restrict__ inv)
{
    __shared__ __align__(16) char smemraw[36864];
    float* smem = (float*)smemraw;
    int blk = blockIdx.x;
    int t = threadIdx.x;

    if (blk < K1_TP) {
        // ---- fused tpw GEMM + tensor product, fully self-contained ----
        // cls: 0 -> out0[:,0:16) (even SEG0/SEG3 tiles); 1 -> out0[:,16:32) (odd);
        // 2 -> out1 (SEG1+SEG2). tile -> edges [tile*16, tile*16+16).
        __half* cS    = (__half*)smemraw;               // [16][CSTR2] = 16640 B
        float*  fbase = (float*)(smemraw + 16640);
        float* x0f  = fbase;                            // [16][64]
        float* x1f  = fbase + 1024;                     // [16][96]
        float* xyf  = fbase + 2560;                     // [16][32]
        float* y1f  = fbase + 3072;                     // [16][4]
        float* envf = fbase + 3136;                     // [16]
        float* dS   = fbase + 3152;                     // [16]
        int*   fI   = (int*)(fbase + 3168);             // [16]
        float* winf = fbase + 3184;                     // [16][52] -> ends 4016
        _Float16* hS = (_Float16*)(smemraw + 32704);    // [16][128] halves = 4096 B

        int cls  = blk % 3;
        int tile = blk / 3;
        int e0t = tile * 16;
        if (t < 16) {
            int e = e0t + t;
            int f = att_dst[e];
            fI[t] = f;
            float d = att_dist[e];
            dS[t] = d;
            envf[t] = (d < CUTOFF) ? 0.5f*(cosf(3.14159265358979323846f*d/CUTOFF) + 1.0f) : 0.0f;
            float vx = att_vec[3*e], vy = att_vec[3*e+1], vz = att_vec[3*e+2];
            float nrm = sqrtf(vx*vx + vy*vy + vz*vz);
            float is = 1.0f / fmaxf(nrm, 1e-8f);
            const float s3 = 1.7320508075688772f;
            y1f[t*4]   = s3*vx*is;
            y1f[t*4+1] = s3*vy*is;
            y1f[t*4+2] = s3*vz*is;
        }
        __syncthreads();
        // w_in features (49) per edge + h_full gather
        for (int u = t; u < 16*49; u += 256) {
            int e = u / 49, j = u - 49*(u/49);
            int f = fI[e];
            float v;
            if (j < ZEMB) v = z_emb[z[f]*ZEMB + j];
            else if (j == ZEMB) { int b = f / NN, nn = f - b*NN; v = (absorber[b] == nn) ? 1.0f : 0.0f; }
            else {
                int jr = j - 33;
                const float delta = CUTOFF / (RBFN - 1);
                float diff = dS[e] - jr*delta;
                v = expf(-diff*diff / (2.0f*delta*delta));
            }
            winf[e*52 + j] = v;
        }
        for (int p = 0; p < 10; p++) {
            int idx = t + 256*p;
            int edge = idx / 160, j = idx - 160*edge;
            float v = h_full[fI[edge]*NODE_DIM + j];
            if (j < M0I) x0f[edge*64 + j] = v;
            else         x1f[edge*96 + (j - M0I)] = v;
        }
        __syncthreads();
        // xy = x1 . y1
        for (int p = 0; p < 2; p++) {
            int idx = t + 256*p;
            int edge = idx >> 5, i = idx & 31;
            xyf[edge*32 + i] = x1f[edge*96 + 3*i]*y1f[edge*4]
                             + x1f[edge*96 + 3*i+1]*y1f[edge*4+1]
                             + x1f[edge*96 + 3*i+2]*y1f[edge*4+2];
        }
        // hidden = silu(w_in @ rw1 + rb1): 16 edges x 128 cols, fp16 into hS.
        // EXACT loop structure of the proven edge-block hidden (bit-identical).
        {
            int e = t >> 4;
            const float* wf = winf + e*52;
            #pragma unroll
            for (int p = 0; p < 4; p++) {
                int c2 = 2*((t & 15) + 16*p);
                float2 a0 = *(const float2*)&rb1[c2];
                float2 a1 = make_float2(0.f, 0.f);
                #pragma unroll 8
                for (int i = 0; i < 48; i += 2) {
                    float x0v = wf[i], x1v = wf[i + 1];
                    float2 w0 = *(const float2*)&rw1[i*HID + c2];
                    float2 w1 = *(const float2*)&rw1[(i+1)*HID + c2];
                    a0.x += x0v*w0.x; a0.y += x0v*w0.y;
                    a1.x += x1v*w1.x; a1.y += x1v*w1.y;
                }
                {
                    float x0v = wf[48];
                    float2 w0 = *(const float2*)&rw1[48*HID + c2];
                    a0.x += x0v*w0.x; a0.y += x0v*w0.y;
                }
                *(__half2*)&hS[e*128 + c2] =
                    __floats2half2_rn(silu_f(a0.x + a1.x), silu_f(a0.y + a1.y));
            }
        }
        __syncthreads();

        int wv = t >> 6;
        int lane = t & 63;
        int mrow = lane & 15, quad = lane >> 4;
        half8_t af[4];
        #pragma unroll
        for (int kc = 0; kc < 4; kc++)
            af[kc] = *(const half8_t*)&hS[mrow*128 + quad*8 + kc*32];

        int edge = t >> 4, o = t & 15;
        float t00 = 0.f, t11 = 0.f;
        float t01 = 0.f, tm0 = 0.f, tm1 = 0.f, tm2 = 0.f;
        int clsAdd = (cls == 1) ? 1 : 0;

        for (int g = 0; g < 3; g++) {
            // MFMA 32 tiles (8 per wave), B read directly from rw2 (transposed access,
            // 64B-granule coalesced per quarter-wave; fp16 cast == old rw2T values)
            #pragma unroll
            for (int jj = 0; jj < 8; jj++) {
                int jl = wv*8 + jj;
                int j = g*32 + jl;
                int ntg = (cls == 2) ? (128 + j)
                                     : (2*j + clsAdd + ((j >= 64) ? 96 : 0));
                const float* bcol = rw2 + ntg*16 + mrow;
                float4v acc = {0.f, 0.f, 0.f, 0.f};
                #pragma unroll
                for (int kc = 0; kc < 4; kc++) {
                    half8_t bfr;
                    #pragma unroll
                    for (int m = 0; m < 8; m++)
                        bfr[m] = (_Float16)bcol[(quad*8 + kc*32 + m)*WNUM];
                    acc = __builtin_amdgcn_mfma_f32_16x16x32_f16(af[kc], bfr, acc, 0, 0, 0);
                }
                float bias = rb2[ntg*16 + mrow];
                #pragma unroll
                for (int r = 0; r < 4; r++)
                    cS[(quad*4 + r)*CSTR2 + jl*16 + mrow] = __float2half(acc[r] + bias);
            }
            __syncthreads();
            // TP accumulate this group's 32 tiles (j ascending == proven order)
            const __half* cRow = cS + edge*CSTR2 + o;
            if (cls < 2) {
                if (g < 2) {
                    #pragma unroll 8
                    for (int jl = 0; jl < 32; jl++)
                        t00 += x0f[edge*64 + g*32 + jl]*__half2float(cRow[jl*16]);
                } else {
                    #pragma unroll 8
                    for (int jl = 0; jl < 32; jl++)
                        t11 += xyf[edge*32 + jl]*__half2float(cRow[jl*16]);
                }
            } else {
                if (g < 2) {
                    #pragma unroll 8
                    for (int jl = 0; jl < 32; jl++)
                        t01 += x0f[edge*64 + g*32 + jl]*__half2float(cRow[jl*16]);
                } else {
                    #pragma unroll 8
                    for (int jl = 0; jl < 32; jl++) {
                        float C = __half2float(cRow[jl*16]);
                        tm0 += x1f[edge*96 + 3*jl]*C;
                        tm1 += x1f[edge*96 + 3*jl+1]*C;
                        tm2 += x1f[edge*96 + 3*jl+2]*C;
                    }
                }
            }
            __syncthreads();
        }
        const float alpha = 0.10206207261596575f;  // 1/sqrt(96)
        const float ccf   = 0.5773502691896258f;   // 1/sqrt(3)
        int f = fI[edge];
        float env = envf[edge];
        if (cls < 2) {
            virr[f*OUT_DIM + cls*16 + o] = alpha*(t00 + ccf*t11)*env;
        } else {
            float y0 = y1f[edge*4], y1v = y1f[edge*4+1], y2 = y1f[edge*4+2];
            virr[f*OUT_DIM + M0O + 3*o]     = alpha*ccf*(t01*y0 + tm0)*env;
            virr[f*OUT_DIM + M0O + 3*o + 1] = alpha*ccf*(t01*y1v + tm1)*env;
            virr[f*OUT_DIM + M0O + 3*o + 2] = alpha*ccf*(t01*y2 + tm2)*env;
        }
    } else if (blk < K1_Q_AT) {
        // ---- edge features + k-MLP (R5-proven, hidden-GEMV removed) ----
        float (*sin1)[184] = (float(*)[184])smem;
        float (*l1S)[128]  = (float(*)[128])(smem + 736);
        float (*l2S)[128]  = (float(*)[128])(smem + 736 + 512);
        int w = t >> 6;
        int c = t & 63;
        int e = (blk - K1_EDGE_AT)*4 + w;
        int f = att_dst[e];
        int b = f / NN, nn = f - b*NN;
        float d = att_dist[e];
        {
            float2 hv = *(const float2*)&h[f*ATOM + 2*c];
            sin1[w][2*c] = hv.x; sin1[w][2*c + 1] = hv.y;
        }
        if (c < ZEMB) sin1[w][ATOM + c] = z_emb[z[f]*ZEMB + c];
        if (c >= 32 && c < 48) {
            int j = c - 32;
            const float delta = CUTOFF / (RBFN - 1);
            float diff = d - j*delta;
            sin1[w][ATOM + ZEMB + 1 + j] = expf(-diff*diff / (2.0f*delta*delta));
        }
        if (c == 48) sin1[w][ATOM + ZEMB] = (absorber[b] == nn) ? 1.0f : 0.0f;
        __syncthreads();
        int c2 = 2*c;
        {   // k layer 1: 177 -> 128
            float2 a0 = *(const float2*)&kb1[c2];
            float2 a1 = make_float2(0.f, 0.f);
            #pragma unroll 8
            for (int i = 0; i < 176; i += 2) {
                float x0v = sin1[w][i], x1v = sin1[w][i + 1];
                float2 w0 = *(const float2*)&kw1[i*HID + c2];
                float2 w1 = *(const float2*)&kw1[(i+1)*HID + c2];
                a0.x += x0v*w0.x; a0.y += x0v*w0.y;
                a1.x += x1v*w1.x; a1.y += x1v*w1.y;
            }
            {
                float x0v = sin1[w][176];
                float2 w0 = *(const float2*)&kw1[176*HID + c2];
                a0.x += x0v*w0.x; a0.y += x0v*w0.y;
            }
            l1S[w][c2] = silu_f(a0.x + a1.x); l1S[w][c2+1] = silu_f(a0.y + a1.y);
        }
        __syncthreads();
        {   // k layer 2
            float2 a0 = *(const float2*)&kb2[c2];
            float2 a1 = make_float2(0.f, 0.f);
            #pragma unroll 8
            for (int i = 0; i < HID; i += 2) {
                float x0v = l1S[w][i], x1v = l1S[w][i + 1];
                float2 w0 = *(const float2*)&kw2[i*HID + c2];
                float2 w1 = *(const float2*)&kw2[(i+1)*HID + c2];
                a0.x += x0v*w0.x; a0.y += x0v*w0.y;
                a1.x += x1v*w1.x; a1.y += x1v*w1.y;
            }
            l2S[w][c2] = silu_f(a0.x + a1.x); l2S[w][c2+1] = silu_f(a0.y + a1.y);
        }
        __syncthreads();
        {   // k layer 3 -> kmat
            float2 a0 = *(const float2*)&kb3[c2];
            float2 a1 = make_float2(0.f, 0.f);
            #pragma unroll 8
            for (int i = 0; i < HID; i += 2) {
                float x0v = l2S[w][i], x1v = l2S[w][i + 1];
                float2 w0 = *(const float2*)&kw3[i*HID + c2];
                float2 w1 = *(const float2*)&kw3[(i+1)*HID + c2];
                a0.x += x0v*w0.x; a0.y += x0v*w0.y;
                a1.x += x1v*w1.x; a1.y += x1v*w1.y;
            }
            float2 o; o.x = a0.x + a1.x; o.y = a0.y + a1.y;
            *(float2*)&kmatw[f*HID + c2] = o;
        }
    } else if (blk < K1_GATE_AT) {
        // ---- q-MLP (R4/R5-proven self-contained layer1) ----
        float* hA          = smem;
        float (*ef)[16]    = (float(*)[16])(smem + 128);
        float (*part)[128] = (float(*)[128])(smem + 256);
        float* l1S         = smem + 1280;
        float* l2S         = smem + 2304;
        int idx = blk - K1_Q_AT;
        int r0 = idx * 8;
        int b  = r0 >> 8;
        int e8 = r0 & 255;
        if (t < 32) *(float4*)&hA[t*4] = *(const float4*)&h[(b*NN + absorber[b])*ATOM + t*4];
        if (t >= 128 && t < 256) { int e = (t - 128) >> 4, j = t & 15; ef[e][j] = e_feat[(e8 + e)*EDIM + j]; }
        __syncthreads();
        int r = t >> 5, c0 = (t & 31)*4;
        {
            float4 a0 = make_float4(0,0,0,0);
            int k0 = r*16;
            #pragma unroll
            for (int k = 0; k < 16; k++) {
                float hv = hA[k0 + k];
                float4 w0 = *(const float4*)&qw1[(k0 + k)*HID + c0];
                a0.x += hv*w0.x; a0.y += hv*w0.y; a0.z += hv*w0.z; a0.w += hv*w0.w;
            }
            *(float4*)&part[r][c0] = a0;
        }
        __syncthreads();
        {
            float4 s = *(const float4*)&qb1[c0];
            #pragma unroll
            for (int g = 0; g < 8; g++) {
                float4 pg = *(const float4*)&part[g][c0];
                s.x += pg.x; s.y += pg.y; s.z += pg.z; s.w += pg.w;
            }
            #pragma unroll
            for (int j = 0; j < 16; j++) {
                float a = ef[r][j];
                float4 w0 = *(const float4*)&qw1[(ATOM + j)*HID + c0];
                s.x += a*w0.x; s.y += a*w0.y; s.z += a*w0.z; s.w += a*w0.w;
            }
            l1S[r*128 + c0]   = silu_f(s.x); l1S[r*128 + c0+1] = silu_f(s.y);
            l1S[r*128 + c0+2] = silu_f(s.z); l1S[r*128 + c0+3] = silu_f(s.w);
        }
        __syncthreads();
        {
            float4 a0 = *(const float4*)&qb2[c0];
            float4 a1 = make_float4(0,0,0,0);
            #pragma unroll 8
            for (int i = 0; i < HID; i += 2) {
                float x0v = l1S[r*128 + i], x1v = l1S[r*128 + i+1];
                float4 w0 = *(const float4*)&qw2[i*HID + c0];
                float4 w1 = *(const float4*)&qw2[(i+1)*HID + c0];
                a0.x += x0v*w0.x; a0.y += x0v*w0.y; a0.z += x0v*w0.z; a0.w += x0v*w0.w;
                a1.x += x1v*w1.x; a1.y += x1v*w1.y; a1.z += x1v*w1.z; a1.w += x1v*w1.w;
            }
            l2S[r*128 + c0]   = silu_f(a0.x + a1.x); l2S[r*128 + c0+1] = silu_f(a0.y + a1.y);
            l2S[r*128 + c0+2] = silu_f(a0.z + a1.z); l2S[r*128 + c0+3] = silu_f(a0.w + a1.w);
        }
        __syncthreads();
        {
            float4 a0 = *(const float4*)&qb3[c0];
            float4 a1 = make_float4(0,0,0,0);
            #pragma unroll 8
            for (int i = 0; i < HID; i += 2) {
                float x0v = l2S[r*128 + i], x1v = l2S[r*128 + i+1];
                float4 w0 = *(const float4*)&qw3[i*HID + c0];
                float4 w1 = *(const float4*)&qw3[(i+1)*HID + c0];
                a0.x += x0v*w0.x; a0.y += x0v*w0.y; a0.z += x0v*w0.z; a0.w += x0v*w0.w;
                a1.x += x1v*w1.x; a1.y += x1v*w1.y; a1.z += x1v*w1.z; a1.w += x1v*w1.w;
            }
            float4 o;
            o.x = a0.x + a1.x; o.y = a0.y + a1.y; o.z = a0.z + a1.z; o.w = a0.w + a1.w;
            *(float4*)&qmat[(r0 + r)*LAT + c0] = o;
        }
    } else if (blk < K1_PREP_AT) {
        // ---- gates (proven) ----
        float (*ef)[16]   = (float(*)[16])smem;
        float (*l1g)[128] = (float(*)[128])(smem + 256);
        float (*gg)[48]   = (float(*)[48])(smem + 256 + 2048);
        int e0 = (blk - K1_GATE_AT) * 16;
        { int e = t >> 4, i = t & 15; ef[e][i] = e_feat[(e0 + e)*EDIM + i]; }
        __syncthreads();
        int r = t >> 4, c0 = (t & 15)*8;
        {
            float4 a0 = *(const float4*)&eb1[c0];
            float4 a1 = *(const float4*)&eb1[c0 + 4];
            #pragma unroll
            for (int i = 0; i < EDIM; i++) {
                float a = ef[r][i];
                float4 w0 = *(const float4*)&ew1[i*HID + c0];
                float4 w1 = *(const float4*)&ew1[i*HID + c0 + 4];
                a0.x += a*w0.x; a0.y += a*w0.y; a0.z += a*w0.z; a0.w += a*w0.w;
                a1.x += a*w1.x; a1.y += a*w1.y; a1.z += a*w1.z; a1.w += a*w1.w;
            }
            l1g[r][c0]   = silu_f(a0.x); l1g[r][c0+1] = silu_f(a0.y);
            l1g[r][c0+2] = silu_f(a0.z); l1g[r][c0+3] = silu_f(a0.w);
            l1g[r][c0+4] = silu_f(a1.x); l1g[r][c0+5] = silu_f(a1.y);
            l1g[r][c0+6] = silu_f(a1.z); l1g[r][c0+7] = silu_f(a1.w);
        }
        __syncthreads();
        for (int u = t; u < 16*48; u += 256) {
            int e = u / 48, j = u - 48*(u/48);
            float acc = eb2[j];
            #pragma unroll 4
            for (int i = 0; i < HID; i++) acc += l1g[e][i]*ew2[i*48 + j];
            gg[e][j] = acc;
        }
        __syncthreads();
        for (int u = t; u < 16*80; u += 256) {
            int e = u / 80, cc = u - 80*(u/80);
            gexp[(e0 + e)*OUT_DIM + cc] = (cc < M0O) ? gg[e][cc] : gg[e][M0O + (cc - M0O)/3];
        }
    } else {
        // ---- prep: inv init + scatter ----
        for (int p = 0; p < 6; p++) inv[t + 256*p] = -1;
        __syncthreads();
        for (int p = 0; p < 4; p++) { int e = t + 256*p; inv[att_dst[e]] = e; }
    }
}

// =======================================================================
// K2: in-block scores GEMM + softmax + PV + final MLP
// =======================================================================
__global__ __launch_bounds__(256) void k_attf(
    const float* __restrict__ qmat, const float* __restrict__ kmat,
    const int* __restrict__ inv,
    const float* __restrict__ virr, const float* __restrict__ gexp,
    const float* __restrict__ ow1, const float* __restrict__ ob1,
    const float* __restrict__ ow2, const float* __restrict__ ob2,
    const float* __restrict__ ow3, const float* __restrict__ ob3,
    float* __restrict__ out)
{
    int b  = blockIdx.x >> 5;
    int e0 = (blockIdx.x & 31) * 8;
    int t = threadIdx.x;
    __shared__ float smem[7936];
    float (*aS)[100]   = (float(*)[100])smem;            // 800
    float (*gS)[84]    = (float(*)[84])(smem + 800);     // 672
    float (*ocS)[84]   = (float(*)[84])(smem + 1472);    // 672
    float* mS          = smem + 2144;                    // 96
    float (*inS)[INVD] = (float(*)[INVD])(smem + 2240);  // 384
    float (*q8)[132]   = (float(*)[132])(smem + 2624);   // 1056 -> 3680
    float* Kt          = smem + 3680;                    // [32][133]=4256 (scores phase)
    float (*l1S)[HID]  = (float(*)[HID])(smem + 3680);   // alias (MLP phase)
    float (*l2S)[HID]  = (float(*)[HID])(smem + 3680 + 1024);

    if (t < 160) {
        int el = t / 20, c4 = t - 20*(t/20);
        *(float4*)&gS[el][c4*4] = *(const float4*)&gexp[(e0 + el)*OUT_DIM + c4*4];
    }
    if (t < NN) mS[t] = ((unsigned)inv[b*NN + t] < E_ATT) ? 1.0f : 0.0f;
    {
        int el = t >> 5, i4 = t & 31;
        *(float4*)&q8[el][i4*4] = *(const float4*)&qmat[(b*NE + e0 + el)*LAT + i4*4];
    }

    // ---- scores: 8 e-rows x 96 n, K staged in conflict-free stride-133 tiles ----
    int el = t >> 5, tn = t & 31;
    float sacc0 = 0.f, sacc1 = 0.f, sacc2 = 0.f;
    #pragma unroll
    for (int nt = 0; nt < 3; nt++) {
        __syncthreads();
        for (int p = 0; p < 4; p++) {
            int idx = t + 256*p; int n = idx >> 5, i4 = idx & 31;
            *(float4*)&Kt[n*133 + i4*4] = *(const float4*)&kmat[(b*NN + nt*32 + n)*LAT + i4*4];
        }
        __syncthreads();
        float acc = 0.f;
        for (int i = 0; i < LAT; i++) acc += q8[el][i]*Kt[tn*133 + i];
        if (nt == 0) sacc0 = acc; else if (nt == 1) sacc1 = acc; else sacc2 = acc;
    }

    // ---- masked scores + softmax (registers; same op order as proven) ----
    {
        const float scale = 0.04419417382415922f;  // (1/HEADS)*HD^-0.5
        int ng = tn;
        float m0 = mS[ng], m1 = mS[ng + 32], m2 = mS[ng + 64];
        float s0 = (m0 != 0.f) ? sacc0*scale : -1e9f;
        float s1 = (m1 != 0.f) ? sacc1*scale : -1e9f;
        float s2 = (m2 != 0.f) ? sacc2*scale : -1e9f;
        float mx = fmaxf(s0, fmaxf(s1, s2));
        #pragma unroll
        for (int off = 1; off < 32; off <<= 1) mx = fmaxf(mx, __shfl_xor(mx, off));
        float e0v = expf(s0 - mx), e1v = expf(s1 - mx), e2v = expf(s2 - mx);
        float sm = e0v + e1v + e2v;
        #pragma unroll
        for (int off = 1; off < 32; off <<= 1) sm += __shfl_xor(sm, off);
        float r = 1.0f / sm;
        float p0 = m0*e0v*r, p1 = m1*e1v*r, p2 = m2*e2v*r;
        float ss = p0 + p1 + p2;
        #pragma unroll
        for (int off = 1; off < 32; off <<= 1) ss += __shfl_xor(ss, off);
        float is = 1.0f / fmaxf(ss, 1e-8f);
        aS[el][ng]      = p0*is;
        aS[el][ng + 32] = p1*is;
        aS[el][ng + 64] = p2*is;
    }
    __syncthreads();

    if (t < 160) {
        int el2 = t / 20, c4 = t - 20*(t/20);
        const float* vp = virr + (long)b*NN*OUT_DIM + c4*4;
        float4 acc = make_float4(0,0,0,0);
        #pragma unroll 4
        for (int n = 0; n < NN; n++) {
            float a = aS[el2][n];
            float4 v = *(const float4*)&vp[n*OUT_DIM];
            acc.x += a*v.x; acc.y += a*v.y; acc.z += a*v.z; acc.w += a*v.w;
        }
        float4 g = *(float4*)&gS[el2][c4*4];
        float4 o; o.x = acc.x*g.x; o.y = acc.y*g.y; o.z = acc.z*g.z; o.w = acc.w*g.w;
        *(float4*)&ocS[el2][c4*4] = o;
    }
    __syncthreads();

    for (int u = t; u < 8*INVD; u += 256) {
        int el2 = u / INVD, j = u - INVD*(u/INVD);
        float val;
        if (j < M0O) val = ocS[el2][j];
        else {
            int o = j - M0O;
            float x = ocS[el2][M0O + 3*o], y = ocS[el2][M0O + 3*o + 1], zz = ocS[el2][M0O + 3*o + 2];
            val = sqrtf(x*x + y*y + zz*zz + 1e-12f);
        }
        inS[el2][j] = val;
    }
    __syncthreads();

    int r = t >> 5, c0 = (t & 31)*4;
    {
        float4 a0 = *(const float4*)&ob1[c0];
        float4 a1 = make_float4(0,0,0,0);
        #pragma unroll 8
        for (int i = 0; i < INVD; i += 2) {
            float x0v = inS[r][i], x1v = inS[r][i+1];
            float4 w0 = *(const float4*)&ow1[i*HID + c0];
            float4 w1 = *(const float4*)&ow1[(i+1)*HID + c0];
            a0.x += x0v*w0.x; a0.y += x0v*w0.y; a0.z += x0v*w0.z; a0.w += x0v*w0.w;
            a1.x += x1v*w1.x; a1.y += x1v*w1.y; a1.z += x1v*w1.z; a1.w += x1v*w1.w;
        }
        l1S[r][c0]   = silu_f(a0.x + a1.x); l1S[r][c0+1] = silu_f(a0.y + a1.y);
        l1S[r][c0+2] = silu_f(a0.z + a1.z); l1S[r][c0+3] = silu_f(a0.w + a1.w);
    }
    __syncthreads();
    {
        float4 a0 = *(const float4*)&ob2[c0];
        float4 a1 = make_float4(0,0,0,0);
        #pragma unroll 8
        for (int i = 0; i < HID; i += 2) {
            float x0v = l1S[r][i], x1v = l1S[r][i+1];
            float4 w0 = *(const float4*)&ow2[i*HID + c0];
            float4 w1 = *(const float4*)&ow2[(i+1)*HID + c0];
            a0.x += x0v*w0.x; a0.y += x0v*w0.y; a0.z += x0v*w0.z; a0.w += x0v*w0.w;
            a1.x += x1v*w1.x; a1.y += x1v*w1.y; a1.z += x1v*w1.z; a1.w += x1v*w1.w;
        }
        l2S[r][c0]   = silu_f(a0.x + a1.x); l2S[r][c0+1] = silu_f(a0.y + a1.y);
        l2S[r][c0+2] = silu_f(a0.z + a1.z); l2S[r][c0+3] = silu_f(a0.w + a1.w);
    }
    __syncthreads();
    {
        float4 a0 = *(const float4*)&ob3[c0];
        float4 a1 = make_float4(0,0,0,0);
        #pragma unroll 8
        for (int i = 0; i < HID; i += 2) {
            float x0v = l2S[r][i], x1v = l2S[r][i+1];
            float4 w0 = *(const float4*)&ow3[i*HID + c0];
            float4 w1 = *(const float4*)&ow3[(i+1)*HID + c0];
            a0.x += x0v*w0.x; a0.y += x0v*w0.y; a0.z += x0v*w0.z; a0.w += x0v*w0.w;
            a1.x += x1v*w1.x; a1.y += x1v*w1.y; a1.z += x1v*w1.z; a1.w += x1v*w1.w;
        }
        float4 o;
        o.x = a0.x + a1.x; o.y = a0.y + a1.y; o.z = a0.z + a1.z; o.w = a0.w + a1.w;
        *(float4*)&out[((b*NE + e0) + r)*LAT + c0] = o;
    }
}

extern "C" void kernel_launch(void* const* d_in, const int* in_sizes, int n_in,
                              void* d_out, int out_size, void* d_ws, size_t ws_size,
                              hipStream_t stream) {
    const float* h        = (const float*)d_in[0];
    const float* h_full   = (const float*)d_in[1];
    const float* e_feat   = (const float*)d_in[2];
    const float* att_dist = (const float*)d_in[3];
    const float* att_vec  = (const float*)d_in[4];
    const float* z_emb    = (const float*)d_in[5];
    const float* rw1 = (const float*)d_in[6];  const float* rb1 = (const float*)d_in[7];
    const float* rw2 = (const float*)d_in[8];  const float* rb2 = (const float*)d_in[9];
    const float* ew1 = (const float*)d_in[10]; const float* eb1 = (const float*)d_in[11];
    const float* ew2 = (const float*)d_in[12]; const float* eb2 = (const float*)d_in[13];
    const float* qw1 = (const float*)d_in[14]; const float* qb1 = (const float*)d_in[15];
    const float* qw2 = (const float*)d_in[16]; const float* qb2 = (const float*)d_in[17];
    const float* qw3 = (const float*)d_in[18]; const float* qb3 = (const float*)d_in[19];
    const float* kw1 = (const float*)d_in[20]; const float* kb1 = (const float*)d_in[21];
    const float* kw2 = (const float*)d_in[22]; const float* kb2 = (const float*)d_in[23];
    const float* kw3 = (const float*)d_in[24]; const float* kb3 = (const float*)d_in[25];
    const float* ow1 = (const float*)d_in[26]; const float* ob1 = (const float*)d_in[27];
    const float* ow2 = (const float*)d_in[28]; const float* ob2 = (const float*)d_in[29];
    const float* ow3 = (const float*)d_in[30]; const float* ob3 = (const float*)d_in[31];
    const int* z        = (const int*)d_in[32];
    const int* absorber = (const int*)d_in[34];
    const int* att_dst  = (const int*)d_in[35];

    float* ws = (float*)d_ws;
    int*   inv     = (int*)ws;                    // 1536
    float* kmat    = ws + 5632;                   // 196608 (1536x128)
    float* qmat    = ws + 202240;                 // 524288 (4096x128)
    float* gexp    = ws + 726528;                 // 20480
    float* virr    = ws + 747008;                 // 122880 (1536x80)

    float* out = (float*)d_out;

    k1<<<K1_BLKS, 256, 0, stream>>>(h, h_full, z_emb, z, absorber, e_feat,
                                    att_dst, att_dist, att_vec,
                                    rw1, rb1, rw2, rb2,
                                    kw1, kb1, kw2, kb2, kw3, kb3,
                                    qw1, qb1, qw2, qb2, qw3, qb3,
                                    ew1, eb1, ew2, eb2,
                                    kmat, qmat, gexp, virr, inv);
    k_attf<<<BB*32, 256, 0, stream>>>(qmat, kmat, inv, virr, gexp,
                                      ow1, ob1, ow2, ob2, ow3, ob3, out);
}

// Round 8
// 210.978 us; speedup vs baseline: 2.3416x; 1.0019x over previous
//
#include <hip/hip_runtime.h>
#include <hip/hip_fp16.h>
#include <math.h>

#define BB 16
#define NN 96
#define NE 256
#define FF (BB*NN)      // 1536
#define ATOM 128
#define EDIM 16
#define HID 128
#define LAT 128
#define RBFN 16
#define CUTOFF 5.0f
#define ZEMB 32
#define E_ATT 1024
#define M0I 64
#define M1I 32
#define M0O 32
#define M1O 16
#define NODE_DIM 160
#define OUT_DIM 80
#define INVD 48
#define WNUM 4608

// ---- K1 block layout ----
#define K1_TP 192                   // [0,192)    fused GEMM+TP (self-contained)
#define K1_EDGE_AT 192              // [192,448)  4 edges/block: features + k-MLP
#define K1_Q_AT 448                 // [448,960)  8 q-rows/block
#define K1_GATE_AT 960              // [960,976)
#define K1_PREP_AT 976              // [976]
#define K1_BLKS 977

typedef _Float16 half8_t __attribute__((ext_vector_type(8)));
typedef float float4v __attribute__((ext_vector_type(4)));

__device__ __forceinline__ float silu_f(float x) { return x / (1.0f + expf(-x)); }

// =======================================================================
// K1: TP(GEMM+contract) + edge k-MLP + q-MLP + gates + prep  (independent)
// Static LDS cut to 21248 B (was 36864) -> 7 blocks/CU instead of 4.
// =======================================================================
__global__ __launch_bounds__(256) void k1(
    const float* __restrict__ h, const float* __restrict__ h_full,
    const float* __restrict__ z_emb, const int* __restrict__ z,
    const int* __restrict__ absorber, const float* __restrict__ e_feat,
    const int* __restrict__ att_dst, const float* __restrict__ att_dist,
    const float* __restrict__ att_vec,
    const float* __restrict__ rw1, const float* __restrict__ rb1,
    const float* __restrict__ rw2, const float* __restrict__ rb2,
    const float* __restrict__ kw1, const float* __restrict__ kb1,
    const float* __restrict__ kw2, const float* __restrict__ kb2,
    const float* __restrict__ kw3, const float* __restrict__ kb3,
    const float* __restrict__ qw1, const float* __restrict__ qb1,
    const float* __restrict__ qw2, const float* __restrict__ qb2,
    const float* __restrict__ qw3, const float* __restrict__ qb3,
    const float* __restrict__ ew1, const float* __restrict__ eb1,
    const float* __restrict__ ew2, const float* __restrict__ eb2,
    float* __restrict__ kmatw, float* __restrict__ qmat,
    float* __restrict__ gexp, float* __restrict__ virr,
    int* __restrict__ inv)
{
    __shared__ __align__(16) char smemraw[21248];
    float* smem = (float*)smemraw;
    int blk = blockIdx.x;
    int t = threadIdx.x;

    if (blk < K1_TP) {
        // ---- fused tpw GEMM + tensor product (R5 group loop + R7 operand sourcing) ----
        // cls: 0 -> out0[:,0:16) (even SEG0/SEG3 tiles); 1 -> out0[:,16:32) (odd);
        // 2 -> out1 (SEG1+SEG2). tile -> edges [tile*16, tile*16+16).
        __half* cS   = (__half*)smemraw;                // [16][136] halves = 4352 B (MFMA phase)
        float*  winf = (float*)smemraw;                 // [16][52] floats = 3328 B (aliases cS; dead before MFMA)
        float*  fbase = (float*)smemraw + 1088;
        float* x0f  = fbase;                            // [16][64]
        float* x1f  = fbase + 1024;                     // [16][96]
        float* xyf  = fbase + 2560;                     // [16][32]
        float* y1f  = fbase + 3072;                     // [16][4]
        float* envf = fbase + 3136;                     // [16]
        float* dS   = fbase + 3152;                     // [16]
        int*   fI   = (int*)(fbase + 3168);             // [16]
        _Float16* hS = (_Float16*)(smemraw + 17088);    // [16][128] halves = 4096 B -> 21184

        int cls  = blk % 3;
        int tile = blk / 3;
        int e0t = tile * 16;
        if (t < 16) {
            int e = e0t + t;
            int f = att_dst[e];
            fI[t] = f;
            float d = att_dist[e];
            dS[t] = d;
            envf[t] = (d < CUTOFF) ? 0.5f*(cosf(3.14159265358979323846f*d/CUTOFF) + 1.0f) : 0.0f;
            float vx = att_vec[3*e], vy = att_vec[3*e+1], vz = att_vec[3*e+2];
            float nrm = sqrtf(vx*vx + vy*vy + vz*vz);
            float is = 1.0f / fmaxf(nrm, 1e-8f);
            const float s3 = 1.7320508075688772f;
            y1f[t*4]   = s3*vx*is;
            y1f[t*4+1] = s3*vy*is;
            y1f[t*4+2] = s3*vz*is;
        }
        __syncthreads();
        // w_in features (49) per edge + h_full gather
        for (int u = t; u < 16*49; u += 256) {
            int e = u / 49, j = u - 49*(u/49);
            int f = fI[e];
            float v;
            if (j < ZEMB) v = z_emb[z[f]*ZEMB + j];
            else if (j == ZEMB) { int b = f / NN, nn = f - b*NN; v = (absorber[b] == nn) ? 1.0f : 0.0f; }
            else {
                int jr = j - 33;
                const float delta = CUTOFF / (RBFN - 1);
                float diff = dS[e] - jr*delta;
                v = expf(-diff*diff / (2.0f*delta*delta));
            }
            winf[e*52 + j] = v;
        }
        for (int p = 0; p < 10; p++) {
            int idx = t + 256*p;
            int edge = idx / 160, j = idx - 160*edge;
            float v = h_full[fI[edge]*NODE_DIM + j];
            if (j < M0I) x0f[edge*64 + j] = v;
            else         x1f[edge*96 + (j - M0I)] = v;
        }
        __syncthreads();
        // xy = x1 . y1
        for (int p = 0; p < 2; p++) {
            int idx = t + 256*p;
            int edge = idx >> 5, i = idx & 31;
            xyf[edge*32 + i] = x1f[edge*96 + 3*i]*y1f[edge*4]
                             + x1f[edge*96 + 3*i+1]*y1f[edge*4+1]
                             + x1f[edge*96 + 3*i+2]*y1f[edge*4+2];
        }
        // hidden = silu(w_in @ rw1 + rb1): 16 edges x 128 cols, fp16 into hS (R7-proven)
        {
            int e = t >> 4;
            const float* wf = winf + e*52;
            #pragma unroll
            for (int p = 0; p < 4; p++) {
                int c2 = 2*((t & 15) + 16*p);
                float2 a0 = *(const float2*)&rb1[c2];
                float2 a1 = make_float2(0.f, 0.f);
                #pragma unroll 8
                for (int i = 0; i < 48; i += 2) {
                    float x0v = wf[i], x1v = wf[i + 1];
                    float2 w0 = *(const float2*)&rw1[i*HID + c2];
                    float2 w1 = *(const float2*)&rw1[(i+1)*HID + c2];
                    a0.x += x0v*w0.x; a0.y += x0v*w0.y;
                    a1.x += x1v*w1.x; a1.y += x1v*w1.y;
                }
                {
                    float x0v = wf[48];
                    float2 w0 = *(const float2*)&rw1[48*HID + c2];
                    a0.x += x0v*w0.x; a0.y += x0v*w0.y;
                }
                *(__half2*)&hS[e*128 + c2] =
                    __floats2half2_rn(silu_f(a0.x + a1.x), silu_f(a0.y + a1.y));
            }
        }
        __syncthreads();   // winf now dead; cS region free for MFMA writes

        int wv = t >> 6;
        int lane = t & 63;
        int mrow = lane & 15, quad = lane >> 4;
        half8_t af[4];
        #pragma unroll
        for (int kc = 0; kc < 4; kc++)
            af[kc] = *(const half8_t*)&hS[mrow*128 + quad*8 + kc*32];

        int edge = t >> 4, o = t & 15;
        float t00 = 0.f, t11 = 0.f;
        float t01 = 0.f, tm0 = 0.f, tm1 = 0.f, tm2 = 0.f;
        int clsAdd = (cls == 1) ? 1 : 0;

        for (int g = 0; g < 12; g++) {
            // ---- MFMA phase: wave wv computes local tiles {2wv, 2wv+1} (R5 layout) ----
            #pragma unroll
            for (int sub = 0; sub < 2; sub++) {
                int ntl = 2*wv + sub;          // local tile 0..7
                int j = g*8 + ntl;             // 0..95
                int ntg = (cls == 2) ? (128 + j)
                                     : (2*j + clsAdd + ((j >= 64) ? 96 : 0));
                const float* bcol = rw2 + ntg*16 + mrow;
                float4v acc = {0.f, 0.f, 0.f, 0.f};
                #pragma unroll
                for (int kc = 0; kc < 4; kc++) {
                    half8_t bfr;
                    #pragma unroll
                    for (int m = 0; m < 8; m++)
                        bfr[m] = (_Float16)bcol[(quad*8 + kc*32 + m)*WNUM];
                    acc = __builtin_amdgcn_mfma_f32_16x16x32_f16(af[kc], bfr, acc, 0, 0, 0);
                }
                float bias = rb2[ntg*16 + mrow];
                #pragma unroll
                for (int r = 0; r < 4; r++)
                    cS[(quad*4 + r)*136 + ntl*16 + mrow] = __float2half(acc[r] + bias);
            }
            __syncthreads();
            // ---- TP phase: thread owns (edge, o) (R5-proven order) ----
            const __half* cRow = cS + edge*136 + o;
            if (cls < 2) {
                if (g < 8) {
                    #pragma unroll
                    for (int nt = 0; nt < 8; nt++)
                        t00 += x0f[edge*64 + g*8 + nt]*__half2float(cRow[nt*16]);
                } else {
                    #pragma unroll
                    for (int nt = 0; nt < 8; nt++)
                        t11 += xyf[edge*32 + (g*8 + nt - 64)]*__half2float(cRow[nt*16]);
                }
            } else {
                if (g < 8) {
                    #pragma unroll
                    for (int nt = 0; nt < 8; nt++)
                        t01 += x0f[edge*64 + g*8 + nt]*__half2float(cRow[nt*16]);
                } else {
                    #pragma unroll
                    for (int nt = 0; nt < 8; nt++) {
                        int i = g*8 + nt - 64;
                        float C = __half2float(cRow[nt*16]);
                        tm0 += x1f[edge*96 + 3*i]*C;
                        tm1 += x1f[edge*96 + 3*i+1]*C;
                        tm2 += x1f[edge*96 + 3*i+2]*C;
                    }
                }
            }
            __syncthreads();
        }
        const float alpha = 0.10206207261596575f;  // 1/sqrt(96)
        const float ccf   = 0.5773502691896258f;   // 1/sqrt(3)
        int f = fI[edge];
        float env = envf[edge];
        if (cls < 2) {
            virr[f*OUT_DIM + cls*16 + o] = alpha*(t00 + ccf*t11)*env;
        } else {
            float y0 = y1f[edge*4], y1v = y1f[edge*4+1], y2 = y1f[edge*4+2];
            virr[f*OUT_DIM + M0O + 3*o]     = alpha*ccf*(t01*y0 + tm0)*env;
            virr[f*OUT_DIM + M0O + 3*o + 1] = alpha*ccf*(t01*y1v + tm1)*env;
            virr[f*OUT_DIM + M0O + 3*o + 2] = alpha*ccf*(t01*y2 + tm2)*env;
        }
    } else if (blk < K1_Q_AT) {
        // ---- edge features + k-MLP (proven verbatim) ----
        float (*sin1)[184] = (float(*)[184])smem;
        float (*l1S)[128]  = (float(*)[128])(smem + 736);
        float (*l2S)[128]  = (float(*)[128])(smem + 736 + 512);
        int w = t >> 6;
        int c = t & 63;
        int e = (blk - K1_EDGE_AT)*4 + w;
        int f = att_dst[e];
        int b = f / NN, nn = f - b*NN;
        float d = att_dist[e];
        {
            float2 hv = *(const float2*)&h[f*ATOM + 2*c];
            sin1[w][2*c] = hv.x; sin1[w][2*c + 1] = hv.y;
        }
        if (c < ZEMB) sin1[w][ATOM + c] = z_emb[z[f]*ZEMB + c];
        if (c >= 32 && c < 48) {
            int j = c - 32;
            const float delta = CUTOFF / (RBFN - 1);
            float diff = d - j*delta;
            sin1[w][ATOM + ZEMB + 1 + j] = expf(-diff*diff / (2.0f*delta*delta));
        }
        if (c == 48) sin1[w][ATOM + ZEMB] = (absorber[b] == nn) ? 1.0f : 0.0f;
        __syncthreads();
        int c2 = 2*c;
        {   // k layer 1: 177 -> 128
            float2 a0 = *(const float2*)&kb1[c2];
            float2 a1 = make_float2(0.f, 0.f);
            #pragma unroll 8
            for (int i = 0; i < 176; i += 2) {
                float x0v = sin1[w][i], x1v = sin1[w][i + 1];
                float2 w0 = *(const float2*)&kw1[i*HID + c2];
                float2 w1 = *(const float2*)&kw1[(i+1)*HID + c2];
                a0.x += x0v*w0.x; a0.y += x0v*w0.y;
                a1.x += x1v*w1.x; a1.y += x1v*w1.y;
            }
            {
                float x0v = sin1[w][176];
                float2 w0 = *(const float2*)&kw1[176*HID + c2];
                a0.x += x0v*w0.x; a0.y += x0v*w0.y;
            }
            l1S[w][c2] = silu_f(a0.x + a1.x); l1S[w][c2+1] = silu_f(a0.y + a1.y);
        }
        __syncthreads();
        {   // k layer 2
            float2 a0 = *(const float2*)&kb2[c2];
            float2 a1 = make_float2(0.f, 0.f);
            #pragma unroll 8
            for (int i = 0; i < HID; i += 2) {
                float x0v = l1S[w][i], x1v = l1S[w][i + 1];
                float2 w0 = *(const float2*)&kw2[i*HID + c2];
                float2 w1 = *(const float2*)&kw2[(i+1)*HID + c2];
                a0.x += x0v*w0.x; a0.y += x0v*w0.y;
                a1.x += x1v*w1.x; a1.y += x1v*w1.y;
            }
            l2S[w][c2] = silu_f(a0.x + a1.x); l2S[w][c2+1] = silu_f(a0.y + a1.y);
        }
        __syncthreads();
        {   // k layer 3 -> kmat
            float2 a0 = *(const float2*)&kb3[c2];
            float2 a1 = make_float2(0.f, 0.f);
            #pragma unroll 8
            for (int i = 0; i < HID; i += 2) {
                float x0v = l2S[w][i], x1v = l2S[w][i + 1];
                float2 w0 = *(const float2*)&kw3[i*HID + c2];
                float2 w1 = *(const float2*)&kw3[(i+1)*HID + c2];
                a0.x += x0v*w0.x; a0.y += x0v*w0.y;
                a1.x += x1v*w1.x; a1.y += x1v*w1.y;
            }
            float2 o; o.x = a0.x + a1.x; o.y = a0.y + a1.y;
            *(float2*)&kmatw[f*HID + c2] = o;
        }
    } else if (blk < K1_GATE_AT) {
        // ---- q-MLP (proven verbatim) ----
        float* hA          = smem;
        float (*ef)[16]    = (float(*)[16])(smem + 128);
        float (*part)[128] = (float(*)[128])(smem + 256);
        float* l1S         = smem + 1280;
        float* l2S         = smem + 2304;
        int idx = blk - K1_Q_AT;
        int r0 = idx * 8;
        int b  = r0 >> 8;
        int e8 = r0 & 255;
        if (t < 32) *(float4*)&hA[t*4] = *(const float4*)&h[(b*NN + absorber[b])*ATOM + t*4];
        if (t >= 128 && t < 256) { int e = (t - 128) >> 4, j = t & 15; ef[e][j] = e_feat[(e8 + e)*EDIM + j]; }
        __syncthreads();
        int r = t >> 5, c0 = (t & 31)*4;
        {
            float4 a0 = make_float4(0,0,0,0);
            int k0 = r*16;
            #pragma unroll
            for (int k = 0; k < 16; k++) {
                float hv = hA[k0 + k];
                float4 w0 = *(const float4*)&qw1[(k0 + k)*HID + c0];
                a0.x += hv*w0.x; a0.y += hv*w0.y; a0.z += hv*w0.z; a0.w += hv*w0.w;
            }
            *(float4*)&part[r][c0] = a0;
        }
        __syncthreads();
        {
            float4 s = *(const float4*)&qb1[c0];
            #pragma unroll
            for (int g = 0; g < 8; g++) {
                float4 pg = *(const float4*)&part[g][c0];
                s.x += pg.x; s.y += pg.y; s.z += pg.z; s.w += pg.w;
            }
            #pragma unroll
            for (int j = 0; j < 16; j++) {
                float a = ef[r][j];
                float4 w0 = *(const float4*)&qw1[(ATOM + j)*HID + c0];
                s.x += a*w0.x; s.y += a*w0.y; s.z += a*w0.z; s.w += a*w0.w;
            }
            l1S[r*128 + c0]   = silu_f(s.x); l1S[r*128 + c0+1] = silu_f(s.y);
            l1S[r*128 + c0+2] = silu_f(s.z); l1S[r*128 + c0+3] = silu_f(s.w);
        }
        __syncthreads();
        {
            float4 a0 = *(const float4*)&qb2[c0];
            float4 a1 = make_float4(0,0,0,0);
            #pragma unroll 8
            for (int i = 0; i < HID; i += 2) {
                float x0v = l1S[r*128 + i], x1v = l1S[r*128 + i+1];
                float4 w0 = *(const float4*)&qw2[i*HID + c0];
                float4 w1 = *(const float4*)&qw2[(i+1)*HID + c0];
                a0.x += x0v*w0.x; a0.y += x0v*w0.y; a0.z += x0v*w0.z; a0.w += x0v*w0.w;
                a1.x += x1v*w1.x; a1.y += x1v*w1.y; a1.z += x1v*w1.z; a1.w += x1v*w1.w;
            }
            l2S[r*128 + c0]   = silu_f(a0.x + a1.x); l2S[r*128 + c0+1] = silu_f(a0.y + a1.y);
            l2S[r*128 + c0+2] = silu_f(a0.z + a1.z); l2S[r*128 + c0+3] = silu_f(a0.w + a1.w);
        }
        __syncthreads();
        {
            float4 a0 = *(const float4*)&qb3[c0];
            float4 a1 = make_float4(0,0,0,0);
            #pragma unroll 8
            for (int i = 0; i < HID; i += 2) {
                float x0v = l2S[r*128 + i], x1v = l2S[r*128 + i+1];
                float4 w0 = *(const float4*)&qw3[i*HID + c0];
                float4 w1 = *(const float4*)&qw3[(i+1)*HID + c0];
                a0.x += x0v*w0.x; a0.y += x0v*w0.y; a0.z += x0v*w0.z; a0.w += x0v*w0.w;
                a1.x += x1v*w1.x; a1.y += x1v*w1.y; a1.z += x1v*w1.z; a1.w += x1v*w1.w;
            }
            float4 o;
            o.x = a0.x + a1.x; o.y = a0.y + a1.y; o.z = a0.z + a1.z; o.w = a0.w + a1.w;
            *(float4*)&qmat[(r0 + r)*LAT + c0] = o;
        }
    } else if (blk < K1_PREP_AT) {
        // ---- gates (proven verbatim) ----
        float (*ef)[16]   = (float(*)[16])smem;
        float (*l1g)[128] = (float(*)[128])(smem + 256);
        float (*gg)[48]   = (float(*)[48])(smem + 256 + 2048);
        int e0 = (blk - K1_GATE_AT) * 16;
        { int e = t >> 4, i = t & 15; ef[e][i] = e_feat[(e0 + e)*EDIM + i]; }
        __syncthreads();
        int r = t >> 4, c0 = (t & 15)*8;
        {
            float4 a0 = *(const float4*)&eb1[c0];
            float4 a1 = *(const float4*)&eb1[c0 + 4];
            #pragma unroll
            for (int i = 0; i < EDIM; i++) {
                float a = ef[r][i];
                float4 w0 = *(const float4*)&ew1[i*HID + c0];
                float4 w1 = *(const float4*)&ew1[i*HID + c0 + 4];
                a0.x += a*w0.x; a0.y += a*w0.y; a0.z += a*w0.z; a0.w += a*w0.w;
                a1.x += a*w1.x; a1.y += a*w1.y; a1.z += a*w1.z; a1.w += a*w1.w;
            }
            l1g[r][c0]   = silu_f(a0.x); l1g[r][c0+1] = silu_f(a0.y);
            l1g[r][c0+2] = silu_f(a0.z); l1g[r][c0+3] = silu_f(a0.w);
            l1g[r][c0+4] = silu_f(a1.x); l1g[r][c0+5] = silu_f(a1.y);
            l1g[r][c0+6] = silu_f(a1.z); l1g[r][c0+7] = silu_f(a1.w);
        }
        __syncthreads();
        for (int u = t; u < 16*48; u += 256) {
            int e = u / 48, j = u - 48*(u/48);
            float acc = eb2[j];
            #pragma unroll 4
            for (int i = 0; i < HID; i++) acc += l1g[e][i]*ew2[i*48 + j];
            gg[e][j] = acc;
        }
        __syncthreads();
        for (int u = t; u < 16*80; u += 256) {
            int e = u / 80, cc = u - 80*(u/80);
            gexp[(e0 + e)*OUT_DIM + cc] = (cc < M0O) ? gg[e][cc] : gg[e][M0O + (cc - M0O)/3];
        }
    } else {
        // ---- prep: inv init + scatter ----
        for (int p = 0; p < 6; p++) inv[t + 256*p] = -1;
        __syncthreads();
        for (int p = 0; p < 4; p++) { int e = t + 256*p; inv[att_dst[e]] = e; }
    }
}

// =======================================================================
// K2: in-block scores GEMM + softmax + PV + final MLP
// =======================================================================
__global__ __launch_bounds__(256) void k_attf(
    const float* __restrict__ qmat, const float* __restrict__ kmat,
    const int* __restrict__ inv,
    const float* __restrict__ virr, const float* __restrict__ gexp,
    const float* __restrict__ ow1, const float* __restrict__ ob1,
    const float* __restrict__ ow2, const float* __restrict__ ob2,
    const float* __restrict__ ow3, const float* __restrict__ ob3,
    float* __restrict__ out)
{
    int b  = blockIdx.x >> 5;
    int e0 = (blockIdx.x & 31) * 8;
    int t = threadIdx.x;
    __shared__ float smem[7936];
    float (*aS)[100]   = (float(*)[100])smem;            // 800
    float (*gS)[84]    = (float(*)[84])(smem + 800);     // 672
    float (*ocS)[84]   = (float(*)[84])(smem + 1472);    // 672
    float* mS          = smem + 2144;                    // 96
    float (*inS)[INVD] = (float(*)[INVD])(smem + 2240);  // 384
    float (*q8)[132]   = (float(*)[132])(smem + 2624);   // 1056 -> 3680
    float* Kt          = smem + 3680;                    // [32][133]=4256 (scores phase)
    float (*l1S)[HID]  = (float(*)[HID])(smem + 3680);   // alias (MLP phase)
    float (*l2S)[HID]  = (float(*)[HID])(smem + 3680 + 1024);

    if (t < 160) {
        int el = t / 20, c4 = t - 20*(t/20);
        *(float4*)&gS[el][c4*4] = *(const float4*)&gexp[(e0 + el)*OUT_DIM + c4*4];
    }
    if (t < NN) mS[t] = ((unsigned)inv[b*NN + t] < E_ATT) ? 1.0f : 0.0f;
    {
        int el = t >> 5, i4 = t & 31;
        *(float4*)&q8[el][i4*4] = *(const float4*)&qmat[(b*NE + e0 + el)*LAT + i4*4];
    }

    // ---- scores: 8 e-rows x 96 n, K staged in conflict-free stride-133 tiles ----
    int el = t >> 5, tn = t & 31;
    float sacc0 = 0.f, sacc1 = 0.f, sacc2 = 0.f;
    #pragma unroll
    for (int nt = 0; nt < 3; nt++) {
        __syncthreads();
        for (int p = 0; p < 4; p++) {
            int idx = t + 256*p; int n = idx >> 5, i4 = idx & 31;
            *(float4*)&Kt[n*133 + i4*4] = *(const float4*)&kmat[(b*NN + nt*32 + n)*LAT + i4*4];
        }
        __syncthreads();
        float a0 = 0.f, a1 = 0.f;   // 2 partial accumulators: break the FMA chain
        #pragma unroll 16
        for (int i = 0; i < LAT; i += 2) {
            a0 += q8[el][i]*Kt[tn*133 + i];
            a1 += q8[el][i+1]*Kt[tn*133 + i+1];
        }
        float acc = a0 + a1;
        if (nt == 0) sacc0 = acc; else if (nt == 1) sacc1 = acc; else sacc2 = acc;
    }

    // ---- masked scores + softmax (registers; same op order as proven) ----
    {
        const float scale = 0.04419417382415922f;  // (1/HEADS)*HD^-0.5
        int ng = tn;
        float m0 = mS[ng], m1 = mS[ng + 32], m2 = mS[ng + 64];
        float s0 = (m0 != 0.f) ? sacc0*scale : -1e9f;
        float s1 = (m1 != 0.f) ? sacc1*scale : -1e9f;
        float s2 = (m2 != 0.f) ? sacc2*scale : -1e9f;
        float mx = fmaxf(s0, fmaxf(s1, s2));
        #pragma unroll
        for (int off = 1; off < 32; off <<= 1) mx = fmaxf(mx, __shfl_xor(mx, off));
        float e0v = expf(s0 - mx), e1v = expf(s1 - mx), e2v = expf(s2 - mx);
        float sm = e0v + e1v + e2v;
        #pragma unroll
        for (int off = 1; off < 32; off <<= 1) sm += __shfl_xor(sm, off);
        float r = 1.0f / sm;
        float p0 = m0*e0v*r, p1 = m1*e1v*r, p2 = m2*e2v*r;
        float ss = p0 + p1 + p2;
        #pragma unroll
        for (int off = 1; off < 32; off <<= 1) ss += __shfl_xor(ss, off);
        float is = 1.0f / fmaxf(ss, 1e-8f);
        aS[el][ng]      = p0*is;
        aS[el][ng + 32] = p1*is;
        aS[el][ng + 64] = p2*is;
    }
    __syncthreads();

    if (t < 160) {
        int el2 = t / 20, c4 = t - 20*(t/20);
        const float* vp = virr + (long)b*NN*OUT_DIM + c4*4;
        float4 acc = make_float4(0,0,0,0);
        #pragma unroll 8
        for (int n = 0; n < NN; n++) {
            float a = aS[el2][n];
            float4 v = *(const float4*)&vp[n*OUT_DIM];
            acc.x += a*v.x; acc.y += a*v.y; acc.z += a*v.z; acc.w += a*v.w;
        }
        float4 g = *(float4*)&gS[el2][c4*4];
        float4 o; o.x = acc.x*g.x; o.y = acc.y*g.y; o.z = acc.z*g.z; o.w = acc.w*g.w;
        *(float4*)&ocS[el2][c4*4] = o;
    }
    __syncthreads();

    for (int u = t; u < 8*INVD; u += 256) {
        int el2 = u / INVD, j = u - INVD*(u/INVD);
        float val;
        if (j < M0O) val = ocS[el2][j];
        else {
            int o = j - M0O;
            float x = ocS[el2][M0O + 3*o], y = ocS[el2][M0O + 3*o + 1], zz = ocS[el2][M0O + 3*o + 2];
            val = sqrtf(x*x + y*y + zz*zz + 1e-12f);
        }
        inS[el2][j] = val;
    }
    __syncthreads();

    int r = t >> 5, c0 = (t & 31)*4;
    {
        float4 a0 = *(const float4*)&ob1[c0];
        float4 a1 = make_float4(0,0,0,0);
        #pragma unroll 8
        for (int i = 0; i < INVD; i += 2) {
            float x0v = inS[r][i], x1v = inS[r][i+1];
            float4 w0 = *(const float4*)&ow1[i*HID + c0];
            float4 w1 = *(const float4*)&ow1[(i+1)*HID + c0];
            a0.x += x0v*w0.x; a0.y += x0v*w0.y; a0.z += x0v*w0.z; a0.w += x0v*w0.w;
            a1.x += x1v*w1.x; a1.y += x1v*w1.y; a1.z += x1v*w1.z; a1.w += x1v*w1.w;
        }
        l1S[r][c0]   = silu_f(a0.x + a1.x); l1S[r][c0+1] = silu_f(a0.y + a1.y);
        l1S[r][c0+2] = silu_f(a0.z + a1.z); l1S[r][c0+3] = silu_f(a0.w + a1.w);
    }
    __syncthreads();
    {
        float4 a0 = *(const float4*)&ob2[c0];
        float4 a1 = make_float4(0,0,0,0);
        #pragma unroll 8
        for (int i = 0; i < HID; i += 2) {
            float x0v = l1S[r][i], x1v = l1S[r][i+1];
            float4 w0 = *(const float4*)&ow2[i*HID + c0];
            float4 w1 = *(const float4*)&ow2[(i+1)*HID + c0];
            a0.x += x0v*w0.x; a0.y += x0v*w0.y; a0.z += x0v*w0.z; a0.w += x0v*w0.w;
            a1.x += x1v*w1.x; a1.y += x1v*w1.y; a1.z += x1v*w1.z; a1.w += x1v*w1.w;
        }
        l2S[r][c0]   = silu_f(a0.x + a1.x); l2S[r][c0+1] = silu_f(a0.y + a1.y);
        l2S[r][c0+2] = silu_f(a0.z + a1.z); l2S[r][c0+3] = silu_f(a0.w + a1.w);
    }
    __syncthreads();
    {
        float4 a0 = *(const float4*)&ob3[c0];
        float4 a1 = make_float4(0,0,0,0);
        #pragma unroll 8
        for (int i = 0; i < HID; i += 2) {
            float x0v = l2S[r][i], x1v = l2S[r][i+1];
            float4 w0 = *(const float4*)&ow3[i*HID + c0];
            float4 w1 = *(const float4*)&ow3[(i+1)*HID + c0];
            a0.x += x0v*w0.x; a0.y += x0v*w0.y; a0.z += x0v*w0.z; a0.w += x0v*w0.w;
            a1.x += x1v*w1.x; a1.y += x1v*w1.y; a1.z += x1v*w1.z; a1.w += x1v*w1.w;
        }
        float4 o;
        o.x = a0.x + a1.x; o.y = a0.y + a1.y; o.z = a0.z + a1.z; o.w = a0.w + a1.w;
        *(float4*)&out[((b*NE + e0) + r)*LAT + c0] = o;
    }
}

extern "C" void kernel_launch(void* const* d_in, const int* in_sizes, int n_in,
                              void* d_out, int out_size, void* d_ws, size_t ws_size,
                              hipStream_t stream) {
    const float* h        = (const float*)d_in[0];
    const float* h_full   = (const float*)d_in[1];
    const float* e_feat   = (const float*)d_in[2];
    const float* att_dist = (const float*)d_in[3];
    const float* att_vec  = (const float*)d_in[4];
    const float* z_emb    = (const float*)d_in[5];
    const float* rw1 = (const float*)d_in[6];  const float* rb1 = (const float*)d_in[7];
    const float* rw2 = (const float*)d_in[8];  const float* rb2 = (const float*)d_in[9];
    const float* ew1 = (const float*)d_in[10]; const float* eb1 = (const float*)d_in[11];
    const float* ew2 = (const float*)d_in[12]; const float* eb2 = (const float*)d_in[13];
    const float* qw1 = (const float*)d_in[14]; const float* qb1 = (const float*)d_in[15];
    const float* qw2 = (const float*)d_in[16]; const float* qb2 = (const float*)d_in[17];
    const float* qw3 = (const float*)d_in[18]; const float* qb3 = (const float*)d_in[19];
    const float* kw1 = (const float*)d_in[20]; const float* kb1 = (const float*)d_in[21];
    const float* kw2 = (const float*)d_in[22]; const float* kb2 = (const float*)d_in[23];
    const float* kw3 = (const float*)d_in[24]; const float* kb3 = (const float*)d_in[25];
    const float* ow1 = (const float*)d_in[26]; const float* ob1 = (const float*)d_in[27];
    const float* ow2 = (const float*)d_in[28]; const float* ob2 = (const float*)d_in[29];
    const float* ow3 = (const float*)d_in[30]; const float* ob3 = (const float*)d_in[31];
    const int* z        = (const int*)d_in[32];
    const int* absorber = (const int*)d_in[34];
    const int* att_dst  = (const int*)d_in[35];

    float* ws = (float*)d_ws;
    int*   inv     = (int*)ws;                    // 1536
    float* kmat    = ws + 5632;                   // 196608 (1536x128)
    float* qmat    = ws + 202240;                 // 524288 (4096x128)
    float* gexp    = ws + 726528;                 // 20480
    float* virr    = ws + 747008;                 // 122880 (1536x80)

    float* out = (float*)d_out;

    k1<<<K1_BLKS, 256, 0, stream>>>(h, h_full, z_emb, z, absorber, e_feat,
                                    att_dst, att_dist, att_vec,
                                    rw1, rb1, rw2, rb2,
                                    kw1, kb1, kw2, kb2, kw3, kb3,
                                    qw1, qb1, qw2, qb2, qw3, qb3,
                                    ew1, eb1, ew2, eb2,
                                    kmat, qmat, gexp, virr, inv);
    k_attf<<<BB*32, 256, 0, stream>>>(qmat, kmat, inv, virr, gexp,
                                      ow1, ob1, ow2, ob2, ow3, ob3, out);
}